// Round 1
// baseline (777.575 us; speedup 1.0000x reference)
//
#include <hip/hip_runtime.h>

#define NN 50000          // nodes
#define NE 800000         // edges (without self loops)
#define NE2 (NE + NN)     // edges + self loops
#define FD 128            // input feature dim
#define HD 128            // hidden dim
#define NHD 4             // heads
#define OD 512            // heads * HD
#define NG 512            // graphs
#define BN_EPS 1e-5f

// ---------------- CSR build ----------------
__global__ void init_k(int* __restrict__ deg, int* __restrict__ fill) {
    int i = blockIdx.x * blockDim.x + threadIdx.x;
    if (i < NN) { deg[i] = 1; fill[i] = 0; }   // 1 = self loop
}

__global__ void count_k(const int* __restrict__ ei, int* __restrict__ deg) {
    int e = blockIdx.x * blockDim.x + threadIdx.x;
    if (e < NE) atomicAdd(&deg[ei[NE + e]], 1);
}

__global__ __launch_bounds__(1024) void scan_k(const int* __restrict__ deg,
                                               int* __restrict__ rowptr) {
    __shared__ int part[1024];
    int tid = threadIdx.x;
    const int chunk = (NN + 1023) / 1024;
    int beg = tid * chunk;
    int end = min(beg + chunk, NN);
    int s = 0;
    for (int i = beg; i < end; ++i) s += deg[i];
    part[tid] = s;
    __syncthreads();
    for (int off = 1; off < 1024; off <<= 1) {
        int v = (tid >= off) ? part[tid - off] : 0;
        __syncthreads();
        part[tid] += v;
        __syncthreads();
    }
    int run = (tid == 0) ? 0 : part[tid - 1];
    for (int i = beg; i < end; ++i) { rowptr[i] = run; run += deg[i]; }
    if (tid == 0) rowptr[NN] = part[1023];
}

__global__ void fill_k(const int* __restrict__ ei, const int* __restrict__ rowptr,
                       int* __restrict__ fill, int* __restrict__ csr) {
    int e = blockIdx.x * blockDim.x + threadIdx.x;
    if (e >= NE2) return;
    int src, dst;
    if (e < NE) { src = ei[e]; dst = ei[NE + e]; }
    else        { src = e - NE; dst = e - NE; }
    int pos = atomicAdd(&fill[dst], 1);
    csr[rowptr[dst] + pos] = src;
}

// ---------------- fp32 tiled GEMM: C[M,N] = A[M,K] @ B[K,N] ----------------
__global__ __launch_bounds__(256) void sgemm64(const float* __restrict__ A,
                                               const float* __restrict__ B,
                                               float* __restrict__ C,
                                               int M, int N, int K) {
    __shared__ float As[16][68];   // padded: conflict-light, 16B-aligned rows
    __shared__ float Bs[16][64];
    const int tid = threadIdx.x;
    const int tx = tid & 15, ty = tid >> 4;
    const int row0 = blockIdx.x * 64;
    const int col0 = blockIdx.y * 64;
    float acc[4][4] = {};
    const int la_m = tid >> 2;
    const int la_k = (tid & 3) << 2;
    const int lb_k = tid >> 4;
    const int lb_n = (tid & 15) << 2;
    for (int k0 = 0; k0 < K; k0 += 16) {
        int ar = row0 + la_m;
        float4 av = make_float4(0.f, 0.f, 0.f, 0.f);
        if (ar < M) av = *(const float4*)(A + (size_t)ar * K + k0 + la_k);
        As[la_k + 0][la_m] = av.x; As[la_k + 1][la_m] = av.y;
        As[la_k + 2][la_m] = av.z; As[la_k + 3][la_m] = av.w;
        *(float4*)(&Bs[lb_k][lb_n]) =
            *(const float4*)(B + (size_t)(k0 + lb_k) * N + col0 + lb_n);
        __syncthreads();
        #pragma unroll
        for (int k = 0; k < 16; ++k) {
            float a[4], b[4];
            #pragma unroll
            for (int i = 0; i < 4; ++i) a[i] = As[k][(ty << 2) + i];
            #pragma unroll
            for (int j = 0; j < 4; ++j) b[j] = Bs[k][(tx << 2) + j];
            #pragma unroll
            for (int i = 0; i < 4; ++i)
                #pragma unroll
                for (int j = 0; j < 4; ++j)
                    acc[i][j] = fmaf(a[i], b[j], acc[i][j]);
        }
        __syncthreads();
    }
    #pragma unroll
    for (int i = 0; i < 4; ++i) {
        int r = row0 + (ty << 2) + i;
        if (r < M) {
            float4 v = make_float4(acc[i][0], acc[i][1], acc[i][2], acc[i][3]);
            *(float4*)(C + (size_t)r * N + col0 + (tx << 2)) = v;
        }
    }
}

// ---------------- precompute wa[k][j]: j<4 -> w_gat col-block . a_src[head] ----------------
__global__ void wa_k(const float* __restrict__ w_gat, const float* __restrict__ a_src,
                     const float* __restrict__ a_dst, float* __restrict__ wa) {
    int t = blockIdx.x * blockDim.x + threadIdx.x;
    if (t >= 128 * 8) return;
    int k = t >> 3, j = t & 7, head = j & 3;
    const float* av = (j < 4 ? a_src : a_dst) + head * 128;
    const float* w = w_gat + (size_t)k * OD + head * 128;
    float s = 0.f;
    for (int d = 0; d < 128; ++d) s += w[d] * av[d];
    wa[k * 8 + j] = s;
}

// ---------------- GCN aggregate + bias + BN + ReLU, fused asrc/adst ----------------
__global__ __launch_bounds__(128) void gcn_agg_k(
    const float* __restrict__ h0, const int* __restrict__ rowptr,
    const int* __restrict__ csr, const int* __restrict__ deg,
    const float* __restrict__ b_gcn, const float* __restrict__ gam,
    const float* __restrict__ bet, const float* __restrict__ mean,
    const float* __restrict__ var, const float* __restrict__ wa,
    float* __restrict__ h, float* __restrict__ asrc, float* __restrict__ adst) {
    int n = blockIdx.x;
    int d = threadIdx.x;
    int r0 = rowptr[n], r1 = rowptr[n + 1];
    float acc = 0.f;
    for (int e = r0; e < r1; ++e) {
        int s = csr[e];
        float ns = rsqrtf((float)deg[s]);
        acc += h0[(size_t)s * HD + d] * ns;
    }
    float v = acc * rsqrtf((float)deg[n]) + b_gcn[d];
    v = (v - mean[d]) * rsqrtf(var[d] + BN_EPS) * gam[d] + bet[d];
    v = fmaxf(v, 0.f);
    h[(size_t)n * HD + d] = v;
    __shared__ float hrow[HD];
    hrow[d] = v;
    __syncthreads();
    if (d < 8) {
        const float* w = wa + d;
        float s = 0.f;
        for (int k = 0; k < HD; ++k) s += hrow[k] * w[k * 8];
        if (d < 4) asrc[n * 4 + d] = s;
        else       adst[n * 4 + (d - 4)] = s;
    }
}

// ---------------- GAT: one wave per node, online segment-softmax + aggregate ----------------
__global__ __launch_bounds__(256) void gat_agg_k(
    const float* __restrict__ hg, const float* __restrict__ asrc,
    const float* __restrict__ adst, const int* __restrict__ rowptr,
    const int* __restrict__ csr, const float* __restrict__ b_gat,
    const float* __restrict__ gam, const float* __restrict__ bet,
    const float* __restrict__ mean, const float* __restrict__ var,
    float* __restrict__ outfeat) {
    int wid = threadIdx.x >> 6;
    int lane = threadIdx.x & 63;
    int n = blockIdx.x * 4 + wid;       // grid is exactly NN/4
    int r0 = rowptr[n], r1 = rowptr[n + 1];
    float4 ad = *(const float4*)(adst + n * 4);
    float m0 = -__builtin_inff(), m1 = m0, m2 = m0, m3 = m0;
    float s0 = 0.f, s1 = 0.f, s2 = 0.f, s3 = 0.f;
    float acc[8] = {0.f, 0.f, 0.f, 0.f, 0.f, 0.f, 0.f, 0.f};
    for (int e = r0; e < r1; ++e) {
        int src = csr[e];
        float4 as = *(const float4*)(asrc + src * 4);
        float e0 = as.x + ad.x, e1 = as.y + ad.y, e2 = as.z + ad.z, e3 = as.w + ad.w;
        e0 = e0 >= 0.f ? e0 : 0.2f * e0;
        e1 = e1 >= 0.f ? e1 : 0.2f * e1;
        e2 = e2 >= 0.f ? e2 : 0.2f * e2;
        e3 = e3 >= 0.f ? e3 : 0.2f * e3;
        float n0 = fmaxf(m0, e0), n1 = fmaxf(m1, e1), n2 = fmaxf(m2, e2), n3 = fmaxf(m3, e3);
        float c0 = __expf(m0 - n0), c1 = __expf(m1 - n1), c2 = __expf(m2 - n2), c3 = __expf(m3 - n3);
        float p0 = __expf(e0 - n0), p1 = __expf(e1 - n1), p2 = __expf(e2 - n2), p3 = __expf(e3 - n3);
        m0 = n0; m1 = n1; m2 = n2; m3 = n3;
        s0 = s0 * c0 + p0; s1 = s1 * c1 + p1; s2 = s2 * c2 + p2; s3 = s3 * c3 + p3;
        const float* hr = hg + (size_t)src * OD;
        float sc[4] = {c0, c1, c2, c3};
        float pp[4] = {p0, p1, p2, p3};
        #pragma unroll
        for (int j = 0; j < 8; ++j) {
            int hh = j >> 1;
            acc[j] = acc[j] * sc[hh] + pp[hh] * hr[lane + 64 * j];
        }
    }
    float sd[4] = {s0 + 1e-16f, s1 + 1e-16f, s2 + 1e-16f, s3 + 1e-16f};
    #pragma unroll
    for (int j = 0; j < 8; ++j) {
        int hh = j >> 1;
        int d = lane + 64 * j;
        float v = acc[j] / sd[hh] + b_gat[d];
        v = (v - mean[d]) * rsqrtf(var[d] + BN_EPS) * gam[d] + bet[d];
        v = fmaxf(v, 0.f);
        outfeat[(size_t)n * OD + d] = v;
    }
}

// ---------------- pooling: one block per graph ----------------
__global__ __launch_bounds__(256) void pool_k(const float* __restrict__ outfeat,
                                              const int* __restrict__ batch,
                                              float* __restrict__ feat) {
    int g = blockIdx.x;
    int lo = 0, hi = NN;
    while (lo < hi) { int mid = (lo + hi) >> 1; if (batch[mid] < g) lo = mid + 1; else hi = mid; }
    int start = lo;
    hi = NN;
    while (lo < hi) { int mid = (lo + hi) >> 1; if (batch[mid] < g + 1) lo = mid + 1; else hi = mid; }
    int end = lo;
    int cnt = end - start;
    for (int d = threadIdx.x; d < OD; d += 256) {
        float sadd = 0.f, smax = -3.402823466e38f;
        for (int i = start; i < end; ++i) {
            float v = outfeat[(size_t)i * OD + d];
            sadd += v;
            smax = fmaxf(smax, v);
        }
        float smean;
        if (cnt > 0) { smean = sadd / (float)cnt; }
        else { sadd = 0.f; smax = 0.f; smean = 0.f; }
        feat[g * 1536 + d] = sadd;
        feat[g * 1536 + 512 + d] = smax;
        feat[g * 1536 + 1024 + d] = smean;
    }
}

// ---------------- head: out = sigmoid(feat @ w_lin + b_lin) ----------------
__global__ __launch_bounds__(256) void head_k(const float* __restrict__ feat,
                                              const float* __restrict__ w_lin,
                                              const float* __restrict__ b_lin,
                                              float* __restrict__ out) {
    __shared__ float red[256];
    int g = blockIdx.x;
    int t = threadIdx.x;
    int o = t & 15, part = t >> 4;
    float s = 0.f;
    int kbeg = part * 96;
    for (int k = kbeg; k < kbeg + 96; ++k) s += feat[g * 1536 + k] * w_lin[k * 16 + o];
    red[t] = s;
    __syncthreads();
    if (t < 16) {
        float tot = b_lin[o];
        for (int p = 0; p < 16; ++p) tot += red[p * 16 + o];
        out[g * 16 + o] = 1.f / (1.f + __expf(-tot));
    }
}

extern "C" void kernel_launch(void* const* d_in, const int* in_sizes, int n_in,
                              void* d_out, int out_size, void* d_ws, size_t ws_size,
                              hipStream_t stream) {
    const float* x       = (const float*)d_in[0];
    const int*   ei      = (const int*)d_in[1];
    const int*   batch   = (const int*)d_in[2];
    const float* w_gcn   = (const float*)d_in[3];
    const float* b_gcn   = (const float*)d_in[4];
    const float* g2_gam  = (const float*)d_in[5];
    const float* g2_bet  = (const float*)d_in[6];
    const float* g2_mean = (const float*)d_in[7];
    const float* g2_var  = (const float*)d_in[8];
    const float* w_gat   = (const float*)d_in[9];
    const float* a_src   = (const float*)d_in[10];
    const float* a_dst   = (const float*)d_in[11];
    const float* b_gat   = (const float*)d_in[12];
    const float* g1_gam  = (const float*)d_in[13];
    const float* g1_bet  = (const float*)d_in[14];
    const float* g1_mean = (const float*)d_in[15];
    const float* g1_var  = (const float*)d_in[16];
    const float* w_lin   = (const float*)d_in[17];
    const float* b_lin   = (const float*)d_in[18];
    float* out = (float*)d_out;

    char* ws = (char*)d_ws;
    size_t off = 0;
    auto alloc = [&](size_t bytes) -> void* {
        void* p = ws + off;
        off += (bytes + 255) & ~(size_t)255;
        return p;
    };
    int* deg     = (int*)alloc((size_t)NN * 4);
    int* fill    = (int*)alloc((size_t)NN * 4);
    int* rowptr  = (int*)alloc((size_t)(NN + 1) * 4);
    int* csr     = (int*)alloc((size_t)NE2 * 4);
    float* h0    = (float*)alloc((size_t)NN * HD * 4);
    float* h     = (float*)alloc((size_t)NN * HD * 4);
    float* hg    = (float*)alloc((size_t)NN * OD * 4);
    float* asrc  = (float*)alloc((size_t)NN * 4 * 4);
    float* adst  = (float*)alloc((size_t)NN * 4 * 4);
    float* wa    = (float*)alloc((size_t)128 * 8 * 4);
    float* ofeat = (float*)alloc((size_t)NN * OD * 4);
    float* feat  = (float*)alloc((size_t)NG * 1536 * 4);

    // CSR build
    init_k<<<(NN + 255) / 256, 256, 0, stream>>>(deg, fill);
    count_k<<<(NE + 255) / 256, 256, 0, stream>>>(ei, deg);
    scan_k<<<1, 1024, 0, stream>>>(deg, rowptr);
    fill_k<<<(NE2 + 255) / 256, 256, 0, stream>>>(ei, rowptr, fill, csr);

    // GCN linear: h0 = x @ w_gcn
    sgemm64<<<dim3((NN + 63) / 64, HD / 64), 256, 0, stream>>>(x, w_gcn, h0, NN, HD, FD);

    // attention weight pre-projection
    wa_k<<<4, 256, 0, stream>>>(w_gat, a_src, a_dst, wa);

    // GCN aggregate + BN2 + ReLU (+ fused asrc/adst)
    gcn_agg_k<<<NN, 128, 0, stream>>>(h0, rowptr, csr, deg, b_gcn, g2_gam, g2_bet,
                                      g2_mean, g2_var, wa, h, asrc, adst);

    // GAT linear: hg = h @ w_gat
    sgemm64<<<dim3((NN + 63) / 64, OD / 64), 256, 0, stream>>>(h, w_gat, hg, NN, OD, HD);

    // GAT attention + aggregate + BN1 + ReLU
    gat_agg_k<<<NN / 4, 256, 0, stream>>>(hg, asrc, adst, rowptr, csr, b_gat,
                                          g1_gam, g1_bet, g1_mean, g1_var, ofeat);

    // pooling
    pool_k<<<NG, 256, 0, stream>>>(ofeat, batch, feat);

    // head
    head_k<<<NG, 256, 0, stream>>>(feat, w_lin, b_lin, out);
}

// Round 2
// 612.855 us; speedup vs baseline: 1.2688x; 1.2688x over previous
//
#include <hip/hip_runtime.h>

#define NN 50000          // nodes
#define NE 800000         // edges (without self loops)
#define NE2 (NE + NN)     // edges + self loops
#define FD 128            // input feature dim
#define HD 128            // hidden dim
#define NHD 4             // heads
#define OD 512            // heads * HD
#define NG 512            // graphs
#define BN_EPS 1e-5f

typedef __attribute__((ext_vector_type(8))) short bfrag;   // 8 bf16 = 4 VGPRs
typedef __attribute__((ext_vector_type(4))) float f32x4;
typedef unsigned short ushort_t;

__device__ inline ushort_t f2bf(float f) {               // RNE fp32->bf16
    unsigned int u = __float_as_uint(f);
    unsigned int r = (u + 0x7fffu + ((u >> 16) & 1u)) >> 16;
    return (ushort_t)r;
}
__device__ inline float bf2f_lo(unsigned int v) { return __uint_as_float(v << 16); }
__device__ inline float bf2f_hi(unsigned int v) { return __uint_as_float(v & 0xffff0000u); }

// ---------------- CSR build ----------------
__global__ void init_k(int* __restrict__ deg, int* __restrict__ fill) {
    int i = blockIdx.x * blockDim.x + threadIdx.x;
    if (i < NN) { deg[i] = 1; fill[i] = 0; }   // 1 = self loop
}

__global__ void count_k(const int* __restrict__ ei, int* __restrict__ deg) {
    int e = blockIdx.x * blockDim.x + threadIdx.x;
    if (e < NE) atomicAdd(&deg[ei[NE + e]], 1);
}

__global__ __launch_bounds__(1024) void scan_k(const int* __restrict__ deg,
                                               int* __restrict__ rowptr) {
    __shared__ int part[1024];
    int tid = threadIdx.x;
    const int chunk = (NN + 1023) / 1024;
    int beg = tid * chunk;
    int end = min(beg + chunk, NN);
    int s = 0;
    for (int i = beg; i < end; ++i) s += deg[i];
    part[tid] = s;
    __syncthreads();
    for (int off = 1; off < 1024; off <<= 1) {
        int v = (tid >= off) ? part[tid - off] : 0;
        __syncthreads();
        part[tid] += v;
        __syncthreads();
    }
    int run = (tid == 0) ? 0 : part[tid - 1];
    for (int i = beg; i < end; ++i) { rowptr[i] = run; run += deg[i]; }
    if (tid == 0) rowptr[NN] = part[1023];
}

__global__ void fill_k(const int* __restrict__ ei, const int* __restrict__ rowptr,
                       int* __restrict__ fill, int* __restrict__ csr) {
    int e = blockIdx.x * blockDim.x + threadIdx.x;
    if (e >= NE2) return;
    int src, dst;
    if (e < NE) { src = ei[e]; dst = ei[NE + e]; }
    else        { src = e - NE; dst = e - NE; }
    int pos = atomicAdd(&fill[dst], 1);
    csr[rowptr[dst] + pos] = src;
}

// ---------------- casts ----------------
__global__ void cast_x_k(const float* __restrict__ x, ushort_t* __restrict__ xb) {
    int t = blockIdx.x * blockDim.x + threadIdx.x;      // one float4 per thread
    const int total = NN * FD / 4;
    if (t >= total) return;
    float4 v = ((const float4*)x)[t];
    ushort_t o[4] = {f2bf(v.x), f2bf(v.y), f2bf(v.z), f2bf(v.w)};
    *(unsigned long long*)(xb + 4 * t) = *(unsigned long long*)o;
}

// wT[n*K + k] = bf16(w[k*N + n])
__global__ void trcast_k(const float* __restrict__ w, ushort_t* __restrict__ wT,
                         int K, int N) {
    int t = blockIdx.x * blockDim.x + threadIdx.x;
    if (t >= K * N) return;
    int n = t / K, k = t - n * K;
    wT[n * K + k] = f2bf(w[k * N + n]);
}

// ---------------- bf16 MFMA GEMM: C[M,N] = A[M,128] @ B[128,N], C stored bf16
// A: bf16 row-major [M][128]; BT: bf16 [N][128] (pre-transposed). Tile 128x64, 4 waves.
__global__ __launch_bounds__(256) void gemm_bf16(const ushort_t* __restrict__ A,
                                                 const ushort_t* __restrict__ BT,
                                                 ushort_t* __restrict__ C,
                                                 int M, int N) {
    __shared__ short As[128][136];   // +8 shorts pad: row stride 272B -> 2-way max
    __shared__ short Bs[64][136];
    const int tid = threadIdx.x;
    const int m0 = blockIdx.x * 128;
    const int n0 = blockIdx.y * 64;

    // stage A tile: 128 rows x 128 bf16 = 2048 16B-chunks
    #pragma unroll
    for (int i = 0; i < 8; ++i) {
        int c = tid + 256 * i;
        int row = c >> 4, off = (c & 15) * 8;
        bfrag v = (bfrag)0;
        if (m0 + row < M) v = *(const bfrag*)(A + (size_t)(m0 + row) * 128 + off);
        *(bfrag*)&As[row][off] = v;
    }
    // stage B tile: 64 rows x 128 bf16 = 1024 chunks
    #pragma unroll
    for (int i = 0; i < 4; ++i) {
        int c = tid + 256 * i;
        int row = c >> 4, off = (c & 15) * 8;
        *(bfrag*)&Bs[row][off] = *(const bfrag*)(BT + (size_t)(n0 + row) * 128 + off);
    }
    __syncthreads();

    const int w = tid >> 6;            // wave id: rows 32w..32w+31
    const int lr = tid & 15;           // lane & 15
    const int kg = (tid & 63) >> 4;    // lane >> 4

    f32x4 acc[2][4];
    #pragma unroll
    for (int mi = 0; mi < 2; ++mi)
        #pragma unroll
        for (int ni = 0; ni < 4; ++ni) acc[mi][ni] = (f32x4)0.f;

    #pragma unroll
    for (int ks = 0; ks < 4; ++ks) {
        bfrag af[2], bb[4];
        #pragma unroll
        for (int mi = 0; mi < 2; ++mi)
            af[mi] = *(const bfrag*)&As[32 * w + 16 * mi + lr][32 * ks + 8 * kg];
        #pragma unroll
        for (int ni = 0; ni < 4; ++ni)
            bb[ni] = *(const bfrag*)&Bs[16 * ni + lr][32 * ks + 8 * kg];
        #pragma unroll
        for (int mi = 0; mi < 2; ++mi)
            #pragma unroll
            for (int ni = 0; ni < 4; ++ni)
                acc[mi][ni] = __builtin_amdgcn_mfma_f32_16x16x32_bf16(
                    af[mi], bb[ni], acc[mi][ni], 0, 0, 0);
    }

    #pragma unroll
    for (int mi = 0; mi < 2; ++mi) {
        #pragma unroll
        for (int r = 0; r < 4; ++r) {
            int row = m0 + 32 * w + 16 * mi + 4 * kg + r;
            if (row < M) {
                #pragma unroll
                for (int ni = 0; ni < 4; ++ni) {
                    int col = n0 + 16 * ni + lr;
                    C[(size_t)row * N + col] = f2bf(acc[mi][ni][r]);
                }
            }
        }
    }
}

// ---------------- precompute wa[k][j]: j<4 -> w_gat col-block . a_src[head] ----------------
__global__ void wa_k(const float* __restrict__ w_gat, const float* __restrict__ a_src,
                     const float* __restrict__ a_dst, float* __restrict__ wa) {
    int t = blockIdx.x * blockDim.x + threadIdx.x;
    if (t >= 128 * 8) return;
    int k = t >> 3, j = t & 7, head = j & 3;
    const float* av = (j < 4 ? a_src : a_dst) + head * 128;
    const float* w = w_gat + (size_t)k * OD + head * 128;
    float s = 0.f;
    for (int d = 0; d < 128; ++d) s += w[d] * av[d];
    wa[k * 8 + j] = s;
}

// ---------------- GCN aggregate + bias + BN + ReLU, fused asrc/adst; h0 bf16 in, h bf16 out
__global__ __launch_bounds__(128) void gcn_agg_k(
    const ushort_t* __restrict__ h0, const int* __restrict__ rowptr,
    const int* __restrict__ csr, const int* __restrict__ deg,
    const float* __restrict__ b_gcn, const float* __restrict__ gam,
    const float* __restrict__ bet, const float* __restrict__ mean,
    const float* __restrict__ var, const float* __restrict__ wa,
    ushort_t* __restrict__ h, float* __restrict__ asrc, float* __restrict__ adst) {
    int n = blockIdx.x;
    int d = threadIdx.x;
    int r0 = rowptr[n], r1 = rowptr[n + 1];
    float acc = 0.f;
    for (int e = r0; e < r1; ++e) {
        int s = csr[e];
        float ns = rsqrtf((float)deg[s]);
        float hv = bf2f_lo((unsigned int)h0[(size_t)s * HD + d]);
        acc += hv * ns;
    }
    float v = acc * rsqrtf((float)deg[n]) + b_gcn[d];
    v = (v - mean[d]) * rsqrtf(var[d] + BN_EPS) * gam[d] + bet[d];
    v = fmaxf(v, 0.f);
    h[(size_t)n * HD + d] = f2bf(v);
    __shared__ float hrow[HD];
    hrow[d] = v;
    __syncthreads();
    if (d < 8) {
        const float* w = wa + d;
        float s = 0.f;
        for (int k = 0; k < HD; ++k) s += hrow[k] * w[k * 8];
        if (d < 4) asrc[n * 4 + d] = s;
        else       adst[n * 4 + (d - 4)] = s;
    }
}

// ---------------- GAT: one wave per node, online segment-softmax + aggregate (bf16 hg)
__global__ __launch_bounds__(256) void gat_agg_k(
    const ushort_t* __restrict__ hg, const float* __restrict__ asrc,
    const float* __restrict__ adst, const int* __restrict__ rowptr,
    const int* __restrict__ csr, const float* __restrict__ b_gat,
    const float* __restrict__ gam, const float* __restrict__ bet,
    const float* __restrict__ mean, const float* __restrict__ var,
    float* __restrict__ outfeat) {
    int wid = threadIdx.x >> 6;
    int lane = threadIdx.x & 63;
    int n = blockIdx.x * 4 + wid;       // grid is exactly NN/4
    int r0 = rowptr[n], r1 = rowptr[n + 1];
    float4 ad = *(const float4*)(adst + n * 4);
    float m0 = -__builtin_inff(), m1 = m0, m2 = m0, m3 = m0;
    float s0 = 0.f, s1 = 0.f, s2 = 0.f, s3 = 0.f;
    float acc[8] = {0.f, 0.f, 0.f, 0.f, 0.f, 0.f, 0.f, 0.f};
    for (int e = r0; e < r1; ++e) {
        int src = csr[e];
        float4 as = *(const float4*)(asrc + src * 4);
        float e0 = as.x + ad.x, e1 = as.y + ad.y, e2 = as.z + ad.z, e3 = as.w + ad.w;
        e0 = e0 >= 0.f ? e0 : 0.2f * e0;
        e1 = e1 >= 0.f ? e1 : 0.2f * e1;
        e2 = e2 >= 0.f ? e2 : 0.2f * e2;
        e3 = e3 >= 0.f ? e3 : 0.2f * e3;
        float n0 = fmaxf(m0, e0), n1 = fmaxf(m1, e1), n2 = fmaxf(m2, e2), n3 = fmaxf(m3, e3);
        float c0 = __expf(m0 - n0), c1 = __expf(m1 - n1), c2 = __expf(m2 - n2), c3 = __expf(m3 - n3);
        float p0 = __expf(e0 - n0), p1 = __expf(e1 - n1), p2 = __expf(e2 - n2), p3 = __expf(e3 - n3);
        m0 = n0; m1 = n1; m2 = n2; m3 = n3;
        s0 = s0 * c0 + p0; s1 = s1 * c1 + p1; s2 = s2 * c2 + p2; s3 = s3 * c3 + p3;
        const ushort_t* hr = hg + (size_t)src * OD;
        float sc[4] = {c0, c1, c2, c3};
        float pp[4] = {p0, p1, p2, p3};
        #pragma unroll
        for (int q = 0; q < 4; ++q) {                    // d = 128q + 2*lane + {0,1}
            unsigned int v = *(const unsigned int*)(hr + 128 * q + 2 * lane);
            acc[2 * q]     = acc[2 * q]     * sc[q] + pp[q] * bf2f_lo(v);
            acc[2 * q + 1] = acc[2 * q + 1] * sc[q] + pp[q] * bf2f_hi(v);
        }
    }
    float sd[4] = {s0 + 1e-16f, s1 + 1e-16f, s2 + 1e-16f, s3 + 1e-16f};
    #pragma unroll
    for (int q = 0; q < 4; ++q) {
        int d = 128 * q + 2 * lane;
        float v0 = acc[2 * q] / sd[q] + b_gat[d];
        float v1 = acc[2 * q + 1] / sd[q] + b_gat[d + 1];
        v0 = (v0 - mean[d]) * rsqrtf(var[d] + BN_EPS) * gam[d] + bet[d];
        v1 = (v1 - mean[d + 1]) * rsqrtf(var[d + 1] + BN_EPS) * gam[d + 1] + bet[d + 1];
        v0 = fmaxf(v0, 0.f);
        v1 = fmaxf(v1, 0.f);
        *(float2*)(outfeat + (size_t)n * OD + d) = make_float2(v0, v1);
    }
}

// ---------------- pooling: one block per graph ----------------
__global__ __launch_bounds__(256) void pool_k(const float* __restrict__ outfeat,
                                              const int* __restrict__ batch,
                                              float* __restrict__ feat) {
    int g = blockIdx.x;
    int lo = 0, hi = NN;
    while (lo < hi) { int mid = (lo + hi) >> 1; if (batch[mid] < g) lo = mid + 1; else hi = mid; }
    int start = lo;
    hi = NN;
    while (lo < hi) { int mid = (lo + hi) >> 1; if (batch[mid] < g + 1) lo = mid + 1; else hi = mid; }
    int end = lo;
    int cnt = end - start;
    for (int d = threadIdx.x; d < OD; d += 256) {
        float sadd = 0.f, smax = -3.402823466e38f;
        for (int i = start; i < end; ++i) {
            float v = outfeat[(size_t)i * OD + d];
            sadd += v;
            smax = fmaxf(smax, v);
        }
        float smean;
        if (cnt > 0) { smean = sadd / (float)cnt; }
        else { sadd = 0.f; smax = 0.f; smean = 0.f; }
        feat[g * 1536 + d] = sadd;
        feat[g * 1536 + 512 + d] = smax;
        feat[g * 1536 + 1024 + d] = smean;
    }
}

// ---------------- head: out = sigmoid(feat @ w_lin + b_lin) ----------------
__global__ __launch_bounds__(256) void head_k(const float* __restrict__ feat,
                                              const float* __restrict__ w_lin,
                                              const float* __restrict__ b_lin,
                                              float* __restrict__ out) {
    __shared__ float red[256];
    int g = blockIdx.x;
    int t = threadIdx.x;
    int o = t & 15, part = t >> 4;
    float s = 0.f;
    int kbeg = part * 96;
    for (int k = kbeg; k < kbeg + 96; ++k) s += feat[g * 1536 + k] * w_lin[k * 16 + o];
    red[t] = s;
    __syncthreads();
    if (t < 16) {
        float tot = b_lin[o];
        for (int p = 0; p < 16; ++p) tot += red[p * 16 + o];
        out[g * 16 + o] = 1.f / (1.f + __expf(-tot));
    }
}

extern "C" void kernel_launch(void* const* d_in, const int* in_sizes, int n_in,
                              void* d_out, int out_size, void* d_ws, size_t ws_size,
                              hipStream_t stream) {
    const float* x       = (const float*)d_in[0];
    const int*   ei      = (const int*)d_in[1];
    const int*   batch   = (const int*)d_in[2];
    const float* w_gcn   = (const float*)d_in[3];
    const float* b_gcn   = (const float*)d_in[4];
    const float* g2_gam  = (const float*)d_in[5];
    const float* g2_bet  = (const float*)d_in[6];
    const float* g2_mean = (const float*)d_in[7];
    const float* g2_var  = (const float*)d_in[8];
    const float* w_gat   = (const float*)d_in[9];
    const float* a_src   = (const float*)d_in[10];
    const float* a_dst   = (const float*)d_in[11];
    const float* b_gat   = (const float*)d_in[12];
    const float* g1_gam  = (const float*)d_in[13];
    const float* g1_bet  = (const float*)d_in[14];
    const float* g1_mean = (const float*)d_in[15];
    const float* g1_var  = (const float*)d_in[16];
    const float* w_lin   = (const float*)d_in[17];
    const float* b_lin   = (const float*)d_in[18];
    float* out = (float*)d_out;

    char* ws = (char*)d_ws;
    size_t off = 0;
    auto alloc = [&](size_t bytes) -> void* {
        void* p = ws + off;
        off += (bytes + 255) & ~(size_t)255;
        return p;
    };
    int* deg        = (int*)alloc((size_t)NN * 4);
    int* fill       = (int*)alloc((size_t)NN * 4);
    int* rowptr     = (int*)alloc((size_t)(NN + 1) * 4);
    int* csr        = (int*)alloc((size_t)NE2 * 4);
    ushort_t* xb    = (ushort_t*)alloc((size_t)NN * FD * 2);
    ushort_t* wgT   = (ushort_t*)alloc((size_t)FD * HD * 2);
    ushort_t* wgatT = (ushort_t*)alloc((size_t)HD * OD * 2);
    ushort_t* h0b   = (ushort_t*)alloc((size_t)NN * HD * 2);
    ushort_t* hb    = (ushort_t*)alloc((size_t)NN * HD * 2);
    ushort_t* hgb   = (ushort_t*)alloc((size_t)NN * OD * 2);
    float* asrc     = (float*)alloc((size_t)NN * 4 * 4);
    float* adst     = (float*)alloc((size_t)NN * 4 * 4);
    float* wa       = (float*)alloc((size_t)128 * 8 * 4);
    float* ofeat    = (float*)alloc((size_t)NN * OD * 4);
    float* feat     = (float*)alloc((size_t)NG * 1536 * 4);

    // CSR build
    init_k<<<(NN + 255) / 256, 256, 0, stream>>>(deg, fill);
    count_k<<<(NE + 255) / 256, 256, 0, stream>>>(ei, deg);
    scan_k<<<1, 1024, 0, stream>>>(deg, rowptr);
    fill_k<<<(NE2 + 255) / 256, 256, 0, stream>>>(ei, rowptr, fill, csr);

    // casts: x -> bf16; weights -> transposed bf16
    cast_x_k<<<(NN * FD / 4 + 255) / 256, 256, 0, stream>>>(x, xb);
    trcast_k<<<(FD * HD + 255) / 256, 256, 0, stream>>>(w_gcn, wgT, FD, HD);
    trcast_k<<<(HD * OD + 255) / 256, 256, 0, stream>>>(w_gat, wgatT, HD, OD);

    // GCN linear: h0 = x @ w_gcn   (bf16 MFMA)
    gemm_bf16<<<dim3((NN + 127) / 128, HD / 64), 256, 0, stream>>>(xb, wgT, h0b, NN, HD);

    // attention weight pre-projection
    wa_k<<<4, 256, 0, stream>>>(w_gat, a_src, a_dst, wa);

    // GCN aggregate + BN2 + ReLU (+ fused asrc/adst)
    gcn_agg_k<<<NN, 128, 0, stream>>>(h0b, rowptr, csr, deg, b_gcn, g2_gam, g2_bet,
                                      g2_mean, g2_var, wa, hb, asrc, adst);

    // GAT linear: hg = h @ w_gat   (bf16 MFMA)
    gemm_bf16<<<dim3((NN + 127) / 128, OD / 64), 256, 0, stream>>>(hb, wgatT, hgb, NN, OD);

    // GAT attention + aggregate + BN1 + ReLU
    gat_agg_k<<<NN / 4, 256, 0, stream>>>(hgb, asrc, adst, rowptr, csr, b_gat,
                                          g1_gam, g1_bet, g1_mean, g1_var, ofeat);

    // pooling
    pool_k<<<NG, 256, 0, stream>>>(ofeat, batch, feat);

    // head
    head_k<<<NG, 256, 0, stream>>>(feat, w_lin, b_lin, out);
}

// Round 3
// 535.494 us; speedup vs baseline: 1.4521x; 1.1445x over previous
//
#include <hip/hip_runtime.h>

#define NN 50000          // nodes
#define NE 800000         // edges (without self loops)
#define NE2 (NE + NN)     // edges + self loops
#define FD 128            // input feature dim
#define HD 128            // hidden dim
#define NHD 4             // heads
#define OD 512            // heads * HD
#define NG 512            // graphs
#define BN_EPS 1e-5f

typedef __attribute__((ext_vector_type(8))) short bfrag;   // 8 bf16 = 4 VGPRs
typedef __attribute__((ext_vector_type(4))) float f32x4;
typedef unsigned short ushort_t;

__device__ inline ushort_t f2bf(float f) {               // RNE fp32->bf16
    unsigned int u = __float_as_uint(f);
    unsigned int r = (u + 0x7fffu + ((u >> 16) & 1u)) >> 16;
    return (ushort_t)r;
}
__device__ inline float bf2f_lo(unsigned int v) { return __uint_as_float(v << 16); }
__device__ inline float bf2f_hi(unsigned int v) { return __uint_as_float(v & 0xffff0000u); }
__device__ inline float lk(float x) { return fmaxf(x, 0.2f * x); }   // leaky_relu 0.2

// ---------------- CSR build ----------------
__global__ void init_k(int* __restrict__ deg, int* __restrict__ fill) {
    int i = blockIdx.x * blockDim.x + threadIdx.x;
    if (i < NN) { deg[i] = 1; fill[i] = 0; }   // 1 = self loop
}

__global__ void count_k(const int* __restrict__ ei, int* __restrict__ deg) {
    int e = blockIdx.x * blockDim.x + threadIdx.x;
    if (e < NE) atomicAdd(&deg[ei[NE + e]], 1);
}

__global__ __launch_bounds__(1024) void scan_k(const int* __restrict__ deg,
                                               int* __restrict__ rowptr) {
    __shared__ int part[1024];
    int tid = threadIdx.x;
    const int chunk = (NN + 1023) / 1024;
    int beg = tid * chunk;
    int end = min(beg + chunk, NN);
    int s = 0;
    for (int i = beg; i < end; ++i) s += deg[i];
    part[tid] = s;
    __syncthreads();
    for (int off = 1; off < 1024; off <<= 1) {
        int v = (tid >= off) ? part[tid - off] : 0;
        __syncthreads();
        part[tid] += v;
        __syncthreads();
    }
    int run = (tid == 0) ? 0 : part[tid - 1];
    for (int i = beg; i < end; ++i) { rowptr[i] = run; run += deg[i]; }
    if (tid == 0) rowptr[NN] = part[1023];
}

__global__ void fill_k(const int* __restrict__ ei, const int* __restrict__ rowptr,
                       int* __restrict__ fill, int* __restrict__ csr) {
    int e = blockIdx.x * blockDim.x + threadIdx.x;
    if (e >= NE2) return;
    int src, dst;
    if (e < NE) { src = ei[e]; dst = ei[NE + e]; }
    else        { src = e - NE; dst = e - NE; }
    int pos = atomicAdd(&fill[dst], 1);
    csr[rowptr[dst] + pos] = src;
}

__global__ void dis_k(const int* __restrict__ deg, float* __restrict__ dis) {
    int i = blockIdx.x * blockDim.x + threadIdx.x;
    if (i < NN) dis[i] = rsqrtf((float)deg[i]);
}

// ---------------- BN -> affine precompute ----------------
__global__ void bnaff_k(const float* __restrict__ b_gcn, const float* __restrict__ g2_gam,
                        const float* __restrict__ g2_bet, const float* __restrict__ g2_mean,
                        const float* __restrict__ g2_var, const float* __restrict__ b_gat,
                        const float* __restrict__ g1_gam, const float* __restrict__ g1_bet,
                        const float* __restrict__ g1_mean, const float* __restrict__ g1_var,
                        float* __restrict__ Ag, float* __restrict__ Bg,
                        float* __restrict__ Aa, float* __restrict__ Ba) {
    int t = blockIdx.x * blockDim.x + threadIdx.x;
    if (t < HD) {
        float a = rsqrtf(g2_var[t] + BN_EPS) * g2_gam[t];
        Ag[t] = a;
        Bg[t] = (b_gcn[t] - g2_mean[t]) * a + g2_bet[t];
    } else if (t < HD + OD) {
        int d = t - HD;
        float a = rsqrtf(g1_var[d] + BN_EPS) * g1_gam[d];
        Aa[d] = a;
        Ba[d] = (b_gat[d] - g1_mean[d]) * a + g1_bet[d];
    }
}

// ---------------- casts ----------------
__global__ void cast_x_k(const float* __restrict__ x, ushort_t* __restrict__ xb) {
    int t = blockIdx.x * blockDim.x + threadIdx.x;      // one float4 per thread
    const int total = NN * FD / 4;
    if (t >= total) return;
    float4 v = ((const float4*)x)[t];
    ushort_t o[4] = {f2bf(v.x), f2bf(v.y), f2bf(v.z), f2bf(v.w)};
    *(unsigned long long*)(xb + 4 * t) = *(unsigned long long*)o;
}

// wT[n*K + k] = bf16(w[k*N + n])
__global__ void trcast_k(const float* __restrict__ w, ushort_t* __restrict__ wT,
                         int K, int N) {
    int t = blockIdx.x * blockDim.x + threadIdx.x;
    if (t >= K * N) return;
    int n = t / K, k = t - n * K;
    wT[n * K + k] = f2bf(w[k * N + n]);
}

// ---------------- bf16 MFMA GEMM: C[M,N] = A[M,128] @ B[128,N], C stored bf16
__global__ __launch_bounds__(256) void gemm_bf16(const ushort_t* __restrict__ A,
                                                 const ushort_t* __restrict__ BT,
                                                 ushort_t* __restrict__ C,
                                                 int M, int N) {
    __shared__ short As[128][136];
    __shared__ short Bs[64][136];
    const int tid = threadIdx.x;
    const int m0 = blockIdx.x * 128;
    const int n0 = blockIdx.y * 64;

    #pragma unroll
    for (int i = 0; i < 8; ++i) {
        int c = tid + 256 * i;
        int row = c >> 4, off = (c & 15) * 8;
        bfrag v = (bfrag)0;
        if (m0 + row < M) v = *(const bfrag*)(A + (size_t)(m0 + row) * 128 + off);
        *(bfrag*)&As[row][off] = v;
    }
    #pragma unroll
    for (int i = 0; i < 4; ++i) {
        int c = tid + 256 * i;
        int row = c >> 4, off = (c & 15) * 8;
        *(bfrag*)&Bs[row][off] = *(const bfrag*)(BT + (size_t)(n0 + row) * 128 + off);
    }
    __syncthreads();

    const int w = tid >> 6;
    const int lr = tid & 15;
    const int kg = (tid & 63) >> 4;

    f32x4 acc[2][4];
    #pragma unroll
    for (int mi = 0; mi < 2; ++mi)
        #pragma unroll
        for (int ni = 0; ni < 4; ++ni) acc[mi][ni] = (f32x4)0.f;

    #pragma unroll
    for (int ks = 0; ks < 4; ++ks) {
        bfrag af[2], bb[4];
        #pragma unroll
        for (int mi = 0; mi < 2; ++mi)
            af[mi] = *(const bfrag*)&As[32 * w + 16 * mi + lr][32 * ks + 8 * kg];
        #pragma unroll
        for (int ni = 0; ni < 4; ++ni)
            bb[ni] = *(const bfrag*)&Bs[16 * ni + lr][32 * ks + 8 * kg];
        #pragma unroll
        for (int mi = 0; mi < 2; ++mi)
            #pragma unroll
            for (int ni = 0; ni < 4; ++ni)
                acc[mi][ni] = __builtin_amdgcn_mfma_f32_16x16x32_bf16(
                    af[mi], bb[ni], acc[mi][ni], 0, 0, 0);
    }

    #pragma unroll
    for (int mi = 0; mi < 2; ++mi) {
        #pragma unroll
        for (int r = 0; r < 4; ++r) {
            int row = m0 + 32 * w + 16 * mi + 4 * kg + r;
            if (row < M) {
                #pragma unroll
                for (int ni = 0; ni < 4; ++ni) {
                    int col = n0 + 16 * ni + lr;
                    C[(size_t)row * N + col] = f2bf(acc[mi][ni][r]);
                }
            }
        }
    }
}

// ---------------- precompute wa[k][j]: j<4 -> w_gat col-block . a_src[head] ----------------
__global__ void wa_k(const float* __restrict__ w_gat, const float* __restrict__ a_src,
                     const float* __restrict__ a_dst, float* __restrict__ wa) {
    int t = blockIdx.x * blockDim.x + threadIdx.x;
    if (t >= 128 * 8) return;
    int k = t >> 3, j = t & 7, head = j & 3;
    const float* av = (j < 4 ? a_src : a_dst) + head * 128;
    const float* w = w_gat + (size_t)k * OD + head * 128;
    float s = 0.f;
    for (int d = 0; d < 128; ++d) s += w[d] * av[d];
    wa[k * 8 + j] = s;
}

// ---------------- GCN aggregate: wave per node, 2 dims/lane ----------------
__global__ __launch_bounds__(256) void gcn_agg2_k(
    const ushort_t* __restrict__ h0, const int* __restrict__ rowptr,
    const int* __restrict__ csr, const float* __restrict__ dis,
    const float* __restrict__ Ag, const float* __restrict__ Bg,
    ushort_t* __restrict__ h) {
    int wid = threadIdx.x >> 6, lane = threadIdx.x & 63;
    int n = blockIdx.x * 4 + wid;           // grid = NN/4 exactly
    int r0 = rowptr[n], r1 = rowptr[n + 1];
    float a0 = 0.f, a1 = 0.f;
    int src_n = csr[r0];
    for (int e = r0; e < r1; ++e) {
        int src = src_n;
        float w = dis[src];
        unsigned int hv = *(const unsigned int*)(h0 + (size_t)src * HD + 2 * lane);
        if (e + 1 < r1) src_n = csr[e + 1];
        a0 = fmaf(w, bf2f_lo(hv), a0);
        a1 = fmaf(w, bf2f_hi(hv), a1);
    }
    float t = dis[n];
    int d = 2 * lane;
    float2 A = *(const float2*)(Ag + d);
    float2 B = *(const float2*)(Bg + d);
    float v0 = fmaxf(fmaf(a0 * t, A.x, B.x), 0.f);
    float v1 = fmaxf(fmaf(a1 * t, A.y, B.y), 0.f);
    unsigned int packed = (unsigned int)f2bf(v0) | ((unsigned int)f2bf(v1) << 16);
    *(unsigned int*)(h + (size_t)n * HD + d) = packed;
}

// ---------------- asrc/adst: [N,128] @ wa[128,8] ----------------
__global__ __launch_bounds__(256) void attn_dots_k(const ushort_t* __restrict__ h,
                                                   const float* __restrict__ wa,
                                                   float* __restrict__ asrc,
                                                   float* __restrict__ adst) {
    __shared__ float was[128][8];
    int tid = threadIdx.x;
    for (int i = tid; i < 1024; i += 256) was[i >> 3][i & 7] = wa[i];
    __syncthreads();
    int nl = tid >> 3, j = tid & 7;
    int n = blockIdx.x * 32 + nl;
    if (n >= NN) return;
    const ushort_t* hr = h + (size_t)n * HD;
    float s = 0.f;
    #pragma unroll 4
    for (int i = 0; i < 64; ++i) {
        unsigned int hv = *(const unsigned int*)(hr + 2 * i);
        s += bf2f_lo(hv) * was[2 * i][j] + bf2f_hi(hv) * was[2 * i + 1][j];
    }
    if (j < 4) asrc[n * 4 + j] = s;
    else       adst[n * 4 + (j - 4)] = s;
}

// ---------------- per-edge softmax numerators + per-node inverse sums ----------------
__global__ __launch_bounds__(256) void alpha_k(
    const float* __restrict__ asrc, const float* __restrict__ adst,
    const int* __restrict__ rowptr, const int* __restrict__ csr,
    float* __restrict__ pexp, float* __restrict__ inv_s) {
    int wid = threadIdx.x >> 6, lane = threadIdx.x & 63;
    int n = blockIdx.x * 4 + wid;
    int r0 = rowptr[n], r1 = rowptr[n + 1];
    float4 ad = *(const float4*)(adst + n * 4);
    const float NINF = -__builtin_inff();
    float m0 = NINF, m1 = NINF, m2 = NINF, m3 = NINF;
    for (int base = r0; base < r1; base += 64) {
        int e = base + lane;
        if (e < r1) {
            int src = csr[e];
            float4 as = *(const float4*)(asrc + src * 4);
            m0 = fmaxf(m0, lk(as.x + ad.x));
            m1 = fmaxf(m1, lk(as.y + ad.y));
            m2 = fmaxf(m2, lk(as.z + ad.z));
            m3 = fmaxf(m3, lk(as.w + ad.w));
        }
    }
    #pragma unroll
    for (int o = 32; o; o >>= 1) {
        m0 = fmaxf(m0, __shfl_xor(m0, o));
        m1 = fmaxf(m1, __shfl_xor(m1, o));
        m2 = fmaxf(m2, __shfl_xor(m2, o));
        m3 = fmaxf(m3, __shfl_xor(m3, o));
    }
    float s0 = 0.f, s1 = 0.f, s2 = 0.f, s3 = 0.f;
    for (int base = r0; base < r1; base += 64) {
        int e = base + lane;
        if (e < r1) {
            int src = csr[e];
            float4 as = *(const float4*)(asrc + src * 4);
            float p0 = __expf(lk(as.x + ad.x) - m0);
            float p1 = __expf(lk(as.y + ad.y) - m1);
            float p2 = __expf(lk(as.z + ad.z) - m2);
            float p3 = __expf(lk(as.w + ad.w) - m3);
            s0 += p0; s1 += p1; s2 += p2; s3 += p3;
            *(float4*)(pexp + 4 * (size_t)e) = make_float4(p0, p1, p2, p3);
        }
    }
    #pragma unroll
    for (int o = 32; o; o >>= 1) {
        s0 += __shfl_xor(s0, o);
        s1 += __shfl_xor(s1, o);
        s2 += __shfl_xor(s2, o);
        s3 += __shfl_xor(s3, o);
    }
    if (lane == 0) {
        *(float4*)(inv_s + 4 * n) = make_float4(
            1.f / (s0 + 1e-16f), 1.f / (s1 + 1e-16f),
            1.f / (s2 + 1e-16f), 1.f / (s3 + 1e-16f));
    }
}

// ---------------- GAT gather: wave per node, 8 contiguous dims/lane ----------------
__global__ __launch_bounds__(256) void gat_agg2_k(
    const ushort_t* __restrict__ hg, const int* __restrict__ rowptr,
    const int* __restrict__ csr, const float* __restrict__ pexp,
    const float* __restrict__ inv_s, const float* __restrict__ Aa,
    const float* __restrict__ Ba, float* __restrict__ ofeat) {
    int wid = threadIdx.x >> 6, lane = threadIdx.x & 63;
    int n = blockIdx.x * 4 + wid;           // grid = NN/4 exactly
    int r0 = rowptr[n], r1 = rowptr[n + 1];
    int q = lane >> 4;
    int d0 = 8 * lane;
    float acc[8] = {0.f, 0.f, 0.f, 0.f, 0.f, 0.f, 0.f, 0.f};

    int src_n = csr[r0];
    float p_n = pexp[4 * (size_t)r0 + q];
    uint4 hv_n = *(const uint4*)(hg + (size_t)src_n * OD + d0);
    for (int e = r0; e < r1; ++e) {
        uint4 hv = hv_n;
        float p = p_n;
        int en = e + 1;
        if (en < r1) {
            int sn = csr[en];
            p_n = pexp[4 * (size_t)en + q];
            hv_n = *(const uint4*)(hg + (size_t)sn * OD + d0);
        }
        acc[0] = fmaf(p, bf2f_lo(hv.x), acc[0]);
        acc[1] = fmaf(p, bf2f_hi(hv.x), acc[1]);
        acc[2] = fmaf(p, bf2f_lo(hv.y), acc[2]);
        acc[3] = fmaf(p, bf2f_hi(hv.y), acc[3]);
        acc[4] = fmaf(p, bf2f_lo(hv.z), acc[4]);
        acc[5] = fmaf(p, bf2f_hi(hv.z), acc[5]);
        acc[6] = fmaf(p, bf2f_lo(hv.w), acc[6]);
        acc[7] = fmaf(p, bf2f_hi(hv.w), acc[7]);
    }
    float is = inv_s[4 * n + q];
    float4 A0 = *(const float4*)(Aa + d0);
    float4 A1 = *(const float4*)(Aa + d0 + 4);
    float4 B0 = *(const float4*)(Ba + d0);
    float4 B1 = *(const float4*)(Ba + d0 + 4);
    float4 o0, o1;
    o0.x = fmaxf(fmaf(acc[0] * is, A0.x, B0.x), 0.f);
    o0.y = fmaxf(fmaf(acc[1] * is, A0.y, B0.y), 0.f);
    o0.z = fmaxf(fmaf(acc[2] * is, A0.z, B0.z), 0.f);
    o0.w = fmaxf(fmaf(acc[3] * is, A0.w, B0.w), 0.f);
    o1.x = fmaxf(fmaf(acc[4] * is, A1.x, B1.x), 0.f);
    o1.y = fmaxf(fmaf(acc[5] * is, A1.y, B1.y), 0.f);
    o1.z = fmaxf(fmaf(acc[6] * is, A1.z, B1.z), 0.f);
    o1.w = fmaxf(fmaf(acc[7] * is, A1.w, B1.w), 0.f);
    float* orow = ofeat + (size_t)n * OD + d0;
    *(float4*)orow = o0;
    *(float4*)(orow + 4) = o1;
}

// ---------------- pooling: one block per graph ----------------
__global__ __launch_bounds__(256) void pool_k(const float* __restrict__ outfeat,
                                              const int* __restrict__ batch,
                                              float* __restrict__ feat) {
    int g = blockIdx.x;
    int lo = 0, hi = NN;
    while (lo < hi) { int mid = (lo + hi) >> 1; if (batch[mid] < g) lo = mid + 1; else hi = mid; }
    int start = lo;
    hi = NN;
    while (lo < hi) { int mid = (lo + hi) >> 1; if (batch[mid] < g + 1) lo = mid + 1; else hi = mid; }
    int end = lo;
    int cnt = end - start;
    for (int d = threadIdx.x; d < OD; d += 256) {
        float sadd = 0.f, smax = -3.402823466e38f;
        for (int i = start; i < end; ++i) {
            float v = outfeat[(size_t)i * OD + d];
            sadd += v;
            smax = fmaxf(smax, v);
        }
        float smean;
        if (cnt > 0) { smean = sadd / (float)cnt; }
        else { sadd = 0.f; smax = 0.f; smean = 0.f; }
        feat[g * 1536 + d] = sadd;
        feat[g * 1536 + 512 + d] = smax;
        feat[g * 1536 + 1024 + d] = smean;
    }
}

// ---------------- head: out = sigmoid(feat @ w_lin + b_lin) ----------------
__global__ __launch_bounds__(256) void head_k(const float* __restrict__ feat,
                                              const float* __restrict__ w_lin,
                                              const float* __restrict__ b_lin,
                                              float* __restrict__ out) {
    __shared__ float red[256];
    int g = blockIdx.x;
    int t = threadIdx.x;
    int o = t & 15, part = t >> 4;
    float s = 0.f;
    int kbeg = part * 96;
    for (int k = kbeg; k < kbeg + 96; ++k) s += feat[g * 1536 + k] * w_lin[k * 16 + o];
    red[t] = s;
    __syncthreads();
    if (t < 16) {
        float tot = b_lin[o];
        for (int p = 0; p < 16; ++p) tot += red[p * 16 + o];
        out[g * 16 + o] = 1.f / (1.f + __expf(-tot));
    }
}

extern "C" void kernel_launch(void* const* d_in, const int* in_sizes, int n_in,
                              void* d_out, int out_size, void* d_ws, size_t ws_size,
                              hipStream_t stream) {
    const float* x       = (const float*)d_in[0];
    const int*   ei      = (const int*)d_in[1];
    const int*   batch   = (const int*)d_in[2];
    const float* w_gcn   = (const float*)d_in[3];
    const float* b_gcn   = (const float*)d_in[4];
    const float* g2_gam  = (const float*)d_in[5];
    const float* g2_bet  = (const float*)d_in[6];
    const float* g2_mean = (const float*)d_in[7];
    const float* g2_var  = (const float*)d_in[8];
    const float* w_gat   = (const float*)d_in[9];
    const float* a_src   = (const float*)d_in[10];
    const float* a_dst   = (const float*)d_in[11];
    const float* b_gat   = (const float*)d_in[12];
    const float* g1_gam  = (const float*)d_in[13];
    const float* g1_bet  = (const float*)d_in[14];
    const float* g1_mean = (const float*)d_in[15];
    const float* g1_var  = (const float*)d_in[16];
    const float* w_lin   = (const float*)d_in[17];
    const float* b_lin   = (const float*)d_in[18];
    float* out = (float*)d_out;

    char* ws = (char*)d_ws;
    size_t off = 0;
    auto alloc = [&](size_t bytes) -> void* {
        void* p = ws + off;
        off += (bytes + 255) & ~(size_t)255;
        return p;
    };
    int* deg        = (int*)alloc((size_t)NN * 4);
    int* fill       = (int*)alloc((size_t)NN * 4);
    int* rowptr     = (int*)alloc((size_t)(NN + 1) * 4);
    int* csr        = (int*)alloc((size_t)NE2 * 4);
    float* dis      = (float*)alloc((size_t)NN * 4);
    ushort_t* xb    = (ushort_t*)alloc((size_t)NN * FD * 2);
    ushort_t* wgT   = (ushort_t*)alloc((size_t)FD * HD * 2);
    ushort_t* wgatT = (ushort_t*)alloc((size_t)HD * OD * 2);
    ushort_t* h0b   = (ushort_t*)alloc((size_t)NN * HD * 2);
    ushort_t* hb    = (ushort_t*)alloc((size_t)NN * HD * 2);
    ushort_t* hgb   = (ushort_t*)alloc((size_t)NN * OD * 2);
    float* asrc     = (float*)alloc((size_t)NN * 4 * 4);
    float* adst     = (float*)alloc((size_t)NN * 4 * 4);
    float* wa       = (float*)alloc((size_t)128 * 8 * 4);
    float* Ag       = (float*)alloc((size_t)HD * 4);
    float* Bg       = (float*)alloc((size_t)HD * 4);
    float* Aa       = (float*)alloc((size_t)OD * 4);
    float* Ba       = (float*)alloc((size_t)OD * 4);
    float* pexp     = (float*)alloc((size_t)NE2 * 4 * 4);
    float* inv_s    = (float*)alloc((size_t)NN * 4 * 4);
    float* ofeat    = (float*)alloc((size_t)NN * OD * 4);
    float* feat     = (float*)alloc((size_t)NG * 1536 * 4);

    // CSR build
    init_k<<<(NN + 255) / 256, 256, 0, stream>>>(deg, fill);
    count_k<<<(NE + 255) / 256, 256, 0, stream>>>(ei, deg);
    scan_k<<<1, 1024, 0, stream>>>(deg, rowptr);
    fill_k<<<(NE2 + 255) / 256, 256, 0, stream>>>(ei, rowptr, fill, csr);
    dis_k<<<(NN + 255) / 256, 256, 0, stream>>>(deg, dis);

    // BN affine params
    bnaff_k<<<3, 256, 0, stream>>>(b_gcn, g2_gam, g2_bet, g2_mean, g2_var,
                                   b_gat, g1_gam, g1_bet, g1_mean, g1_var,
                                   Ag, Bg, Aa, Ba);

    // casts: x -> bf16; weights -> transposed bf16
    cast_x_k<<<(NN * FD / 4 + 255) / 256, 256, 0, stream>>>(x, xb);
    trcast_k<<<(FD * HD + 255) / 256, 256, 0, stream>>>(w_gcn, wgT, FD, HD);
    trcast_k<<<(HD * OD + 255) / 256, 256, 0, stream>>>(w_gat, wgatT, HD, OD);

    // GCN linear: h0 = x @ w_gcn   (bf16 MFMA)
    gemm_bf16<<<dim3((NN + 127) / 128, HD / 64), 256, 0, stream>>>(xb, wgT, h0b, NN, HD);

    // attention weight pre-projection
    wa_k<<<4, 256, 0, stream>>>(w_gat, a_src, a_dst, wa);

    // GCN aggregate + BN2 + ReLU
    gcn_agg2_k<<<NN / 4, 256, 0, stream>>>(h0b, rowptr, csr, dis, Ag, Bg, hb);

    // asrc/adst projection
    attn_dots_k<<<(NN + 31) / 32, 256, 0, stream>>>(hb, wa, asrc, adst);

    // per-edge softmax numerators + per-node inverse sums
    alpha_k<<<NN / 4, 256, 0, stream>>>(asrc, adst, rowptr, csr, pexp, inv_s);

    // GAT linear: hg = h @ w_gat   (bf16 MFMA)
    gemm_bf16<<<dim3((NN + 127) / 128, OD / 64), 256, 0, stream>>>(hb, wgatT, hgb, NN, OD);

    // GAT weighted gather + BN1 + ReLU
    gat_agg2_k<<<NN / 4, 256, 0, stream>>>(hgb, rowptr, csr, pexp, inv_s, Aa, Ba, ofeat);

    // pooling
    pool_k<<<NG, 256, 0, stream>>>(ofeat, batch, feat);

    // head
    head_k<<<NG, 256, 0, stream>>>(feat, w_lin, b_lin, out);
}

// Round 4
// 499.794 us; speedup vs baseline: 1.5558x; 1.0714x over previous
//
#include <hip/hip_runtime.h>

#define NN 50000          // nodes
#define NE 800000         // edges (without self loops)
#define NE2 (NE + NN)     // edges + self loops
#define FD 128            // input feature dim
#define HD 128            // hidden dim
#define NHD 4             // heads
#define OD 512            // heads * HD
#define NG 512            // graphs
#define BN_EPS 1e-5f

typedef __attribute__((ext_vector_type(8))) short bfrag;   // 8 bf16 = 4 VGPRs
typedef __attribute__((ext_vector_type(4))) float f32x4;
typedef unsigned short ushort_t;

__device__ inline ushort_t f2bf(float f) {               // RNE fp32->bf16
    unsigned int u = __float_as_uint(f);
    unsigned int r = (u + 0x7fffu + ((u >> 16) & 1u)) >> 16;
    return (ushort_t)r;
}
__device__ inline float bf2f_lo(unsigned int v) { return __uint_as_float(v << 16); }
__device__ inline float bf2f_hi(unsigned int v) { return __uint_as_float(v & 0xffff0000u); }
__device__ inline float lk(float x) { return fmaxf(x, 0.2f * x); }   // leaky_relu 0.2

// ---------------- CSR build ----------------
__global__ void init_k(int* __restrict__ deg, int* __restrict__ fill) {
    int i = blockIdx.x * blockDim.x + threadIdx.x;
    if (i < NN) { deg[i] = 1; fill[i] = 0; }   // 1 = self loop
}

__global__ void count_k(const int* __restrict__ ei, int* __restrict__ deg) {
    int e = blockIdx.x * blockDim.x + threadIdx.x;
    if (e < NE) atomicAdd(&deg[ei[NE + e]], 1);
}

__global__ __launch_bounds__(1024) void scan_k(const int* __restrict__ deg,
                                               int* __restrict__ rowptr) {
    __shared__ int part[1024];
    int tid = threadIdx.x;
    const int chunk = (NN + 1023) / 1024;
    int beg = tid * chunk;
    int end = min(beg + chunk, NN);
    int s = 0;
    for (int i = beg; i < end; ++i) s += deg[i];
    part[tid] = s;
    __syncthreads();
    for (int off = 1; off < 1024; off <<= 1) {
        int v = (tid >= off) ? part[tid - off] : 0;
        __syncthreads();
        part[tid] += v;
        __syncthreads();
    }
    int run = (tid == 0) ? 0 : part[tid - 1];
    for (int i = beg; i < end; ++i) { rowptr[i] = run; run += deg[i]; }
    if (tid == 0) rowptr[NN] = part[1023];
}

__global__ void fill_k(const int* __restrict__ ei, const int* __restrict__ rowptr,
                       int* __restrict__ fill, int* __restrict__ csr) {
    int e = blockIdx.x * blockDim.x + threadIdx.x;
    if (e >= NE2) return;
    int src, dst;
    if (e < NE) { src = ei[e]; dst = ei[NE + e]; }
    else        { src = e - NE; dst = e - NE; }
    int pos = atomicAdd(&fill[dst], 1);
    csr[rowptr[dst] + pos] = src;
}

__global__ void dis_k(const int* __restrict__ deg, float* __restrict__ dis) {
    int i = blockIdx.x * blockDim.x + threadIdx.x;
    if (i < NN) dis[i] = rsqrtf((float)deg[i]);
}

// ---------------- BN -> affine precompute ----------------
__global__ void bnaff_k(const float* __restrict__ b_gcn, const float* __restrict__ g2_gam,
                        const float* __restrict__ g2_bet, const float* __restrict__ g2_mean,
                        const float* __restrict__ g2_var, const float* __restrict__ b_gat,
                        const float* __restrict__ g1_gam, const float* __restrict__ g1_bet,
                        const float* __restrict__ g1_mean, const float* __restrict__ g1_var,
                        float* __restrict__ Ag, float* __restrict__ Bg,
                        float* __restrict__ Aa, float* __restrict__ Ba) {
    int t = blockIdx.x * blockDim.x + threadIdx.x;
    if (t < HD) {
        float a = rsqrtf(g2_var[t] + BN_EPS) * g2_gam[t];
        Ag[t] = a;
        Bg[t] = (b_gcn[t] - g2_mean[t]) * a + g2_bet[t];
    } else if (t < HD + OD) {
        int d = t - HD;
        float a = rsqrtf(g1_var[d] + BN_EPS) * g1_gam[d];
        Aa[d] = a;
        Ba[d] = (b_gat[d] - g1_mean[d]) * a + g1_bet[d];
    }
}

// ---------------- casts ----------------
__global__ void cast_x_k(const float* __restrict__ x, ushort_t* __restrict__ xb) {
    int t = blockIdx.x * blockDim.x + threadIdx.x;      // one float4 per thread
    const int total = NN * FD / 4;
    if (t >= total) return;
    float4 v = ((const float4*)x)[t];
    ushort_t o[4] = {f2bf(v.x), f2bf(v.y), f2bf(v.z), f2bf(v.w)};
    *(unsigned long long*)(xb + 4 * t) = *(unsigned long long*)o;
}

// wT[n*K + k] = bf16(w[k*N + n])
__global__ void trcast_k(const float* __restrict__ w, ushort_t* __restrict__ wT,
                         int K, int N) {
    int t = blockIdx.x * blockDim.x + threadIdx.x;
    if (t >= K * N) return;
    int n = t / K, k = t - n * K;
    wT[n * K + k] = f2bf(w[k * N + n]);
}

// ---------------- bf16 MFMA GEMM: C[M,N] = A[M,128] @ B[128,N], C stored bf16
__global__ __launch_bounds__(256) void gemm_bf16(const ushort_t* __restrict__ A,
                                                 const ushort_t* __restrict__ BT,
                                                 ushort_t* __restrict__ C,
                                                 int M, int N) {
    __shared__ short As[128][136];
    __shared__ short Bs[64][136];
    const int tid = threadIdx.x;
    const int m0 = blockIdx.x * 128;
    const int n0 = blockIdx.y * 64;

    #pragma unroll
    for (int i = 0; i < 8; ++i) {
        int c = tid + 256 * i;
        int row = c >> 4, off = (c & 15) * 8;
        bfrag v = (bfrag)0;
        if (m0 + row < M) v = *(const bfrag*)(A + (size_t)(m0 + row) * 128 + off);
        *(bfrag*)&As[row][off] = v;
    }
    #pragma unroll
    for (int i = 0; i < 4; ++i) {
        int c = tid + 256 * i;
        int row = c >> 4, off = (c & 15) * 8;
        *(bfrag*)&Bs[row][off] = *(const bfrag*)(BT + (size_t)(n0 + row) * 128 + off);
    }
    __syncthreads();

    const int w = tid >> 6;
    const int lr = tid & 15;
    const int kg = (tid & 63) >> 4;

    f32x4 acc[2][4];
    #pragma unroll
    for (int mi = 0; mi < 2; ++mi)
        #pragma unroll
        for (int ni = 0; ni < 4; ++ni) acc[mi][ni] = (f32x4)0.f;

    #pragma unroll
    for (int ks = 0; ks < 4; ++ks) {
        bfrag af[2], bb[4];
        #pragma unroll
        for (int mi = 0; mi < 2; ++mi)
            af[mi] = *(const bfrag*)&As[32 * w + 16 * mi + lr][32 * ks + 8 * kg];
        #pragma unroll
        for (int ni = 0; ni < 4; ++ni)
            bb[ni] = *(const bfrag*)&Bs[16 * ni + lr][32 * ks + 8 * kg];
        #pragma unroll
        for (int mi = 0; mi < 2; ++mi)
            #pragma unroll
            for (int ni = 0; ni < 4; ++ni)
                acc[mi][ni] = __builtin_amdgcn_mfma_f32_16x16x32_bf16(
                    af[mi], bb[ni], acc[mi][ni], 0, 0, 0);
    }

    #pragma unroll
    for (int mi = 0; mi < 2; ++mi) {
        #pragma unroll
        for (int r = 0; r < 4; ++r) {
            int row = m0 + 32 * w + 16 * mi + 4 * kg + r;
            if (row < M) {
                #pragma unroll
                for (int ni = 0; ni < 4; ++ni) {
                    int col = n0 + 16 * ni + lr;
                    C[(size_t)row * N + col] = f2bf(acc[mi][ni][r]);
                }
            }
        }
    }
}

// ---------------- precompute wa[k][j]: j<4 -> w_gat col-block . a_src[head] ----------------
__global__ void wa_k(const float* __restrict__ w_gat, const float* __restrict__ a_src,
                     const float* __restrict__ a_dst, float* __restrict__ wa) {
    int t = blockIdx.x * blockDim.x + threadIdx.x;
    if (t >= 128 * 8) return;
    int k = t >> 3, j = t & 7, head = j & 3;
    const float* av = (j < 4 ? a_src : a_dst) + head * 128;
    const float* w = w_gat + (size_t)k * OD + head * 128;
    float s = 0.f;
    for (int d = 0; d < 128; ++d) s += w[d] * av[d];
    wa[k * 8 + j] = s;
}

// ---------------- GCN aggregate: wave per node, 2 dims/lane, 8-deep pipeline ----------------
__global__ __launch_bounds__(256) void gcn_agg2_k(
    const ushort_t* __restrict__ h0, const int* __restrict__ rowptr,
    const int* __restrict__ csr, const float* __restrict__ dis,
    const float* __restrict__ Ag, const float* __restrict__ Bg,
    ushort_t* __restrict__ h) {
    int wid = threadIdx.x >> 6, lane = threadIdx.x & 63;
    int n = blockIdx.x * 4 + wid;           // grid = NN/4 exactly
    int r0 = rowptr[n], r1 = rowptr[n + 1];
    int d = 2 * lane;
    float a0 = 0.f, a1 = 0.f;

    unsigned int v0 = 0, v1 = 0, v2 = 0, v3 = 0, v4 = 0, v5 = 0, v6 = 0, v7 = 0;
    float w0, w1, w2, w3, w4, w5, w6, w7;

#define GLOAD(V, W, IDX) { int _i = (IDX); W = 0.f; \
    if (_i < r1) { int _s = csr[_i]; W = dis[_s]; \
        V = *(const unsigned int*)(h0 + (size_t)_s * HD + d); } }
#define GACC(V, W) { a0 = fmaf(W, bf2f_lo(V), a0); a1 = fmaf(W, bf2f_hi(V), a1); }

    GLOAD(v0, w0, r0 + 0) GLOAD(v1, w1, r0 + 1) GLOAD(v2, w2, r0 + 2) GLOAD(v3, w3, r0 + 3)
    GLOAD(v4, w4, r0 + 4) GLOAD(v5, w5, r0 + 5) GLOAD(v6, w6, r0 + 6) GLOAD(v7, w7, r0 + 7)
    for (int base = r0; base < r1; base += 8) {
        GACC(v0, w0) GLOAD(v0, w0, base + 8)
        GACC(v1, w1) GLOAD(v1, w1, base + 9)
        GACC(v2, w2) GLOAD(v2, w2, base + 10)
        GACC(v3, w3) GLOAD(v3, w3, base + 11)
        GACC(v4, w4) GLOAD(v4, w4, base + 12)
        GACC(v5, w5) GLOAD(v5, w5, base + 13)
        GACC(v6, w6) GLOAD(v6, w6, base + 14)
        GACC(v7, w7) GLOAD(v7, w7, base + 15)
    }
#undef GLOAD
#undef GACC

    float t = dis[n];
    float2 A = *(const float2*)(Ag + d);
    float2 B = *(const float2*)(Bg + d);
    float o0 = fmaxf(fmaf(a0 * t, A.x, B.x), 0.f);
    float o1 = fmaxf(fmaf(a1 * t, A.y, B.y), 0.f);
    unsigned int packed = (unsigned int)f2bf(o0) | ((unsigned int)f2bf(o1) << 16);
    *(unsigned int*)(h + (size_t)n * HD + d) = packed;
}

// ---------------- asrc/adst: [N,128] @ wa[128,8] ----------------
__global__ __launch_bounds__(256) void attn_dots_k(const ushort_t* __restrict__ h,
                                                   const float* __restrict__ wa,
                                                   float* __restrict__ asrc,
                                                   float* __restrict__ adst) {
    __shared__ float was[128][8];
    int tid = threadIdx.x;
    for (int i = tid; i < 1024; i += 256) was[i >> 3][i & 7] = wa[i];
    __syncthreads();
    int nl = tid >> 3, j = tid & 7;
    int n = blockIdx.x * 32 + nl;
    if (n >= NN) return;
    const ushort_t* hr = h + (size_t)n * HD;
    float s = 0.f;
    #pragma unroll 4
    for (int i = 0; i < 64; ++i) {
        unsigned int hv = *(const unsigned int*)(hr + 2 * i);
        s += bf2f_lo(hv) * was[2 * i][j] + bf2f_hi(hv) * was[2 * i + 1][j];
    }
    if (j < 4) asrc[n * 4 + j] = s;
    else       adst[n * 4 + (j - 4)] = s;
}

// ---------------- per-edge softmax numerators + per-node inverse sums ----------------
__global__ __launch_bounds__(256) void alpha_k(
    const float* __restrict__ asrc, const float* __restrict__ adst,
    const int* __restrict__ rowptr, const int* __restrict__ csr,
    float* __restrict__ pexp, float* __restrict__ inv_s) {
    int wid = threadIdx.x >> 6, lane = threadIdx.x & 63;
    int n = blockIdx.x * 4 + wid;
    int r0 = rowptr[n], r1 = rowptr[n + 1];
    float4 ad = *(const float4*)(adst + n * 4);
    const float NINF = -__builtin_inff();
    float m0 = NINF, m1 = NINF, m2 = NINF, m3 = NINF;
    for (int base = r0; base < r1; base += 64) {
        int e = base + lane;
        if (e < r1) {
            int src = csr[e];
            float4 as = *(const float4*)(asrc + src * 4);
            m0 = fmaxf(m0, lk(as.x + ad.x));
            m1 = fmaxf(m1, lk(as.y + ad.y));
            m2 = fmaxf(m2, lk(as.z + ad.z));
            m3 = fmaxf(m3, lk(as.w + ad.w));
        }
    }
    #pragma unroll
    for (int o = 32; o; o >>= 1) {
        m0 = fmaxf(m0, __shfl_xor(m0, o));
        m1 = fmaxf(m1, __shfl_xor(m1, o));
        m2 = fmaxf(m2, __shfl_xor(m2, o));
        m3 = fmaxf(m3, __shfl_xor(m3, o));
    }
    float s0 = 0.f, s1 = 0.f, s2 = 0.f, s3 = 0.f;
    for (int base = r0; base < r1; base += 64) {
        int e = base + lane;
        if (e < r1) {
            int src = csr[e];
            float4 as = *(const float4*)(asrc + src * 4);
            float p0 = __expf(lk(as.x + ad.x) - m0);
            float p1 = __expf(lk(as.y + ad.y) - m1);
            float p2 = __expf(lk(as.z + ad.z) - m2);
            float p3 = __expf(lk(as.w + ad.w) - m3);
            s0 += p0; s1 += p1; s2 += p2; s3 += p3;
            *(float4*)(pexp + 4 * (size_t)e) = make_float4(p0, p1, p2, p3);
        }
    }
    #pragma unroll
    for (int o = 32; o; o >>= 1) {
        s0 += __shfl_xor(s0, o);
        s1 += __shfl_xor(s1, o);
        s2 += __shfl_xor(s2, o);
        s3 += __shfl_xor(s3, o);
    }
    if (lane == 0) {
        *(float4*)(inv_s + 4 * n) = make_float4(
            1.f / (s0 + 1e-16f), 1.f / (s1 + 1e-16f),
            1.f / (s2 + 1e-16f), 1.f / (s3 + 1e-16f));
    }
}

// ---------------- GAT gather: wave per node, 8 dims/lane, 4-deep pipeline ----------------
__global__ __launch_bounds__(256) void gat_agg2_k(
    const ushort_t* __restrict__ hg, const int* __restrict__ rowptr,
    const int* __restrict__ csr, const float* __restrict__ pexp,
    const float* __restrict__ inv_s, const float* __restrict__ Aa,
    const float* __restrict__ Ba, float* __restrict__ ofeat) {
    int wid = threadIdx.x >> 6, lane = threadIdx.x & 63;
    int n = blockIdx.x * 4 + wid;           // grid = NN/4 exactly
    int r0 = rowptr[n], r1 = rowptr[n + 1];
    int q = lane >> 4;
    int d0 = 8 * lane;
    float acc[8] = {0.f, 0.f, 0.f, 0.f, 0.f, 0.f, 0.f, 0.f};

    uint4 hv0 = {0,0,0,0}, hv1 = {0,0,0,0}, hv2 = {0,0,0,0}, hv3 = {0,0,0,0};
    float p0, p1, p2, p3;

#define ALOAD(HV, P, IDX) { int _i = (IDX); P = 0.f; \
    if (_i < r1) { int _s = csr[_i]; P = pexp[4 * (size_t)_i + q]; \
        HV = *(const uint4*)(hg + (size_t)_s * OD + d0); } }
#define AACC(HV, P) { \
    acc[0] = fmaf(P, bf2f_lo(HV.x), acc[0]); \
    acc[1] = fmaf(P, bf2f_hi(HV.x), acc[1]); \
    acc[2] = fmaf(P, bf2f_lo(HV.y), acc[2]); \
    acc[3] = fmaf(P, bf2f_hi(HV.y), acc[3]); \
    acc[4] = fmaf(P, bf2f_lo(HV.z), acc[4]); \
    acc[5] = fmaf(P, bf2f_hi(HV.z), acc[5]); \
    acc[6] = fmaf(P, bf2f_lo(HV.w), acc[6]); \
    acc[7] = fmaf(P, bf2f_hi(HV.w), acc[7]); }

    ALOAD(hv0, p0, r0 + 0) ALOAD(hv1, p1, r0 + 1)
    ALOAD(hv2, p2, r0 + 2) ALOAD(hv3, p3, r0 + 3)
    for (int base = r0; base < r1; base += 4) {
        AACC(hv0, p0) ALOAD(hv0, p0, base + 4)
        AACC(hv1, p1) ALOAD(hv1, p1, base + 5)
        AACC(hv2, p2) ALOAD(hv2, p2, base + 6)
        AACC(hv3, p3) ALOAD(hv3, p3, base + 7)
    }
#undef ALOAD
#undef AACC

    float is = inv_s[4 * n + q];
    float4 A0 = *(const float4*)(Aa + d0);
    float4 A1 = *(const float4*)(Aa + d0 + 4);
    float4 B0 = *(const float4*)(Ba + d0);
    float4 B1 = *(const float4*)(Ba + d0 + 4);
    float4 o0, o1;
    o0.x = fmaxf(fmaf(acc[0] * is, A0.x, B0.x), 0.f);
    o0.y = fmaxf(fmaf(acc[1] * is, A0.y, B0.y), 0.f);
    o0.z = fmaxf(fmaf(acc[2] * is, A0.z, B0.z), 0.f);
    o0.w = fmaxf(fmaf(acc[3] * is, A0.w, B0.w), 0.f);
    o1.x = fmaxf(fmaf(acc[4] * is, A1.x, B1.x), 0.f);
    o1.y = fmaxf(fmaf(acc[5] * is, A1.y, B1.y), 0.f);
    o1.z = fmaxf(fmaf(acc[6] * is, A1.z, B1.z), 0.f);
    o1.w = fmaxf(fmaf(acc[7] * is, A1.w, B1.w), 0.f);
    float* orow = ofeat + (size_t)n * OD + d0;
    *(float4*)orow = o0;
    *(float4*)(orow + 4) = o1;
}

// ---------------- pooling: one (graph, 256-dim half) per block ----------------
__global__ __launch_bounds__(256) void pool_k(const float* __restrict__ outfeat,
                                              const int* __restrict__ batch,
                                              float* __restrict__ feat) {
    int g = blockIdx.x;
    int d = blockIdx.y * 256 + threadIdx.x;
    int lo = 0, hi = NN;
    while (lo < hi) { int mid = (lo + hi) >> 1; if (batch[mid] < g) lo = mid + 1; else hi = mid; }
    int start = lo;
    hi = NN;
    while (lo < hi) { int mid = (lo + hi) >> 1; if (batch[mid] < g + 1) lo = mid + 1; else hi = mid; }
    int end = lo;
    int cnt = end - start;
    float sadd = 0.f, smax = -3.402823466e38f;
    for (int i = start; i < end; ++i) {
        float v = outfeat[(size_t)i * OD + d];
        sadd += v;
        smax = fmaxf(smax, v);
    }
    float smean;
    if (cnt > 0) { smean = sadd / (float)cnt; }
    else { sadd = 0.f; smax = 0.f; smean = 0.f; }
    feat[g * 1536 + d] = sadd;
    feat[g * 1536 + 512 + d] = smax;
    feat[g * 1536 + 1024 + d] = smean;
}

// ---------------- head: out = sigmoid(feat @ w_lin + b_lin) ----------------
__global__ __launch_bounds__(256) void head_k(const float* __restrict__ feat,
                                              const float* __restrict__ w_lin,
                                              const float* __restrict__ b_lin,
                                              float* __restrict__ out) {
    __shared__ float red[256];
    int g = blockIdx.x;
    int t = threadIdx.x;
    int o = t & 15, part = t >> 4;
    float s = 0.f;
    int kbeg = part * 96;
    for (int k = kbeg; k < kbeg + 96; ++k) s += feat[g * 1536 + k] * w_lin[k * 16 + o];
    red[t] = s;
    __syncthreads();
    if (t < 16) {
        float tot = b_lin[o];
        for (int p = 0; p < 16; ++p) tot += red[p * 16 + o];
        out[g * 16 + o] = 1.f / (1.f + __expf(-tot));
    }
}

extern "C" void kernel_launch(void* const* d_in, const int* in_sizes, int n_in,
                              void* d_out, int out_size, void* d_ws, size_t ws_size,
                              hipStream_t stream) {
    const float* x       = (const float*)d_in[0];
    const int*   ei      = (const int*)d_in[1];
    const int*   batch   = (const int*)d_in[2];
    const float* w_gcn   = (const float*)d_in[3];
    const float* b_gcn   = (const float*)d_in[4];
    const float* g2_gam  = (const float*)d_in[5];
    const float* g2_bet  = (const float*)d_in[6];
    const float* g2_mean = (const float*)d_in[7];
    const float* g2_var  = (const float*)d_in[8];
    const float* w_gat   = (const float*)d_in[9];
    const float* a_src   = (const float*)d_in[10];
    const float* a_dst   = (const float*)d_in[11];
    const float* b_gat   = (const float*)d_in[12];
    const float* g1_gam  = (const float*)d_in[13];
    const float* g1_bet  = (const float*)d_in[14];
    const float* g1_mean = (const float*)d_in[15];
    const float* g1_var  = (const float*)d_in[16];
    const float* w_lin   = (const float*)d_in[17];
    const float* b_lin   = (const float*)d_in[18];
    float* out = (float*)d_out;

    char* ws = (char*)d_ws;
    size_t off = 0;
    auto alloc = [&](size_t bytes) -> void* {
        void* p = ws + off;
        off += (bytes + 255) & ~(size_t)255;
        return p;
    };
    int* deg        = (int*)alloc((size_t)NN * 4);
    int* fill       = (int*)alloc((size_t)NN * 4);
    int* rowptr     = (int*)alloc((size_t)(NN + 1) * 4);
    int* csr        = (int*)alloc((size_t)NE2 * 4);
    float* dis      = (float*)alloc((size_t)NN * 4);
    ushort_t* xb    = (ushort_t*)alloc((size_t)NN * FD * 2);
    ushort_t* wgT   = (ushort_t*)alloc((size_t)FD * HD * 2);
    ushort_t* wgatT = (ushort_t*)alloc((size_t)HD * OD * 2);
    ushort_t* h0b   = (ushort_t*)alloc((size_t)NN * HD * 2);
    ushort_t* hb    = (ushort_t*)alloc((size_t)NN * HD * 2);
    ushort_t* hgb   = (ushort_t*)alloc((size_t)NN * OD * 2);
    float* asrc     = (float*)alloc((size_t)NN * 4 * 4);
    float* adst     = (float*)alloc((size_t)NN * 4 * 4);
    float* wa       = (float*)alloc((size_t)128 * 8 * 4);
    float* Ag       = (float*)alloc((size_t)HD * 4);
    float* Bg       = (float*)alloc((size_t)HD * 4);
    float* Aa       = (float*)alloc((size_t)OD * 4);
    float* Ba       = (float*)alloc((size_t)OD * 4);
    float* pexp     = (float*)alloc((size_t)NE2 * 4 * 4);
    float* inv_s    = (float*)alloc((size_t)NN * 4 * 4);
    float* ofeat    = (float*)alloc((size_t)NN * OD * 4);
    float* feat     = (float*)alloc((size_t)NG * 1536 * 4);

    // CSR build
    init_k<<<(NN + 255) / 256, 256, 0, stream>>>(deg, fill);
    count_k<<<(NE + 255) / 256, 256, 0, stream>>>(ei, deg);
    scan_k<<<1, 1024, 0, stream>>>(deg, rowptr);
    fill_k<<<(NE2 + 255) / 256, 256, 0, stream>>>(ei, rowptr, fill, csr);
    dis_k<<<(NN + 255) / 256, 256, 0, stream>>>(deg, dis);

    // BN affine params
    bnaff_k<<<3, 256, 0, stream>>>(b_gcn, g2_gam, g2_bet, g2_mean, g2_var,
                                   b_gat, g1_gam, g1_bet, g1_mean, g1_var,
                                   Ag, Bg, Aa, Ba);

    // casts: x -> bf16; weights -> transposed bf16
    cast_x_k<<<(NN * FD / 4 + 255) / 256, 256, 0, stream>>>(x, xb);
    trcast_k<<<(FD * HD + 255) / 256, 256, 0, stream>>>(w_gcn, wgT, FD, HD);
    trcast_k<<<(HD * OD + 255) / 256, 256, 0, stream>>>(w_gat, wgatT, HD, OD);

    // GCN linear: h0 = x @ w_gcn   (bf16 MFMA)
    gemm_bf16<<<dim3((NN + 127) / 128, HD / 64), 256, 0, stream>>>(xb, wgT, h0b, NN, HD);

    // attention weight pre-projection
    wa_k<<<4, 256, 0, stream>>>(w_gat, a_src, a_dst, wa);

    // GCN aggregate + BN2 + ReLU
    gcn_agg2_k<<<NN / 4, 256, 0, stream>>>(h0b, rowptr, csr, dis, Ag, Bg, hb);

    // asrc/adst projection
    attn_dots_k<<<(NN + 31) / 32, 256, 0, stream>>>(hb, wa, asrc, adst);

    // per-edge softmax numerators + per-node inverse sums
    alpha_k<<<NN / 4, 256, 0, stream>>>(asrc, adst, rowptr, csr, pexp, inv_s);

    // GAT linear: hg = h @ w_gat   (bf16 MFMA)
    gemm_bf16<<<dim3((NN + 127) / 128, OD / 64), 256, 0, stream>>>(hb, wgatT, hgb, NN, OD);

    // GAT weighted gather + BN1 + ReLU
    gat_agg2_k<<<NN / 4, 256, 0, stream>>>(hgb, rowptr, csr, pexp, inv_s, Aa, Ba, ofeat);

    // pooling
    pool_k<<<dim3(NG, 2), 256, 0, stream>>>(ofeat, batch, feat);

    // head
    head_k<<<NG, 256, 0, stream>>>(feat, w_lin, b_lin, out);
}

// Round 5
// 483.506 us; speedup vs baseline: 1.6082x; 1.0337x over previous
//
#include <hip/hip_runtime.h>

#define NN 50000          // nodes
#define NE 800000         // edges (without self loops)
#define NE2 (NE + NN)     // edges + self loops
#define FD 128            // input feature dim
#define HD 128            // hidden dim
#define NHD 4             // heads
#define OD 512            // heads * HD
#define NG 512            // graphs
#define BN_EPS 1e-5f

typedef __attribute__((ext_vector_type(8))) short bfrag;   // 8 bf16 = 4 VGPRs
typedef __attribute__((ext_vector_type(4))) float f32x4;
typedef unsigned short ushort_t;

__device__ inline ushort_t f2bf(float f) {               // RNE fp32->bf16
    unsigned int u = __float_as_uint(f);
    unsigned int r = (u + 0x7fffu + ((u >> 16) & 1u)) >> 16;
    return (ushort_t)r;
}
__device__ inline float bf2f_lo(unsigned int v) { return __uint_as_float(v << 16); }
__device__ inline float bf2f_hi(unsigned int v) { return __uint_as_float(v & 0xffff0000u); }
__device__ inline float lk(float x) { return fmaxf(x, 0.2f * x); }   // leaky_relu 0.2

// ---------------- CSR build ----------------
__global__ void init_k(int* __restrict__ deg, int* __restrict__ fill) {
    int i = blockIdx.x * blockDim.x + threadIdx.x;
    if (i < NN) { deg[i] = 1; fill[i] = 0; }   // 1 = self loop
}

__global__ void count_k(const int* __restrict__ ei, int* __restrict__ deg) {
    int e = blockIdx.x * blockDim.x + threadIdx.x;
    if (e < NE) atomicAdd(&deg[ei[NE + e]], 1);
}

__global__ __launch_bounds__(1024) void scan_k(const int* __restrict__ deg,
                                               int* __restrict__ rowptr) {
    __shared__ int part[1024];
    int tid = threadIdx.x;
    const int chunk = (NN + 1023) / 1024;
    int beg = tid * chunk;
    int end = min(beg + chunk, NN);
    int s = 0;
    for (int i = beg; i < end; ++i) s += deg[i];
    part[tid] = s;
    __syncthreads();
    for (int off = 1; off < 1024; off <<= 1) {
        int v = (tid >= off) ? part[tid - off] : 0;
        __syncthreads();
        part[tid] += v;
        __syncthreads();
    }
    int run = (tid == 0) ? 0 : part[tid - 1];
    for (int i = beg; i < end; ++i) { rowptr[i] = run; run += deg[i]; }
    if (tid == 0) rowptr[NN] = part[1023];
}

__global__ void fill_k(const int* __restrict__ ei, const int* __restrict__ rowptr,
                       int* __restrict__ fill, int* __restrict__ csr) {
    int e = blockIdx.x * blockDim.x + threadIdx.x;
    if (e >= NE2) return;
    int src, dst;
    if (e < NE) { src = ei[e]; dst = ei[NE + e]; }
    else        { src = e - NE; dst = e - NE; }
    int pos = atomicAdd(&fill[dst], 1);
    csr[rowptr[dst] + pos] = src;
}

__global__ void dis_k(const int* __restrict__ deg, float* __restrict__ dis) {
    int i = blockIdx.x * blockDim.x + threadIdx.x;
    if (i < NN) dis[i] = rsqrtf((float)deg[i]);
}

// ---------------- BN -> affine precompute ----------------
__global__ void bnaff_k(const float* __restrict__ b_gcn, const float* __restrict__ g2_gam,
                        const float* __restrict__ g2_bet, const float* __restrict__ g2_mean,
                        const float* __restrict__ g2_var, const float* __restrict__ b_gat,
                        const float* __restrict__ g1_gam, const float* __restrict__ g1_bet,
                        const float* __restrict__ g1_mean, const float* __restrict__ g1_var,
                        float* __restrict__ Ag, float* __restrict__ Bg,
                        float* __restrict__ Aa, float* __restrict__ Ba) {
    int t = blockIdx.x * blockDim.x + threadIdx.x;
    if (t < HD) {
        float a = rsqrtf(g2_var[t] + BN_EPS) * g2_gam[t];
        Ag[t] = a;
        Bg[t] = (b_gcn[t] - g2_mean[t]) * a + g2_bet[t];
    } else if (t < HD + OD) {
        int d = t - HD;
        float a = rsqrtf(g1_var[d] + BN_EPS) * g1_gam[d];
        Aa[d] = a;
        Ba[d] = (b_gat[d] - g1_mean[d]) * a + g1_bet[d];
    }
}

// ---------------- casts ----------------
__global__ void cast_x_k(const float* __restrict__ x, ushort_t* __restrict__ xb) {
    int t = blockIdx.x * blockDim.x + threadIdx.x;      // one float4 per thread
    const int total = NN * FD / 4;
    if (t >= total) return;
    float4 v = ((const float4*)x)[t];
    ushort_t o[4] = {f2bf(v.x), f2bf(v.y), f2bf(v.z), f2bf(v.w)};
    *(unsigned long long*)(xb + 4 * t) = *(unsigned long long*)o;
}

// wT[n*K + k] = bf16(w[k*N + n])
__global__ void trcast_k(const float* __restrict__ w, ushort_t* __restrict__ wT,
                         int K, int N) {
    int t = blockIdx.x * blockDim.x + threadIdx.x;
    if (t >= K * N) return;
    int n = t / K, k = t - n * K;
    wT[n * K + k] = f2bf(w[k * N + n]);
}

// ---------------- bf16 MFMA GEMM: C[M,N] = A[M,128] @ B[128,N], C stored bf16
__global__ __launch_bounds__(256) void gemm_bf16(const ushort_t* __restrict__ A,
                                                 const ushort_t* __restrict__ BT,
                                                 ushort_t* __restrict__ C,
                                                 int M, int N) {
    __shared__ short As[128][136];
    __shared__ short Bs[64][136];
    const int tid = threadIdx.x;
    const int m0 = blockIdx.x * 128;
    const int n0 = blockIdx.y * 64;

    #pragma unroll
    for (int i = 0; i < 8; ++i) {
        int c = tid + 256 * i;
        int row = c >> 4, off = (c & 15) * 8;
        bfrag v = (bfrag)0;
        if (m0 + row < M) v = *(const bfrag*)(A + (size_t)(m0 + row) * 128 + off);
        *(bfrag*)&As[row][off] = v;
    }
    #pragma unroll
    for (int i = 0; i < 4; ++i) {
        int c = tid + 256 * i;
        int row = c >> 4, off = (c & 15) * 8;
        *(bfrag*)&Bs[row][off] = *(const bfrag*)(BT + (size_t)(n0 + row) * 128 + off);
    }
    __syncthreads();

    const int w = tid >> 6;
    const int lr = tid & 15;
    const int kg = (tid & 63) >> 4;

    f32x4 acc[2][4];
    #pragma unroll
    for (int mi = 0; mi < 2; ++mi)
        #pragma unroll
        for (int ni = 0; ni < 4; ++ni) acc[mi][ni] = (f32x4)0.f;

    #pragma unroll
    for (int ks = 0; ks < 4; ++ks) {
        bfrag af[2], bb[4];
        #pragma unroll
        for (int mi = 0; mi < 2; ++mi)
            af[mi] = *(const bfrag*)&As[32 * w + 16 * mi + lr][32 * ks + 8 * kg];
        #pragma unroll
        for (int ni = 0; ni < 4; ++ni)
            bb[ni] = *(const bfrag*)&Bs[16 * ni + lr][32 * ks + 8 * kg];
        #pragma unroll
        for (int mi = 0; mi < 2; ++mi)
            #pragma unroll
            for (int ni = 0; ni < 4; ++ni)
                acc[mi][ni] = __builtin_amdgcn_mfma_f32_16x16x32_bf16(
                    af[mi], bb[ni], acc[mi][ni], 0, 0, 0);
    }

    #pragma unroll
    for (int mi = 0; mi < 2; ++mi) {
        #pragma unroll
        for (int r = 0; r < 4; ++r) {
            int row = m0 + 32 * w + 16 * mi + 4 * kg + r;
            if (row < M) {
                #pragma unroll
                for (int ni = 0; ni < 4; ++ni) {
                    int col = n0 + 16 * ni + lr;
                    C[(size_t)row * N + col] = f2bf(acc[mi][ni][r]);
                }
            }
        }
    }
}

// ---------------- per-head GEMM: ofeat[:,128h:128h+128] = relu(BN(z_h @ W_h)) ----------------
// A = zb + head*NN*HD (bf16 [NN,128], already scaled by inv_s)
// BT = wgatT + head*128*128 (rows = out-cols of this head)
__global__ __launch_bounds__(256) void gemm_z_k(const ushort_t* __restrict__ zb,
                                                const ushort_t* __restrict__ wgatT,
                                                const float* __restrict__ Aa,
                                                const float* __restrict__ Ba,
                                                float* __restrict__ ofeat) {
    __shared__ short As[128][136];
    __shared__ short Bs[64][136];
    const int tid = threadIdx.x;
    const int head = blockIdx.z;
    const int m0 = blockIdx.x * 128;
    const int n0 = blockIdx.y * 64;
    const ushort_t* A = zb + (size_t)head * NN * HD;
    const ushort_t* BT = wgatT + (size_t)head * HD * HD;

    #pragma unroll
    for (int i = 0; i < 8; ++i) {
        int c = tid + 256 * i;
        int row = c >> 4, off = (c & 15) * 8;
        bfrag v = (bfrag)0;
        if (m0 + row < NN) v = *(const bfrag*)(A + (size_t)(m0 + row) * HD + off);
        *(bfrag*)&As[row][off] = v;
    }
    #pragma unroll
    for (int i = 0; i < 4; ++i) {
        int c = tid + 256 * i;
        int row = c >> 4, off = (c & 15) * 8;
        *(bfrag*)&Bs[row][off] = *(const bfrag*)(BT + (size_t)(n0 + row) * HD + off);
    }
    __syncthreads();

    const int w = tid >> 6;
    const int lr = tid & 15;
    const int kg = (tid & 63) >> 4;

    f32x4 acc[2][4];
    #pragma unroll
    for (int mi = 0; mi < 2; ++mi)
        #pragma unroll
        for (int ni = 0; ni < 4; ++ni) acc[mi][ni] = (f32x4)0.f;

    #pragma unroll
    for (int ks = 0; ks < 4; ++ks) {
        bfrag af[2], bb[4];
        #pragma unroll
        for (int mi = 0; mi < 2; ++mi)
            af[mi] = *(const bfrag*)&As[32 * w + 16 * mi + lr][32 * ks + 8 * kg];
        #pragma unroll
        for (int ni = 0; ni < 4; ++ni)
            bb[ni] = *(const bfrag*)&Bs[16 * ni + lr][32 * ks + 8 * kg];
        #pragma unroll
        for (int mi = 0; mi < 2; ++mi)
            #pragma unroll
            for (int ni = 0; ni < 4; ++ni)
                acc[mi][ni] = __builtin_amdgcn_mfma_f32_16x16x32_bf16(
                    af[mi], bb[ni], acc[mi][ni], 0, 0, 0);
    }

    #pragma unroll
    for (int mi = 0; mi < 2; ++mi) {
        #pragma unroll
        for (int r = 0; r < 4; ++r) {
            int row = m0 + 32 * w + 16 * mi + 4 * kg + r;
            if (row < NN) {
                #pragma unroll
                for (int ni = 0; ni < 4; ++ni) {
                    int gc = 128 * head + n0 + 16 * ni + lr;
                    float v = fmaf(acc[mi][ni][r], Aa[gc], Ba[gc]);
                    ofeat[(size_t)row * OD + gc] = fmaxf(v, 0.f);
                }
            }
        }
    }
}

// ---------------- precompute wa[k][j]: j<4 -> w_gat col-block . a_src[head] ----------------
__global__ void wa_k(const float* __restrict__ w_gat, const float* __restrict__ a_src,
                     const float* __restrict__ a_dst, float* __restrict__ wa) {
    int t = blockIdx.x * blockDim.x + threadIdx.x;
    if (t >= 128 * 8) return;
    int k = t >> 3, j = t & 7, head = j & 3;
    const float* av = (j < 4 ? a_src : a_dst) + head * 128;
    const float* w = w_gat + (size_t)k * OD + head * 128;
    float s = 0.f;
    for (int d = 0; d < 128; ++d) s += w[d] * av[d];
    wa[k * 8 + j] = s;
}

// ---------------- GCN aggregate: wave per node, 2 dims/lane, 8-deep pipeline ----------------
__global__ __launch_bounds__(256) void gcn_agg2_k(
    const ushort_t* __restrict__ h0, const int* __restrict__ rowptr,
    const int* __restrict__ csr, const float* __restrict__ dis,
    const float* __restrict__ Ag, const float* __restrict__ Bg,
    ushort_t* __restrict__ h) {
    int wid = threadIdx.x >> 6, lane = threadIdx.x & 63;
    int n = blockIdx.x * 4 + wid;           // grid = NN/4 exactly
    int r0 = rowptr[n], r1 = rowptr[n + 1];
    int d = 2 * lane;
    float a0 = 0.f, a1 = 0.f;

    unsigned int v0 = 0, v1 = 0, v2 = 0, v3 = 0, v4 = 0, v5 = 0, v6 = 0, v7 = 0;
    float w0, w1, w2, w3, w4, w5, w6, w7;

#define GLOAD(V, W, IDX) { int _i = (IDX); W = 0.f; \
    if (_i < r1) { int _s = csr[_i]; W = dis[_s]; \
        V = *(const unsigned int*)(h0 + (size_t)_s * HD + d); } }
#define GACC(V, W) { a0 = fmaf(W, bf2f_lo(V), a0); a1 = fmaf(W, bf2f_hi(V), a1); }

    GLOAD(v0, w0, r0 + 0) GLOAD(v1, w1, r0 + 1) GLOAD(v2, w2, r0 + 2) GLOAD(v3, w3, r0 + 3)
    GLOAD(v4, w4, r0 + 4) GLOAD(v5, w5, r0 + 5) GLOAD(v6, w6, r0 + 6) GLOAD(v7, w7, r0 + 7)
    for (int base = r0; base < r1; base += 8) {
        GACC(v0, w0) GLOAD(v0, w0, base + 8)
        GACC(v1, w1) GLOAD(v1, w1, base + 9)
        GACC(v2, w2) GLOAD(v2, w2, base + 10)
        GACC(v3, w3) GLOAD(v3, w3, base + 11)
        GACC(v4, w4) GLOAD(v4, w4, base + 12)
        GACC(v5, w5) GLOAD(v5, w5, base + 13)
        GACC(v6, w6) GLOAD(v6, w6, base + 14)
        GACC(v7, w7) GLOAD(v7, w7, base + 15)
    }
#undef GLOAD
#undef GACC

    float t = dis[n];
    float2 A = *(const float2*)(Ag + d);
    float2 B = *(const float2*)(Bg + d);
    float o0 = fmaxf(fmaf(a0 * t, A.x, B.x), 0.f);
    float o1 = fmaxf(fmaf(a1 * t, A.y, B.y), 0.f);
    unsigned int packed = (unsigned int)f2bf(o0) | ((unsigned int)f2bf(o1) << 16);
    *(unsigned int*)(h + (size_t)n * HD + d) = packed;
}

// ---------------- asrc/adst: [N,128] @ wa[128,8] ----------------
__global__ __launch_bounds__(256) void attn_dots_k(const ushort_t* __restrict__ h,
                                                   const float* __restrict__ wa,
                                                   float* __restrict__ asrc,
                                                   float* __restrict__ adst) {
    __shared__ float was[128][8];
    int tid = threadIdx.x;
    for (int i = tid; i < 1024; i += 256) was[i >> 3][i & 7] = wa[i];
    __syncthreads();
    int nl = tid >> 3, j = tid & 7;
    int n = blockIdx.x * 32 + nl;
    if (n >= NN) return;
    const ushort_t* hr = h + (size_t)n * HD;
    float s = 0.f;
    #pragma unroll 4
    for (int i = 0; i < 64; ++i) {
        unsigned int hv = *(const unsigned int*)(hr + 2 * i);
        s += bf2f_lo(hv) * was[2 * i][j] + bf2f_hi(hv) * was[2 * i + 1][j];
    }
    if (j < 4) asrc[n * 4 + j] = s;
    else       adst[n * 4 + (j - 4)] = s;
}

// ---------------- per-edge softmax numerators + per-node inverse sums ----------------
__global__ __launch_bounds__(256) void alpha_k(
    const float* __restrict__ asrc, const float* __restrict__ adst,
    const int* __restrict__ rowptr, const int* __restrict__ csr,
    float* __restrict__ pexp, float* __restrict__ inv_s) {
    int wid = threadIdx.x >> 6, lane = threadIdx.x & 63;
    int n = blockIdx.x * 4 + wid;
    int r0 = rowptr[n], r1 = rowptr[n + 1];
    float4 ad = *(const float4*)(adst + n * 4);
    const float NINF = -__builtin_inff();
    float m0 = NINF, m1 = NINF, m2 = NINF, m3 = NINF;
    for (int base = r0; base < r1; base += 64) {
        int e = base + lane;
        if (e < r1) {
            int src = csr[e];
            float4 as = *(const float4*)(asrc + src * 4);
            m0 = fmaxf(m0, lk(as.x + ad.x));
            m1 = fmaxf(m1, lk(as.y + ad.y));
            m2 = fmaxf(m2, lk(as.z + ad.z));
            m3 = fmaxf(m3, lk(as.w + ad.w));
        }
    }
    #pragma unroll
    for (int o = 32; o; o >>= 1) {
        m0 = fmaxf(m0, __shfl_xor(m0, o));
        m1 = fmaxf(m1, __shfl_xor(m1, o));
        m2 = fmaxf(m2, __shfl_xor(m2, o));
        m3 = fmaxf(m3, __shfl_xor(m3, o));
    }
    float s0 = 0.f, s1 = 0.f, s2 = 0.f, s3 = 0.f;
    for (int base = r0; base < r1; base += 64) {
        int e = base + lane;
        if (e < r1) {
            int src = csr[e];
            float4 as = *(const float4*)(asrc + src * 4);
            float p0 = __expf(lk(as.x + ad.x) - m0);
            float p1 = __expf(lk(as.y + ad.y) - m1);
            float p2 = __expf(lk(as.z + ad.z) - m2);
            float p3 = __expf(lk(as.w + ad.w) - m3);
            s0 += p0; s1 += p1; s2 += p2; s3 += p3;
            *(float4*)(pexp + 4 * (size_t)e) = make_float4(p0, p1, p2, p3);
        }
    }
    #pragma unroll
    for (int o = 32; o; o >>= 1) {
        s0 += __shfl_xor(s0, o);
        s1 += __shfl_xor(s1, o);
        s2 += __shfl_xor(s2, o);
        s3 += __shfl_xor(s3, o);
    }
    if (lane == 0) {
        *(float4*)(inv_s + 4 * n) = make_float4(
            1.f / (s0 + 1e-16f), 1.f / (s1 + 1e-16f),
            1.f / (s2 + 1e-16f), 1.f / (s3 + 1e-16f));
    }
}

// ---------------- z gather: z_h[n,:] = inv_s[n,h] * sum_e p[e,h] * h[src_e,:]
// wave per node, 2 dims/lane, 4 heads accumulated from the SAME 256B row, 6-deep pipeline
__global__ __launch_bounds__(256) void zgather_k(
    const ushort_t* __restrict__ h, const int* __restrict__ rowptr,
    const int* __restrict__ csr, const float* __restrict__ pexp,
    const float* __restrict__ inv_s, ushort_t* __restrict__ zb) {
    int wid = threadIdx.x >> 6, lane = threadIdx.x & 63;
    int n = blockIdx.x * 4 + wid;           // grid = NN/4 exactly
    int r0 = rowptr[n], r1 = rowptr[n + 1];
    int d = 2 * lane;
    float acc[8] = {0.f, 0.f, 0.f, 0.f, 0.f, 0.f, 0.f, 0.f};

    unsigned int v0 = 0, v1 = 0, v2 = 0, v3 = 0, v4 = 0, v5 = 0;
    float4 p0, p1, p2, p3, p4, p5;

#define ZLOAD(V, P, IDX) { int _i = (IDX); P = make_float4(0.f, 0.f, 0.f, 0.f); \
    if (_i < r1) { int _s = csr[_i]; P = *(const float4*)(pexp + 4 * (size_t)_i); \
        V = *(const unsigned int*)(h + (size_t)_s * HD + d); } }
#define ZACC(V, P) { float _lo = bf2f_lo(V), _hi = bf2f_hi(V); \
    acc[0] = fmaf(P.x, _lo, acc[0]); acc[1] = fmaf(P.x, _hi, acc[1]); \
    acc[2] = fmaf(P.y, _lo, acc[2]); acc[3] = fmaf(P.y, _hi, acc[3]); \
    acc[4] = fmaf(P.z, _lo, acc[4]); acc[5] = fmaf(P.z, _hi, acc[5]); \
    acc[6] = fmaf(P.w, _lo, acc[6]); acc[7] = fmaf(P.w, _hi, acc[7]); }

    ZLOAD(v0, p0, r0 + 0) ZLOAD(v1, p1, r0 + 1) ZLOAD(v2, p2, r0 + 2)
    ZLOAD(v3, p3, r0 + 3) ZLOAD(v4, p4, r0 + 4) ZLOAD(v5, p5, r0 + 5)
    for (int base = r0; base < r1; base += 6) {
        ZACC(v0, p0) ZLOAD(v0, p0, base + 6)
        ZACC(v1, p1) ZLOAD(v1, p1, base + 7)
        ZACC(v2, p2) ZLOAD(v2, p2, base + 8)
        ZACC(v3, p3) ZLOAD(v3, p3, base + 9)
        ZACC(v4, p4) ZLOAD(v4, p4, base + 10)
        ZACC(v5, p5) ZLOAD(v5, p5, base + 11)
    }
#undef ZLOAD
#undef ZACC

    float4 is = *(const float4*)(inv_s + 4 * n);
    size_t base = (size_t)n * HD + d;
    unsigned int pk;
    pk = (unsigned int)f2bf(acc[0] * is.x) | ((unsigned int)f2bf(acc[1] * is.x) << 16);
    *(unsigned int*)(zb + 0 * (size_t)NN * HD + base) = pk;
    pk = (unsigned int)f2bf(acc[2] * is.y) | ((unsigned int)f2bf(acc[3] * is.y) << 16);
    *(unsigned int*)(zb + 1 * (size_t)NN * HD + base) = pk;
    pk = (unsigned int)f2bf(acc[4] * is.z) | ((unsigned int)f2bf(acc[5] * is.z) << 16);
    *(unsigned int*)(zb + 2 * (size_t)NN * HD + base) = pk;
    pk = (unsigned int)f2bf(acc[6] * is.w) | ((unsigned int)f2bf(acc[7] * is.w) << 16);
    *(unsigned int*)(zb + 3 * (size_t)NN * HD + base) = pk;
}

// ---------------- pooling: one (graph, 256-dim half) per block ----------------
__global__ __launch_bounds__(256) void pool_k(const float* __restrict__ outfeat,
                                              const int* __restrict__ batch,
                                              float* __restrict__ feat) {
    int g = blockIdx.x;
    int d = blockIdx.y * 256 + threadIdx.x;
    int lo = 0, hi = NN;
    while (lo < hi) { int mid = (lo + hi) >> 1; if (batch[mid] < g) lo = mid + 1; else hi = mid; }
    int start = lo;
    hi = NN;
    while (lo < hi) { int mid = (lo + hi) >> 1; if (batch[mid] < g + 1) lo = mid + 1; else hi = mid; }
    int end = lo;
    int cnt = end - start;
    float sadd = 0.f, smax = -3.402823466e38f;
    for (int i = start; i < end; ++i) {
        float v = outfeat[(size_t)i * OD + d];
        sadd += v;
        smax = fmaxf(smax, v);
    }
    float smean;
    if (cnt > 0) { smean = sadd / (float)cnt; }
    else { sadd = 0.f; smax = 0.f; smean = 0.f; }
    feat[g * 1536 + d] = sadd;
    feat[g * 1536 + 512 + d] = smax;
    feat[g * 1536 + 1024 + d] = smean;
}

// ---------------- head: out = sigmoid(feat @ w_lin + b_lin) ----------------
__global__ __launch_bounds__(256) void head_k(const float* __restrict__ feat,
                                              const float* __restrict__ w_lin,
                                              const float* __restrict__ b_lin,
                                              float* __restrict__ out) {
    __shared__ float red[256];
    int g = blockIdx.x;
    int t = threadIdx.x;
    int o = t & 15, part = t >> 4;
    float s = 0.f;
    int kbeg = part * 96;
    for (int k = kbeg; k < kbeg + 96; ++k) s += feat[g * 1536 + k] * w_lin[k * 16 + o];
    red[t] = s;
    __syncthreads();
    if (t < 16) {
        float tot = b_lin[o];
        for (int p = 0; p < 16; ++p) tot += red[p * 16 + o];
        out[g * 16 + o] = 1.f / (1.f + __expf(-tot));
    }
}

extern "C" void kernel_launch(void* const* d_in, const int* in_sizes, int n_in,
                              void* d_out, int out_size, void* d_ws, size_t ws_size,
                              hipStream_t stream) {
    const float* x       = (const float*)d_in[0];
    const int*   ei      = (const int*)d_in[1];
    const int*   batch   = (const int*)d_in[2];
    const float* w_gcn   = (const float*)d_in[3];
    const float* b_gcn   = (const float*)d_in[4];
    const float* g2_gam  = (const float*)d_in[5];
    const float* g2_bet  = (const float*)d_in[6];
    const float* g2_mean = (const float*)d_in[7];
    const float* g2_var  = (const float*)d_in[8];
    const float* w_gat   = (const float*)d_in[9];
    const float* a_src   = (const float*)d_in[10];
    const float* a_dst   = (const float*)d_in[11];
    const float* b_gat   = (const float*)d_in[12];
    const float* g1_gam  = (const float*)d_in[13];
    const float* g1_bet  = (const float*)d_in[14];
    const float* g1_mean = (const float*)d_in[15];
    const float* g1_var  = (const float*)d_in[16];
    const float* w_lin   = (const float*)d_in[17];
    const float* b_lin   = (const float*)d_in[18];
    float* out = (float*)d_out;

    char* ws = (char*)d_ws;
    size_t off = 0;
    auto alloc = [&](size_t bytes) -> void* {
        void* p = ws + off;
        off += (bytes + 255) & ~(size_t)255;
        return p;
    };
    int* deg        = (int*)alloc((size_t)NN * 4);
    int* fill       = (int*)alloc((size_t)NN * 4);
    int* rowptr     = (int*)alloc((size_t)(NN + 1) * 4);
    int* csr        = (int*)alloc((size_t)NE2 * 4);
    float* dis      = (float*)alloc((size_t)NN * 4);
    ushort_t* xb    = (ushort_t*)alloc((size_t)NN * FD * 2);
    ushort_t* wgT   = (ushort_t*)alloc((size_t)FD * HD * 2);
    ushort_t* wgatT = (ushort_t*)alloc((size_t)HD * OD * 2);
    ushort_t* h0b   = (ushort_t*)alloc((size_t)NN * HD * 2);
    ushort_t* hb    = (ushort_t*)alloc((size_t)NN * HD * 2);
    ushort_t* zb    = (ushort_t*)alloc((size_t)NHD * NN * HD * 2);
    float* asrc     = (float*)alloc((size_t)NN * 4 * 4);
    float* adst     = (float*)alloc((size_t)NN * 4 * 4);
    float* wa       = (float*)alloc((size_t)128 * 8 * 4);
    float* Ag       = (float*)alloc((size_t)HD * 4);
    float* Bg       = (float*)alloc((size_t)HD * 4);
    float* Aa       = (float*)alloc((size_t)OD * 4);
    float* Ba       = (float*)alloc((size_t)OD * 4);
    float* pexp     = (float*)alloc((size_t)NE2 * 4 * 4);
    float* inv_s    = (float*)alloc((size_t)NN * 4 * 4);
    float* ofeat    = (float*)alloc((size_t)NN * OD * 4);
    float* feat     = (float*)alloc((size_t)NG * 1536 * 4);

    // CSR build
    init_k<<<(NN + 255) / 256, 256, 0, stream>>>(deg, fill);
    count_k<<<(NE + 255) / 256, 256, 0, stream>>>(ei, deg);
    scan_k<<<1, 1024, 0, stream>>>(deg, rowptr);
    fill_k<<<(NE2 + 255) / 256, 256, 0, stream>>>(ei, rowptr, fill, csr);
    dis_k<<<(NN + 255) / 256, 256, 0, stream>>>(deg, dis);

    // BN affine params
    bnaff_k<<<3, 256, 0, stream>>>(b_gcn, g2_gam, g2_bet, g2_mean, g2_var,
                                   b_gat, g1_gam, g1_bet, g1_mean, g1_var,
                                   Ag, Bg, Aa, Ba);

    // casts: x -> bf16; weights -> transposed bf16
    cast_x_k<<<(NN * FD / 4 + 255) / 256, 256, 0, stream>>>(x, xb);
    trcast_k<<<(FD * HD + 255) / 256, 256, 0, stream>>>(w_gcn, wgT, FD, HD);
    trcast_k<<<(HD * OD + 255) / 256, 256, 0, stream>>>(w_gat, wgatT, HD, OD);

    // GCN linear: h0 = x @ w_gcn   (bf16 MFMA)
    gemm_bf16<<<dim3((NN + 127) / 128, HD / 64), 256, 0, stream>>>(xb, wgT, h0b, NN, HD);

    // attention weight pre-projection
    wa_k<<<4, 256, 0, stream>>>(w_gat, a_src, a_dst, wa);

    // GCN aggregate + BN2 + ReLU
    gcn_agg2_k<<<NN / 4, 256, 0, stream>>>(h0b, rowptr, csr, dis, Ag, Bg, hb);

    // asrc/adst projection
    attn_dots_k<<<(NN + 31) / 32, 256, 0, stream>>>(hb, wa, asrc, adst);

    // per-edge softmax numerators + per-node inverse sums
    alpha_k<<<NN / 4, 256, 0, stream>>>(asrc, adst, rowptr, csr, pexp, inv_s);

    // z gather: per-head weighted sums of h rows (replaces hg GEMM + 1KB/edge gather)
    zgather_k<<<NN / 4, 256, 0, stream>>>(hb, rowptr, csr, pexp, inv_s, zb);

    // per-head GEMM + BN1 + ReLU -> ofeat
    gemm_z_k<<<dim3((NN + 127) / 128, HD / 64, NHD), 256, 0, stream>>>(zb, wgatT, Aa, Ba, ofeat);

    // pooling
    pool_k<<<dim3(NG, 2), 256, 0, stream>>>(ofeat, batch, feat);

    // head
    head_k<<<NG, 256, 0, stream>>>(feat, w_lin, b_lin, out);
}

// Round 6
// 421.599 us; speedup vs baseline: 1.8443x; 1.1468x over previous
//
#include <hip/hip_runtime.h>

#define NN 50000          // nodes
#define NE 800000         // edges (without self loops)
#define NE2 (NE + NN)     // edges + self loops
#define FD 128            // input feature dim
#define HD 128            // hidden dim
#define NHD 4             // heads
#define OD 512            // heads * HD
#define NG 512            // graphs
#define BN_EPS 1e-5f

typedef __attribute__((ext_vector_type(8))) short bfrag;   // 8 bf16 = 4 VGPRs
typedef __attribute__((ext_vector_type(4))) float f32x4;
typedef unsigned short ushort_t;

__device__ inline ushort_t f2bf(float f) {               // RNE fp32->bf16
    unsigned int u = __float_as_uint(f);
    unsigned int r = (u + 0x7fffu + ((u >> 16) & 1u)) >> 16;
    return (ushort_t)r;
}
__device__ inline float bf2f_lo(unsigned int v) { return __uint_as_float(v << 16); }
__device__ inline float bf2f_hi(unsigned int v) { return __uint_as_float(v & 0xffff0000u); }
__device__ inline float lk(float x) { return fmaxf(x, 0.2f * x); }   // leaky_relu 0.2

// ---------------- CSR build ----------------
__global__ void init_k(int* __restrict__ deg, int* __restrict__ fill) {
    int i = blockIdx.x * blockDim.x + threadIdx.x;
    if (i < NN) { deg[i] = 1; fill[i] = 0; }   // 1 = self loop
}

__global__ void count_k(const int* __restrict__ ei, int* __restrict__ deg) {
    int e = blockIdx.x * blockDim.x + threadIdx.x;
    if (e < NE) atomicAdd(&deg[ei[NE + e]], 1);
}

__global__ __launch_bounds__(1024) void scan_k(const int* __restrict__ deg,
                                               int* __restrict__ rowptr) {
    __shared__ int part[1024];
    int tid = threadIdx.x;
    const int chunk = (NN + 1023) / 1024;
    int beg = tid * chunk;
    int end = min(beg + chunk, NN);
    int s = 0;
    for (int i = beg; i < end; ++i) s += deg[i];
    part[tid] = s;
    __syncthreads();
    for (int off = 1; off < 1024; off <<= 1) {
        int v = (tid >= off) ? part[tid - off] : 0;
        __syncthreads();
        part[tid] += v;
        __syncthreads();
    }
    int run = (tid == 0) ? 0 : part[tid - 1];
    for (int i = beg; i < end; ++i) { rowptr[i] = run; run += deg[i]; }
    if (tid == 0) rowptr[NN] = part[1023];
}

__global__ void fill_k(const int* __restrict__ ei, const int* __restrict__ rowptr,
                       int* __restrict__ fill, int* __restrict__ csr) {
    int e = blockIdx.x * blockDim.x + threadIdx.x;
    if (e >= NE2) return;
    int src, dst;
    if (e < NE) { src = ei[e]; dst = ei[NE + e]; }
    else        { src = e - NE; dst = e - NE; }
    int pos = atomicAdd(&fill[dst], 1);
    csr[rowptr[dst] + pos] = src;
}

__global__ void dis_k(const int* __restrict__ deg, float* __restrict__ dis) {
    int i = blockIdx.x * blockDim.x + threadIdx.x;
    if (i < NN) dis[i] = rsqrtf((float)deg[i]);
}

// ---------------- BN -> affine precompute ----------------
__global__ void bnaff_k(const float* __restrict__ b_gcn, const float* __restrict__ g2_gam,
                        const float* __restrict__ g2_bet, const float* __restrict__ g2_mean,
                        const float* __restrict__ g2_var, const float* __restrict__ b_gat,
                        const float* __restrict__ g1_gam, const float* __restrict__ g1_bet,
                        const float* __restrict__ g1_mean, const float* __restrict__ g1_var,
                        float* __restrict__ Ag, float* __restrict__ Bg,
                        float* __restrict__ Aa, float* __restrict__ Ba) {
    int t = blockIdx.x * blockDim.x + threadIdx.x;
    if (t < HD) {
        float a = rsqrtf(g2_var[t] + BN_EPS) * g2_gam[t];
        Ag[t] = a;
        Bg[t] = (b_gcn[t] - g2_mean[t]) * a + g2_bet[t];
    } else if (t < HD + OD) {
        int d = t - HD;
        float a = rsqrtf(g1_var[d] + BN_EPS) * g1_gam[d];
        Aa[d] = a;
        Ba[d] = (b_gat[d] - g1_mean[d]) * a + g1_bet[d];
    }
}

// ---------------- casts ----------------
__global__ void cast_x_k(const float* __restrict__ x, ushort_t* __restrict__ xb) {
    int t = blockIdx.x * blockDim.x + threadIdx.x;      // one float4 per thread
    const int total = NN * FD / 4;
    if (t >= total) return;
    float4 v = ((const float4*)x)[t];
    ushort_t o[4] = {f2bf(v.x), f2bf(v.y), f2bf(v.z), f2bf(v.w)};
    *(unsigned long long*)(xb + 4 * t) = *(unsigned long long*)o;
}

// wT[n*K + k] = bf16(w[k*N + n])
__global__ void trcast_k(const float* __restrict__ w, ushort_t* __restrict__ wT,
                         int K, int N) {
    int t = blockIdx.x * blockDim.x + threadIdx.x;
    if (t >= K * N) return;
    int n = t / K, k = t - n * K;
    wT[n * K + k] = f2bf(w[k * N + n]);
}

// ---------------- bf16 MFMA GEMM: C[M,N] = A[M,128] @ B[128,N], C stored bf16
__global__ __launch_bounds__(256) void gemm_bf16(const ushort_t* __restrict__ A,
                                                 const ushort_t* __restrict__ BT,
                                                 ushort_t* __restrict__ C,
                                                 int M, int N) {
    __shared__ short As[128][136];
    __shared__ short Bs[64][136];
    const int tid = threadIdx.x;
    const int m0 = blockIdx.x * 128;
    const int n0 = blockIdx.y * 64;

    #pragma unroll
    for (int i = 0; i < 8; ++i) {
        int c = tid + 256 * i;
        int row = c >> 4, off = (c & 15) * 8;
        bfrag v = (bfrag)0;
        if (m0 + row < M) v = *(const bfrag*)(A + (size_t)(m0 + row) * 128 + off);
        *(bfrag*)&As[row][off] = v;
    }
    #pragma unroll
    for (int i = 0; i < 4; ++i) {
        int c = tid + 256 * i;
        int row = c >> 4, off = (c & 15) * 8;
        *(bfrag*)&Bs[row][off] = *(const bfrag*)(BT + (size_t)(n0 + row) * 128 + off);
    }
    __syncthreads();

    const int w = tid >> 6;
    const int lr = tid & 15;
    const int kg = (tid & 63) >> 4;

    f32x4 acc[2][4];
    #pragma unroll
    for (int mi = 0; mi < 2; ++mi)
        #pragma unroll
        for (int ni = 0; ni < 4; ++ni) acc[mi][ni] = (f32x4)0.f;

    #pragma unroll
    for (int ks = 0; ks < 4; ++ks) {
        bfrag af[2], bb[4];
        #pragma unroll
        for (int mi = 0; mi < 2; ++mi)
            af[mi] = *(const bfrag*)&As[32 * w + 16 * mi + lr][32 * ks + 8 * kg];
        #pragma unroll
        for (int ni = 0; ni < 4; ++ni)
            bb[ni] = *(const bfrag*)&Bs[16 * ni + lr][32 * ks + 8 * kg];
        #pragma unroll
        for (int mi = 0; mi < 2; ++mi)
            #pragma unroll
            for (int ni = 0; ni < 4; ++ni)
                acc[mi][ni] = __builtin_amdgcn_mfma_f32_16x16x32_bf16(
                    af[mi], bb[ni], acc[mi][ni], 0, 0, 0);
    }

    #pragma unroll
    for (int mi = 0; mi < 2; ++mi) {
        #pragma unroll
        for (int r = 0; r < 4; ++r) {
            int row = m0 + 32 * w + 16 * mi + 4 * kg + r;
            if (row < M) {
                #pragma unroll
                for (int ni = 0; ni < 4; ++ni) {
                    int col = n0 + 16 * ni + lr;
                    C[(size_t)row * N + col] = f2bf(acc[mi][ni][r]);
                }
            }
        }
    }
}

// ---------------- per-head GEMM: ofeat[:,128h:128h+128] = relu(BN(z_h @ W_h)), bf16 out
__global__ __launch_bounds__(256) void gemm_z_k(const ushort_t* __restrict__ zb,
                                                const ushort_t* __restrict__ wgatT,
                                                const float* __restrict__ Aa,
                                                const float* __restrict__ Ba,
                                                ushort_t* __restrict__ ofeat) {
    __shared__ short As[128][136];
    __shared__ short Bs[64][136];
    const int tid = threadIdx.x;
    const int head = blockIdx.z;
    const int m0 = blockIdx.x * 128;
    const int n0 = blockIdx.y * 64;
    const ushort_t* A = zb + (size_t)head * NN * HD;
    const ushort_t* BT = wgatT + (size_t)head * HD * HD;

    #pragma unroll
    for (int i = 0; i < 8; ++i) {
        int c = tid + 256 * i;
        int row = c >> 4, off = (c & 15) * 8;
        bfrag v = (bfrag)0;
        if (m0 + row < NN) v = *(const bfrag*)(A + (size_t)(m0 + row) * HD + off);
        *(bfrag*)&As[row][off] = v;
    }
    #pragma unroll
    for (int i = 0; i < 4; ++i) {
        int c = tid + 256 * i;
        int row = c >> 4, off = (c & 15) * 8;
        *(bfrag*)&Bs[row][off] = *(const bfrag*)(BT + (size_t)(n0 + row) * HD + off);
    }
    __syncthreads();

    const int w = tid >> 6;
    const int lr = tid & 15;
    const int kg = (tid & 63) >> 4;

    f32x4 acc[2][4];
    #pragma unroll
    for (int mi = 0; mi < 2; ++mi)
        #pragma unroll
        for (int ni = 0; ni < 4; ++ni) acc[mi][ni] = (f32x4)0.f;

    #pragma unroll
    for (int ks = 0; ks < 4; ++ks) {
        bfrag af[2], bb[4];
        #pragma unroll
        for (int mi = 0; mi < 2; ++mi)
            af[mi] = *(const bfrag*)&As[32 * w + 16 * mi + lr][32 * ks + 8 * kg];
        #pragma unroll
        for (int ni = 0; ni < 4; ++ni)
            bb[ni] = *(const bfrag*)&Bs[16 * ni + lr][32 * ks + 8 * kg];
        #pragma unroll
        for (int mi = 0; mi < 2; ++mi)
            #pragma unroll
            for (int ni = 0; ni < 4; ++ni)
                acc[mi][ni] = __builtin_amdgcn_mfma_f32_16x16x32_bf16(
                    af[mi], bb[ni], acc[mi][ni], 0, 0, 0);
    }

    #pragma unroll
    for (int mi = 0; mi < 2; ++mi) {
        #pragma unroll
        for (int r = 0; r < 4; ++r) {
            int row = m0 + 32 * w + 16 * mi + 4 * kg + r;
            if (row < NN) {
                #pragma unroll
                for (int ni = 0; ni < 4; ++ni) {
                    int gc = 128 * head + n0 + 16 * ni + lr;
                    float v = fmaf(acc[mi][ni][r], Aa[gc], Ba[gc]);
                    ofeat[(size_t)row * OD + gc] = f2bf(fmaxf(v, 0.f));
                }
            }
        }
    }
}

// ---------------- precompute wa[k][j]: j<4 -> w_gat col-block . a_src[head] ----------------
__global__ void wa_k(const float* __restrict__ w_gat, const float* __restrict__ a_src,
                     const float* __restrict__ a_dst, float* __restrict__ wa) {
    int t = blockIdx.x * blockDim.x + threadIdx.x;
    if (t >= 128 * 8) return;
    int k = t >> 3, j = t & 7, head = j & 3;
    const float* av = (j < 4 ? a_src : a_dst) + head * 128;
    const float* w = w_gat + (size_t)k * OD + head * 128;
    float s = 0.f;
    for (int d = 0; d < 128; ++d) s += w[d] * av[d];
    wa[k * 8 + j] = s;
}

// ---------------- GCN aggregate: wave/node, scalarized indices, 8-deep pipeline ----------------
__global__ __launch_bounds__(256) void gcn_agg2_k(
    const ushort_t* __restrict__ h0, const int* __restrict__ rowptr,
    const int* __restrict__ csr, const float* __restrict__ dis,
    const float* __restrict__ Ag, const float* __restrict__ Bg,
    ushort_t* __restrict__ h) {
    int lane = threadIdx.x & 63;
    int n = __builtin_amdgcn_readfirstlane((int)(blockIdx.x * 4) + (int)(threadIdx.x >> 6));
    int r0 = __builtin_amdgcn_readfirstlane(rowptr[n]);
    int r1 = __builtin_amdgcn_readfirstlane(rowptr[n + 1]);
    int d = 2 * lane;
    const ushort_t* h0d = h0 + d;
    float a0 = 0.f, a1 = 0.f;
    unsigned int hv[8];
    float wv[8];

#define GLOAD(i, IDX) { int _e = (IDX); int _ec = _e < r1 ? _e : r1 - 1; \
    int _s = csr[_ec]; float _w = dis[_s]; \
    wv[i] = _e < r1 ? _w : 0.f; \
    hv[i] = *(const unsigned int*)(h0d + ((unsigned)_s << 7)); }
#define GACC(i) { a0 = fmaf(wv[i], bf2f_lo(hv[i]), a0); a1 = fmaf(wv[i], bf2f_hi(hv[i]), a1); }

    GLOAD(0, r0 + 0) GLOAD(1, r0 + 1) GLOAD(2, r0 + 2) GLOAD(3, r0 + 3)
    GLOAD(4, r0 + 4) GLOAD(5, r0 + 5) GLOAD(6, r0 + 6) GLOAD(7, r0 + 7)
    for (int base = r0; base < r1; base += 8) {
        GACC(0) GLOAD(0, base + 8)
        GACC(1) GLOAD(1, base + 9)
        GACC(2) GLOAD(2, base + 10)
        GACC(3) GLOAD(3, base + 11)
        GACC(4) GLOAD(4, base + 12)
        GACC(5) GLOAD(5, base + 13)
        GACC(6) GLOAD(6, base + 14)
        GACC(7) GLOAD(7, base + 15)
    }
#undef GLOAD
#undef GACC

    float t = dis[n];
    float2 A = *(const float2*)(Ag + d);
    float2 B = *(const float2*)(Bg + d);
    float o0 = fmaxf(fmaf(a0 * t, A.x, B.x), 0.f);
    float o1 = fmaxf(fmaf(a1 * t, A.y, B.y), 0.f);
    unsigned int packed = (unsigned int)f2bf(o0) | ((unsigned int)f2bf(o1) << 16);
    *(unsigned int*)(h + (size_t)n * HD + d) = packed;
}

// ---------------- asrc/adst: [N,128] @ wa[128,8] ----------------
__global__ __launch_bounds__(256) void attn_dots_k(const ushort_t* __restrict__ h,
                                                   const float* __restrict__ wa,
                                                   float* __restrict__ asrc,
                                                   float* __restrict__ adst) {
    __shared__ float was[128][8];
    int tid = threadIdx.x;
    for (int i = tid; i < 1024; i += 256) was[i >> 3][i & 7] = wa[i];
    __syncthreads();
    int nl = tid >> 3, j = tid & 7;
    int n = blockIdx.x * 32 + nl;
    if (n >= NN) return;
    const ushort_t* hr = h + (size_t)n * HD;
    float s = 0.f;
    #pragma unroll 4
    for (int i = 0; i < 64; ++i) {
        unsigned int hv = *(const unsigned int*)(hr + 2 * i);
        s += bf2f_lo(hv) * was[2 * i][j] + bf2f_hi(hv) * was[2 * i + 1][j];
    }
    if (j < 4) asrc[n * 4 + j] = s;
    else       adst[n * 4 + (j - 4)] = s;
}

// ---------------- per-edge softmax numerators + per-node inverse sums (single pass, no max)
// logits = leaky_relu(asrc+adst) are O(1) (std ~0.6): exp() cannot overflow; the
// reference's max-subtraction cancels exactly in alpha = ex/esum.
__global__ __launch_bounds__(256) void alpha_k(
    const float* __restrict__ asrc, const float* __restrict__ adst,
    const int* __restrict__ rowptr, const int* __restrict__ csr,
    float* __restrict__ pexp, float* __restrict__ inv_s) {
    int lane = threadIdx.x & 63;
    int n = __builtin_amdgcn_readfirstlane((int)(blockIdx.x * 4) + (int)(threadIdx.x >> 6));
    int r0 = __builtin_amdgcn_readfirstlane(rowptr[n]);
    int r1 = __builtin_amdgcn_readfirstlane(rowptr[n + 1]);
    float4 ad = *(const float4*)(adst + n * 4);
    float s0 = 0.f, s1 = 0.f, s2 = 0.f, s3 = 0.f;
    for (int base = r0; base < r1; base += 64) {
        int e = base + lane;
        if (e < r1) {
            int src = csr[e];
            float4 as = *(const float4*)(asrc + src * 4);
            float p0 = __expf(lk(as.x + ad.x));
            float p1 = __expf(lk(as.y + ad.y));
            float p2 = __expf(lk(as.z + ad.z));
            float p3 = __expf(lk(as.w + ad.w));
            s0 += p0; s1 += p1; s2 += p2; s3 += p3;
            *(float4*)(pexp + 4 * (size_t)e) = make_float4(p0, p1, p2, p3);
        }
    }
    #pragma unroll
    for (int o = 32; o; o >>= 1) {
        s0 += __shfl_xor(s0, o);
        s1 += __shfl_xor(s1, o);
        s2 += __shfl_xor(s2, o);
        s3 += __shfl_xor(s3, o);
    }
    if (lane == 0) {
        *(float4*)(inv_s + 4 * n) = make_float4(
            1.f / (s0 + 1e-16f), 1.f / (s1 + 1e-16f),
            1.f / (s2 + 1e-16f), 1.f / (s3 + 1e-16f));
    }
}

// ---------------- z gather: z_h[n,:] = inv_s[n,h] * sum_e p[e,h] * h[src_e,:]
// wave/node, 2 dims/lane, scalarized indices/p, 8-deep pipeline
__global__ __launch_bounds__(256) void zgather_k(
    const ushort_t* __restrict__ h, const int* __restrict__ rowptr,
    const int* __restrict__ csr, const float* __restrict__ pexp,
    const float* __restrict__ inv_s, ushort_t* __restrict__ zb) {
    int lane = threadIdx.x & 63;
    int n = __builtin_amdgcn_readfirstlane((int)(blockIdx.x * 4) + (int)(threadIdx.x >> 6));
    int r0 = __builtin_amdgcn_readfirstlane(rowptr[n]);
    int r1 = __builtin_amdgcn_readfirstlane(rowptr[n + 1]);
    int d = 2 * lane;
    const ushort_t* hd = h + d;
    float acc[8] = {0.f, 0.f, 0.f, 0.f, 0.f, 0.f, 0.f, 0.f};
    unsigned int hv[8];
    float4 pv[8];

#define ZLOAD(i, IDX) { int _e = (IDX); int _ec = _e < r1 ? _e : r1 - 1; \
    int _s = csr[_ec]; \
    float4 _p = *(const float4*)(pexp + 4 * (size_t)_ec); \
    bool _v = _e < r1; \
    pv[i].x = _v ? _p.x : 0.f; pv[i].y = _v ? _p.y : 0.f; \
    pv[i].z = _v ? _p.z : 0.f; pv[i].w = _v ? _p.w : 0.f; \
    hv[i] = *(const unsigned int*)(hd + ((unsigned)_s << 7)); }
#define ZACC(i) { float _lo = bf2f_lo(hv[i]), _hi = bf2f_hi(hv[i]); \
    acc[0] = fmaf(pv[i].x, _lo, acc[0]); acc[1] = fmaf(pv[i].x, _hi, acc[1]); \
    acc[2] = fmaf(pv[i].y, _lo, acc[2]); acc[3] = fmaf(pv[i].y, _hi, acc[3]); \
    acc[4] = fmaf(pv[i].z, _lo, acc[4]); acc[5] = fmaf(pv[i].z, _hi, acc[5]); \
    acc[6] = fmaf(pv[i].w, _lo, acc[6]); acc[7] = fmaf(pv[i].w, _hi, acc[7]); }

    ZLOAD(0, r0 + 0) ZLOAD(1, r0 + 1) ZLOAD(2, r0 + 2) ZLOAD(3, r0 + 3)
    ZLOAD(4, r0 + 4) ZLOAD(5, r0 + 5) ZLOAD(6, r0 + 6) ZLOAD(7, r0 + 7)
    for (int base = r0; base < r1; base += 8) {
        ZACC(0) ZLOAD(0, base + 8)
        ZACC(1) ZLOAD(1, base + 9)
        ZACC(2) ZLOAD(2, base + 10)
        ZACC(3) ZLOAD(3, base + 11)
        ZACC(4) ZLOAD(4, base + 12)
        ZACC(5) ZLOAD(5, base + 13)
        ZACC(6) ZLOAD(6, base + 14)
        ZACC(7) ZLOAD(7, base + 15)
    }
#undef ZLOAD
#undef ZACC

    float4 is = *(const float4*)(inv_s + 4 * n);
    size_t base = (size_t)n * HD + d;
    unsigned int pk;
    pk = (unsigned int)f2bf(acc[0] * is.x) | ((unsigned int)f2bf(acc[1] * is.x) << 16);
    *(unsigned int*)(zb + 0 * (size_t)NN * HD + base) = pk;
    pk = (unsigned int)f2bf(acc[2] * is.y) | ((unsigned int)f2bf(acc[3] * is.y) << 16);
    *(unsigned int*)(zb + 1 * (size_t)NN * HD + base) = pk;
    pk = (unsigned int)f2bf(acc[4] * is.z) | ((unsigned int)f2bf(acc[5] * is.z) << 16);
    *(unsigned int*)(zb + 2 * (size_t)NN * HD + base) = pk;
    pk = (unsigned int)f2bf(acc[6] * is.w) | ((unsigned int)f2bf(acc[7] * is.w) << 16);
    *(unsigned int*)(zb + 3 * (size_t)NN * HD + base) = pk;
}

// ---------------- pooling: one (graph, 256-dim half) per block, bf16 ofeat ----------------
__global__ __launch_bounds__(256) void pool_k(const ushort_t* __restrict__ outfeat,
                                              const int* __restrict__ batch,
                                              float* __restrict__ feat) {
    int g = blockIdx.x;
    int d = blockIdx.y * 256 + threadIdx.x;
    int lo = 0, hi = NN;
    while (lo < hi) { int mid = (lo + hi) >> 1; if (batch[mid] < g) lo = mid + 1; else hi = mid; }
    int start = lo;
    hi = NN;
    while (lo < hi) { int mid = (lo + hi) >> 1; if (batch[mid] < g + 1) lo = mid + 1; else hi = mid; }
    int end = lo;
    int cnt = end - start;
    float sadd = 0.f, smax = -3.402823466e38f;
    for (int i = start; i < end; ++i) {
        float v = bf2f_lo((unsigned int)outfeat[(size_t)i * OD + d]);
        sadd += v;
        smax = fmaxf(smax, v);
    }
    float smean;
    if (cnt > 0) { smean = sadd / (float)cnt; }
    else { sadd = 0.f; smax = 0.f; smean = 0.f; }
    feat[g * 1536 + d] = sadd;
    feat[g * 1536 + 512 + d] = smax;
    feat[g * 1536 + 1024 + d] = smean;
}

// ---------------- head: out = sigmoid(feat @ w_lin + b_lin) ----------------
__global__ __launch_bounds__(256) void head_k(const float* __restrict__ feat,
                                              const float* __restrict__ w_lin,
                                              const float* __restrict__ b_lin,
                                              float* __restrict__ out) {
    __shared__ float red[256];
    int g = blockIdx.x;
    int t = threadIdx.x;
    int o = t & 15, part = t >> 4;
    float s = 0.f;
    int kbeg = part * 96;
    for (int k = kbeg; k < kbeg + 96; ++k) s += feat[g * 1536 + k] * w_lin[k * 16 + o];
    red[t] = s;
    __syncthreads();
    if (t < 16) {
        float tot = b_lin[o];
        for (int p = 0; p < 16; ++p) tot += red[p * 16 + o];
        out[g * 16 + o] = 1.f / (1.f + __expf(-tot));
    }
}

extern "C" void kernel_launch(void* const* d_in, const int* in_sizes, int n_in,
                              void* d_out, int out_size, void* d_ws, size_t ws_size,
                              hipStream_t stream) {
    const float* x       = (const float*)d_in[0];
    const int*   ei      = (const int*)d_in[1];
    const int*   batch   = (const int*)d_in[2];
    const float* w_gcn   = (const float*)d_in[3];
    const float* b_gcn   = (const float*)d_in[4];
    const float* g2_gam  = (const float*)d_in[5];
    const float* g2_bet  = (const float*)d_in[6];
    const float* g2_mean = (const float*)d_in[7];
    const float* g2_var  = (const float*)d_in[8];
    const float* w_gat   = (const float*)d_in[9];
    const float* a_src   = (const float*)d_in[10];
    const float* a_dst   = (const float*)d_in[11];
    const float* b_gat   = (const float*)d_in[12];
    const float* g1_gam  = (const float*)d_in[13];
    const float* g1_bet  = (const float*)d_in[14];
    const float* g1_mean = (const float*)d_in[15];
    const float* g1_var  = (const float*)d_in[16];
    const float* w_lin   = (const float*)d_in[17];
    const float* b_lin   = (const float*)d_in[18];
    float* out = (float*)d_out;

    char* ws = (char*)d_ws;
    size_t off = 0;
    auto alloc = [&](size_t bytes) -> void* {
        void* p = ws + off;
        off += (bytes + 255) & ~(size_t)255;
        return p;
    };
    int* deg        = (int*)alloc((size_t)NN * 4);
    int* fill       = (int*)alloc((size_t)NN * 4);
    int* rowptr     = (int*)alloc((size_t)(NN + 1) * 4);
    int* csr        = (int*)alloc((size_t)NE2 * 4);
    float* dis      = (float*)alloc((size_t)NN * 4);
    ushort_t* xb    = (ushort_t*)alloc((size_t)NN * FD * 2);
    ushort_t* wgT   = (ushort_t*)alloc((size_t)FD * HD * 2);
    ushort_t* wgatT = (ushort_t*)alloc((size_t)HD * OD * 2);
    ushort_t* h0b   = (ushort_t*)alloc((size_t)NN * HD * 2);
    ushort_t* hb    = (ushort_t*)alloc((size_t)NN * HD * 2);
    ushort_t* zb    = (ushort_t*)alloc((size_t)NHD * NN * HD * 2);
    float* asrc     = (float*)alloc((size_t)NN * 4 * 4);
    float* adst     = (float*)alloc((size_t)NN * 4 * 4);
    float* wa       = (float*)alloc((size_t)128 * 8 * 4);
    float* Ag       = (float*)alloc((size_t)HD * 4);
    float* Bg       = (float*)alloc((size_t)HD * 4);
    float* Aa       = (float*)alloc((size_t)OD * 4);
    float* Ba       = (float*)alloc((size_t)OD * 4);
    float* pexp     = (float*)alloc((size_t)NE2 * 4 * 4);
    float* inv_s    = (float*)alloc((size_t)NN * 4 * 4);
    ushort_t* ofeat = (ushort_t*)alloc((size_t)NN * OD * 2);
    float* feat     = (float*)alloc((size_t)NG * 1536 * 4);

    // CSR build
    init_k<<<(NN + 255) / 256, 256, 0, stream>>>(deg, fill);
    count_k<<<(NE + 255) / 256, 256, 0, stream>>>(ei, deg);
    scan_k<<<1, 1024, 0, stream>>>(deg, rowptr);
    fill_k<<<(NE2 + 255) / 256, 256, 0, stream>>>(ei, rowptr, fill, csr);
    dis_k<<<(NN + 255) / 256, 256, 0, stream>>>(deg, dis);

    // BN affine params
    bnaff_k<<<3, 256, 0, stream>>>(b_gcn, g2_gam, g2_bet, g2_mean, g2_var,
                                   b_gat, g1_gam, g1_bet, g1_mean, g1_var,
                                   Ag, Bg, Aa, Ba);

    // casts: x -> bf16; weights -> transposed bf16
    cast_x_k<<<(NN * FD / 4 + 255) / 256, 256, 0, stream>>>(x, xb);
    trcast_k<<<(FD * HD + 255) / 256, 256, 0, stream>>>(w_gcn, wgT, FD, HD);
    trcast_k<<<(HD * OD + 255) / 256, 256, 0, stream>>>(w_gat, wgatT, HD, OD);

    // GCN linear: h0 = x @ w_gcn   (bf16 MFMA)
    gemm_bf16<<<dim3((NN + 127) / 128, HD / 64), 256, 0, stream>>>(xb, wgT, h0b, NN, HD);

    // attention weight pre-projection
    wa_k<<<4, 256, 0, stream>>>(w_gat, a_src, a_dst, wa);

    // GCN aggregate + BN2 + ReLU
    gcn_agg2_k<<<NN / 4, 256, 0, stream>>>(h0b, rowptr, csr, dis, Ag, Bg, hb);

    // asrc/adst projection
    attn_dots_k<<<(NN + 31) / 32, 256, 0, stream>>>(hb, wa, asrc, adst);

    // per-edge softmax numerators + per-node inverse sums (single pass)
    alpha_k<<<NN / 4, 256, 0, stream>>>(asrc, adst, rowptr, csr, pexp, inv_s);

    // z gather: per-head weighted sums of h rows
    zgather_k<<<NN / 4, 256, 0, stream>>>(hb, rowptr, csr, pexp, inv_s, zb);

    // per-head GEMM + BN1 + ReLU -> ofeat (bf16)
    gemm_z_k<<<dim3((NN + 127) / 128, HD / 64, NHD), 256, 0, stream>>>(zb, wgatT, Aa, Ba, ofeat);

    // pooling
    pool_k<<<dim3(NG, 2), 256, 0, stream>>>(ofeat, batch, feat);

    // head
    head_k<<<NG, 256, 0, stream>>>(feat, w_lin, b_lin, out);
}

// Round 7
// 358.123 us; speedup vs baseline: 2.1713x; 1.1772x over previous
//
#include <hip/hip_runtime.h>

#define NN 50000          // nodes
#define NE 800000         // edges (without self loops)
#define NE2 (NE + NN)     // edges + self loops
#define FD 128            // input feature dim
#define HD 128            // hidden dim
#define NHD 4             // heads
#define OD 512            // heads * HD
#define NG 512            // graphs
#define BN_EPS 1e-5f

#define SCAN_CHUNK 2048
#define NB_SCAN ((NN + SCAN_CHUNK - 1) / SCAN_CHUNK)   // 25

typedef __attribute__((ext_vector_type(8))) short bfrag;   // 8 bf16 = 4 VGPRs
typedef __attribute__((ext_vector_type(4))) float f32x4;
typedef unsigned short ushort_t;

__device__ inline ushort_t f2bf(float f) {               // RNE fp32->bf16
    unsigned int u = __float_as_uint(f);
    unsigned int r = (u + 0x7fffu + ((u >> 16) & 1u)) >> 16;
    return (ushort_t)r;
}
__device__ inline float bf2f_lo(unsigned int v) { return __uint_as_float(v << 16); }
__device__ inline float bf2f_hi(unsigned int v) { return __uint_as_float(v & 0xffff0000u); }
__device__ inline float lk(float x) { return fmaxf(x, 0.2f * x); }   // leaky_relu 0.2

// ---------------- CSR build ----------------
__global__ void init_k(int* __restrict__ deg, int* __restrict__ fill) {
    int i = blockIdx.x * blockDim.x + threadIdx.x;
    if (i < NN) { deg[i] = 1; fill[i] = 0; }   // 1 = self loop
}

__global__ void count_k(const int* __restrict__ ei, int* __restrict__ deg) {
    int e = blockIdx.x * blockDim.x + threadIdx.x;
    if (e < NE) atomicAdd(&deg[ei[NE + e]], 1);
}

// phase A: per-block sums of 2048-element chunks
__global__ __launch_bounds__(256) void scanA_k(const int* __restrict__ deg,
                                               int* __restrict__ bsum) {
    __shared__ int red[256];
    int b = blockIdx.x, t = threadIdx.x;
    int base = b * SCAN_CHUNK + t * 8;
    int s = 0;
    #pragma unroll
    for (int i = 0; i < 8; ++i) { int idx = base + i; if (idx < NN) s += deg[idx]; }
    red[t] = s;
    __syncthreads();
    for (int off = 128; off; off >>= 1) {
        if (t < off) red[t] += red[t + off];
        __syncthreads();
    }
    if (t == 0) bsum[b] = red[0];
}

// phase B: exclusive scan of 25 block sums
__global__ void scanB_k(const int* __restrict__ bsum, int* __restrict__ boff) {
    if (threadIdx.x == 0) {
        int run = 0;
        for (int i = 0; i < NB_SCAN; ++i) { boff[i] = run; run += bsum[i]; }
    }
}

// phase C: block-local scan + global offset -> rowptr; fused dis = rsqrt(deg)
__global__ __launch_bounds__(256) void scanC_k(const int* __restrict__ deg,
                                               const int* __restrict__ boff,
                                               int* __restrict__ rowptr,
                                               float* __restrict__ dis) {
    __shared__ int red[256];
    int b = blockIdx.x, t = threadIdx.x;
    int base = b * SCAN_CHUNK + t * 8;
    int v[8];
    int s = 0;
    #pragma unroll
    for (int i = 0; i < 8; ++i) {
        int idx = base + i;
        v[i] = (idx < NN) ? deg[idx] : 0;
        s += v[i];
    }
    red[t] = s;
    __syncthreads();
    for (int off = 1; off < 256; off <<= 1) {
        int y = (t >= off) ? red[t - off] : 0;
        __syncthreads();
        red[t] += y;
        __syncthreads();
    }
    int run = boff[b] + red[t] - s;     // exclusive prefix for this thread
    #pragma unroll
    for (int i = 0; i < 8; ++i) {
        int idx = base + i;
        if (idx < NN) {
            rowptr[idx] = run;
            run += v[i];
            dis[idx] = rsqrtf((float)v[i]);
        }
    }
    if (b == 0 && t == 0) rowptr[NN] = NE2;
}

__global__ void fill_k(const int* __restrict__ ei, const int* __restrict__ rowptr,
                       int* __restrict__ fill, int* __restrict__ csr) {
    int e = blockIdx.x * blockDim.x + threadIdx.x;
    if (e >= NE2) return;
    int src, dst;
    if (e < NE) { src = ei[e]; dst = ei[NE + e]; }
    else        { src = e - NE; dst = e - NE; }
    int pos = atomicAdd(&fill[dst], 1);
    csr[rowptr[dst] + pos] = src;
}

// ---------------- BN -> affine precompute ----------------
__global__ void bnaff_k(const float* __restrict__ b_gcn, const float* __restrict__ g2_gam,
                        const float* __restrict__ g2_bet, const float* __restrict__ g2_mean,
                        const float* __restrict__ g2_var, const float* __restrict__ b_gat,
                        const float* __restrict__ g1_gam, const float* __restrict__ g1_bet,
                        const float* __restrict__ g1_mean, const float* __restrict__ g1_var,
                        float* __restrict__ Ag, float* __restrict__ Bg,
                        float* __restrict__ Aa, float* __restrict__ Ba) {
    int t = blockIdx.x * blockDim.x + threadIdx.x;
    if (t < HD) {
        float a = rsqrtf(g2_var[t] + BN_EPS) * g2_gam[t];
        Ag[t] = a;
        Bg[t] = (b_gcn[t] - g2_mean[t]) * a + g2_bet[t];
    } else if (t < HD + OD) {
        int d = t - HD;
        float a = rsqrtf(g1_var[d] + BN_EPS) * g1_gam[d];
        Aa[d] = a;
        Ba[d] = (b_gat[d] - g1_mean[d]) * a + g1_bet[d];
    }
}

// ---------------- casts ----------------
__global__ void cast_x_k(const float* __restrict__ x, ushort_t* __restrict__ xb) {
    int t = blockIdx.x * blockDim.x + threadIdx.x;      // one float4 per thread
    const int total = NN * FD / 4;
    if (t >= total) return;
    float4 v = ((const float4*)x)[t];
    ushort_t o[4] = {f2bf(v.x), f2bf(v.y), f2bf(v.z), f2bf(v.w)};
    *(unsigned long long*)(xb + 4 * t) = *(unsigned long long*)o;
}

// wT[n*K + k] = bf16(w[k*N + n])
__global__ void trcast_k(const float* __restrict__ w, ushort_t* __restrict__ wT,
                         int K, int N) {
    int t = blockIdx.x * blockDim.x + threadIdx.x;
    if (t >= K * N) return;
    int n = t / K, k = t - n * K;
    wT[n * K + k] = f2bf(w[k * N + n]);
}

// ---------------- bf16 MFMA GEMM: C[M,N] = A[M,128] @ B[128,N], C stored bf16
__global__ __launch_bounds__(256) void gemm_bf16(const ushort_t* __restrict__ A,
                                                 const ushort_t* __restrict__ BT,
                                                 ushort_t* __restrict__ C,
                                                 int M, int N) {
    __shared__ short As[128][136];
    __shared__ short Bs[64][136];
    const int tid = threadIdx.x;
    const int m0 = blockIdx.x * 128;
    const int n0 = blockIdx.y * 64;

    #pragma unroll
    for (int i = 0; i < 8; ++i) {
        int c = tid + 256 * i;
        int row = c >> 4, off = (c & 15) * 8;
        bfrag v = (bfrag)0;
        if (m0 + row < M) v = *(const bfrag*)(A + (size_t)(m0 + row) * 128 + off);
        *(bfrag*)&As[row][off] = v;
    }
    #pragma unroll
    for (int i = 0; i < 4; ++i) {
        int c = tid + 256 * i;
        int row = c >> 4, off = (c & 15) * 8;
        *(bfrag*)&Bs[row][off] = *(const bfrag*)(BT + (size_t)(n0 + row) * 128 + off);
    }
    __syncthreads();

    const int w = tid >> 6;
    const int lr = tid & 15;
    const int kg = (tid & 63) >> 4;

    f32x4 acc[2][4];
    #pragma unroll
    for (int mi = 0; mi < 2; ++mi)
        #pragma unroll
        for (int ni = 0; ni < 4; ++ni) acc[mi][ni] = (f32x4)0.f;

    #pragma unroll
    for (int ks = 0; ks < 4; ++ks) {
        bfrag af[2], bb[4];
        #pragma unroll
        for (int mi = 0; mi < 2; ++mi)
            af[mi] = *(const bfrag*)&As[32 * w + 16 * mi + lr][32 * ks + 8 * kg];
        #pragma unroll
        for (int ni = 0; ni < 4; ++ni)
            bb[ni] = *(const bfrag*)&Bs[16 * ni + lr][32 * ks + 8 * kg];
        #pragma unroll
        for (int mi = 0; mi < 2; ++mi)
            #pragma unroll
            for (int ni = 0; ni < 4; ++ni)
                acc[mi][ni] = __builtin_amdgcn_mfma_f32_16x16x32_bf16(
                    af[mi], bb[ni], acc[mi][ni], 0, 0, 0);
    }

    #pragma unroll
    for (int mi = 0; mi < 2; ++mi) {
        #pragma unroll
        for (int r = 0; r < 4; ++r) {
            int row = m0 + 32 * w + 16 * mi + 4 * kg + r;
            if (row < M) {
                #pragma unroll
                for (int ni = 0; ni < 4; ++ni) {
                    int col = n0 + 16 * ni + lr;
                    C[(size_t)row * N + col] = f2bf(acc[mi][ni][r]);
                }
            }
        }
    }
}

// ---------------- per-head GEMM: ofeat[:,128h:128h+128] = relu(BN(z_h @ W_h)), bf16 out
__global__ __launch_bounds__(256) void gemm_z_k(const ushort_t* __restrict__ zb,
                                                const ushort_t* __restrict__ wgatT,
                                                const float* __restrict__ Aa,
                                                const float* __restrict__ Ba,
                                                ushort_t* __restrict__ ofeat) {
    __shared__ short As[128][136];
    __shared__ short Bs[64][136];
    const int tid = threadIdx.x;
    const int head = blockIdx.z;
    const int m0 = blockIdx.x * 128;
    const int n0 = blockIdx.y * 64;
    const ushort_t* A = zb + (size_t)head * NN * HD;
    const ushort_t* BT = wgatT + (size_t)head * HD * HD;

    #pragma unroll
    for (int i = 0; i < 8; ++i) {
        int c = tid + 256 * i;
        int row = c >> 4, off = (c & 15) * 8;
        bfrag v = (bfrag)0;
        if (m0 + row < NN) v = *(const bfrag*)(A + (size_t)(m0 + row) * HD + off);
        *(bfrag*)&As[row][off] = v;
    }
    #pragma unroll
    for (int i = 0; i < 4; ++i) {
        int c = tid + 256 * i;
        int row = c >> 4, off = (c & 15) * 8;
        *(bfrag*)&Bs[row][off] = *(const bfrag*)(BT + (size_t)(n0 + row) * HD + off);
    }
    __syncthreads();

    const int w = tid >> 6;
    const int lr = tid & 15;
    const int kg = (tid & 63) >> 4;

    f32x4 acc[2][4];
    #pragma unroll
    for (int mi = 0; mi < 2; ++mi)
        #pragma unroll
        for (int ni = 0; ni < 4; ++ni) acc[mi][ni] = (f32x4)0.f;

    #pragma unroll
    for (int ks = 0; ks < 4; ++ks) {
        bfrag af[2], bb[4];
        #pragma unroll
        for (int mi = 0; mi < 2; ++mi)
            af[mi] = *(const bfrag*)&As[32 * w + 16 * mi + lr][32 * ks + 8 * kg];
        #pragma unroll
        for (int ni = 0; ni < 4; ++ni)
            bb[ni] = *(const bfrag*)&Bs[16 * ni + lr][32 * ks + 8 * kg];
        #pragma unroll
        for (int mi = 0; mi < 2; ++mi)
            #pragma unroll
            for (int ni = 0; ni < 4; ++ni)
                acc[mi][ni] = __builtin_amdgcn_mfma_f32_16x16x32_bf16(
                    af[mi], bb[ni], acc[mi][ni], 0, 0, 0);
    }

    #pragma unroll
    for (int mi = 0; mi < 2; ++mi) {
        #pragma unroll
        for (int r = 0; r < 4; ++r) {
            int row = m0 + 32 * w + 16 * mi + 4 * kg + r;
            if (row < NN) {
                #pragma unroll
                for (int ni = 0; ni < 4; ++ni) {
                    int gc = 128 * head + n0 + 16 * ni + lr;
                    float v = fmaf(acc[mi][ni][r], Aa[gc], Ba[gc]);
                    ofeat[(size_t)row * OD + gc] = f2bf(fmaxf(v, 0.f));
                }
            }
        }
    }
}

// ---------------- precompute wa[k][j]: j<4 -> w_gat col-block . a_src[head] ----------------
__global__ void wa_k(const float* __restrict__ w_gat, const float* __restrict__ a_src,
                     const float* __restrict__ a_dst, float* __restrict__ wa) {
    int t = blockIdx.x * blockDim.x + threadIdx.x;
    if (t >= 128 * 8) return;
    int k = t >> 3, j = t & 7, head = j & 3;
    const float* av = (j < 4 ? a_src : a_dst) + head * 128;
    const float* w = w_gat + (size_t)k * OD + head * 128;
    float s = 0.f;
    for (int d = 0; d < 128; ++d) s += w[d] * av[d];
    wa[k * 8 + j] = s;
}

// ---------------- GCN aggregate: wave/node, scalarized indices, 8-deep pipeline ----------------
__global__ __launch_bounds__(256) void gcn_agg2_k(
    const ushort_t* __restrict__ h0, const int* __restrict__ rowptr,
    const int* __restrict__ csr, const float* __restrict__ dis,
    const float* __restrict__ Ag, const float* __restrict__ Bg,
    ushort_t* __restrict__ h) {
    int lane = threadIdx.x & 63;
    int n = __builtin_amdgcn_readfirstlane((int)(blockIdx.x * 4) + (int)(threadIdx.x >> 6));
    int r0 = __builtin_amdgcn_readfirstlane(rowptr[n]);
    int r1 = __builtin_amdgcn_readfirstlane(rowptr[n + 1]);
    int d = 2 * lane;
    const ushort_t* h0d = h0 + d;
    float a0 = 0.f, a1 = 0.f;
    unsigned int hv[8];
    float wv[8];

#define GLOAD(i, IDX) { int _e = (IDX); int _ec = _e < r1 ? _e : r1 - 1; \
    int _s = csr[_ec]; float _w = dis[_s]; \
    wv[i] = _e < r1 ? _w : 0.f; \
    hv[i] = *(const unsigned int*)(h0d + ((unsigned)_s << 7)); }
#define GACC(i) { a0 = fmaf(wv[i], bf2f_lo(hv[i]), a0); a1 = fmaf(wv[i], bf2f_hi(hv[i]), a1); }

    GLOAD(0, r0 + 0) GLOAD(1, r0 + 1) GLOAD(2, r0 + 2) GLOAD(3, r0 + 3)
    GLOAD(4, r0 + 4) GLOAD(5, r0 + 5) GLOAD(6, r0 + 6) GLOAD(7, r0 + 7)
    for (int base = r0; base < r1; base += 8) {
        GACC(0) GLOAD(0, base + 8)
        GACC(1) GLOAD(1, base + 9)
        GACC(2) GLOAD(2, base + 10)
        GACC(3) GLOAD(3, base + 11)
        GACC(4) GLOAD(4, base + 12)
        GACC(5) GLOAD(5, base + 13)
        GACC(6) GLOAD(6, base + 14)
        GACC(7) GLOAD(7, base + 15)
    }
#undef GLOAD
#undef GACC

    float t = dis[n];
    float2 A = *(const float2*)(Ag + d);
    float2 B = *(const float2*)(Bg + d);
    float o0 = fmaxf(fmaf(a0 * t, A.x, B.x), 0.f);
    float o1 = fmaxf(fmaf(a1 * t, A.y, B.y), 0.f);
    unsigned int packed = (unsigned int)f2bf(o0) | ((unsigned int)f2bf(o1) << 16);
    *(unsigned int*)(h + (size_t)n * HD + d) = packed;
}

// ---------------- asrc/adst: [N,128] @ wa[128,8] ----------------
__global__ __launch_bounds__(256) void attn_dots_k(const ushort_t* __restrict__ h,
                                                   const float* __restrict__ wa,
                                                   float* __restrict__ asrc,
                                                   float* __restrict__ adst) {
    __shared__ float was[128][8];
    int tid = threadIdx.x;
    for (int i = tid; i < 1024; i += 256) was[i >> 3][i & 7] = wa[i];
    __syncthreads();
    int nl = tid >> 3, j = tid & 7;
    int n = blockIdx.x * 32 + nl;
    if (n >= NN) return;
    const ushort_t* hr = h + (size_t)n * HD;
    float s = 0.f;
    #pragma unroll 4
    for (int i = 0; i < 64; ++i) {
        unsigned int hv = *(const unsigned int*)(hr + 2 * i);
        s += bf2f_lo(hv) * was[2 * i][j] + bf2f_hi(hv) * was[2 * i + 1][j];
    }
    if (j < 4) asrc[n * 4 + j] = s;
    else       adst[n * 4 + (j - 4)] = s;
}

// ---------------- per-edge softmax numerators + per-node inverse sums (single pass, no max)
__global__ __launch_bounds__(256) void alpha_k(
    const float* __restrict__ asrc, const float* __restrict__ adst,
    const int* __restrict__ rowptr, const int* __restrict__ csr,
    float* __restrict__ pexp, float* __restrict__ inv_s) {
    int lane = threadIdx.x & 63;
    int n = __builtin_amdgcn_readfirstlane((int)(blockIdx.x * 4) + (int)(threadIdx.x >> 6));
    int r0 = __builtin_amdgcn_readfirstlane(rowptr[n]);
    int r1 = __builtin_amdgcn_readfirstlane(rowptr[n + 1]);
    float4 ad = *(const float4*)(adst + n * 4);
    float s0 = 0.f, s1 = 0.f, s2 = 0.f, s3 = 0.f;
    for (int base = r0; base < r1; base += 64) {
        int e = base + lane;
        if (e < r1) {
            int src = csr[e];
            float4 as = *(const float4*)(asrc + src * 4);
            float p0 = __expf(lk(as.x + ad.x));
            float p1 = __expf(lk(as.y + ad.y));
            float p2 = __expf(lk(as.z + ad.z));
            float p3 = __expf(lk(as.w + ad.w));
            s0 += p0; s1 += p1; s2 += p2; s3 += p3;
            *(float4*)(pexp + 4 * (size_t)e) = make_float4(p0, p1, p2, p3);
        }
    }
    #pragma unroll
    for (int o = 32; o; o >>= 1) {
        s0 += __shfl_xor(s0, o);
        s1 += __shfl_xor(s1, o);
        s2 += __shfl_xor(s2, o);
        s3 += __shfl_xor(s3, o);
    }
    if (lane == 0) {
        *(float4*)(inv_s + 4 * n) = make_float4(
            1.f / (s0 + 1e-16f), 1.f / (s1 + 1e-16f),
            1.f / (s2 + 1e-16f), 1.f / (s3 + 1e-16f));
    }
}

// ---------------- z gather: z_h[n,:] = inv_s[n,h] * sum_e p[e,h] * h[src_e,:]
__global__ __launch_bounds__(256) void zgather_k(
    const ushort_t* __restrict__ h, const int* __restrict__ rowptr,
    const int* __restrict__ csr, const float* __restrict__ pexp,
    const float* __restrict__ inv_s, ushort_t* __restrict__ zb) {
    int lane = threadIdx.x & 63;
    int n = __builtin_amdgcn_readfirstlane((int)(blockIdx.x * 4) + (int)(threadIdx.x >> 6));
    int r0 = __builtin_amdgcn_readfirstlane(rowptr[n]);
    int r1 = __builtin_amdgcn_readfirstlane(rowptr[n + 1]);
    int d = 2 * lane;
    const ushort_t* hd = h + d;
    float acc[8] = {0.f, 0.f, 0.f, 0.f, 0.f, 0.f, 0.f, 0.f};
    unsigned int hv[8];
    float4 pv[8];

#define ZLOAD(i, IDX) { int _e = (IDX); int _ec = _e < r1 ? _e : r1 - 1; \
    int _s = csr[_ec]; \
    float4 _p = *(const float4*)(pexp + 4 * (size_t)_ec); \
    bool _v = _e < r1; \
    pv[i].x = _v ? _p.x : 0.f; pv[i].y = _v ? _p.y : 0.f; \
    pv[i].z = _v ? _p.z : 0.f; pv[i].w = _v ? _p.w : 0.f; \
    hv[i] = *(const unsigned int*)(hd + ((unsigned)_s << 7)); }
#define ZACC(i) { float _lo = bf2f_lo(hv[i]), _hi = bf2f_hi(hv[i]); \
    acc[0] = fmaf(pv[i].x, _lo, acc[0]); acc[1] = fmaf(pv[i].x, _hi, acc[1]); \
    acc[2] = fmaf(pv[i].y, _lo, acc[2]); acc[3] = fmaf(pv[i].y, _hi, acc[3]); \
    acc[4] = fmaf(pv[i].z, _lo, acc[4]); acc[5] = fmaf(pv[i].z, _hi, acc[5]); \
    acc[6] = fmaf(pv[i].w, _lo, acc[6]); acc[7] = fmaf(pv[i].w, _hi, acc[7]); }

    ZLOAD(0, r0 + 0) ZLOAD(1, r0 + 1) ZLOAD(2, r0 + 2) ZLOAD(3, r0 + 3)
    ZLOAD(4, r0 + 4) ZLOAD(5, r0 + 5) ZLOAD(6, r0 + 6) ZLOAD(7, r0 + 7)
    for (int base = r0; base < r1; base += 8) {
        ZACC(0) ZLOAD(0, base + 8)
        ZACC(1) ZLOAD(1, base + 9)
        ZACC(2) ZLOAD(2, base + 10)
        ZACC(3) ZLOAD(3, base + 11)
        ZACC(4) ZLOAD(4, base + 12)
        ZACC(5) ZLOAD(5, base + 13)
        ZACC(6) ZLOAD(6, base + 14)
        ZACC(7) ZLOAD(7, base + 15)
    }
#undef ZLOAD
#undef ZACC

    float4 is = *(const float4*)(inv_s + 4 * n);
    size_t base = (size_t)n * HD + d;
    unsigned int pk;
    pk = (unsigned int)f2bf(acc[0] * is.x) | ((unsigned int)f2bf(acc[1] * is.x) << 16);
    *(unsigned int*)(zb + 0 * (size_t)NN * HD + base) = pk;
    pk = (unsigned int)f2bf(acc[2] * is.y) | ((unsigned int)f2bf(acc[3] * is.y) << 16);
    *(unsigned int*)(zb + 1 * (size_t)NN * HD + base) = pk;
    pk = (unsigned int)f2bf(acc[4] * is.z) | ((unsigned int)f2bf(acc[5] * is.z) << 16);
    *(unsigned int*)(zb + 2 * (size_t)NN * HD + base) = pk;
    pk = (unsigned int)f2bf(acc[6] * is.w) | ((unsigned int)f2bf(acc[7] * is.w) << 16);
    *(unsigned int*)(zb + 3 * (size_t)NN * HD + base) = pk;
}

// ---------------- pooling: one (graph, 256-dim half) per block, bf16 ofeat ----------------
__global__ __launch_bounds__(256) void pool_k(const ushort_t* __restrict__ outfeat,
                                              const int* __restrict__ batch,
                                              float* __restrict__ feat) {
    int g = blockIdx.x;
    int d = blockIdx.y * 256 + threadIdx.x;
    int lo = 0, hi = NN;
    while (lo < hi) { int mid = (lo + hi) >> 1; if (batch[mid] < g) lo = mid + 1; else hi = mid; }
    int start = lo;
    hi = NN;
    while (lo < hi) { int mid = (lo + hi) >> 1; if (batch[mid] < g + 1) lo = mid + 1; else hi = mid; }
    int end = lo;
    int cnt = end - start;
    float sadd = 0.f, smax = -3.402823466e38f;
    for (int i = start; i < end; ++i) {
        float v = bf2f_lo((unsigned int)outfeat[(size_t)i * OD + d]);
        sadd += v;
        smax = fmaxf(smax, v);
    }
    float smean;
    if (cnt > 0) { smean = sadd / (float)cnt; }
    else { sadd = 0.f; smax = 0.f; smean = 0.f; }
    feat[g * 1536 + d] = sadd;
    feat[g * 1536 + 512 + d] = smax;
    feat[g * 1536 + 1024 + d] = smean;
}

// ---------------- head: out = sigmoid(feat @ w_lin + b_lin) ----------------
__global__ __launch_bounds__(256) void head_k(const float* __restrict__ feat,
                                              const float* __restrict__ w_lin,
                                              const float* __restrict__ b_lin,
                                              float* __restrict__ out) {
    __shared__ float red[256];
    int g = blockIdx.x;
    int t = threadIdx.x;
    int o = t & 15, part = t >> 4;
    float s = 0.f;
    int kbeg = part * 96;
    for (int k = kbeg; k < kbeg + 96; ++k) s += feat[g * 1536 + k] * w_lin[k * 16 + o];
    red[t] = s;
    __syncthreads();
    if (t < 16) {
        float tot = b_lin[o];
        for (int p = 0; p < 16; ++p) tot += red[p * 16 + o];
        out[g * 16 + o] = 1.f / (1.f + __expf(-tot));
    }
}

extern "C" void kernel_launch(void* const* d_in, const int* in_sizes, int n_in,
                              void* d_out, int out_size, void* d_ws, size_t ws_size,
                              hipStream_t stream) {
    const float* x       = (const float*)d_in[0];
    const int*   ei      = (const int*)d_in[1];
    const int*   batch   = (const int*)d_in[2];
    const float* w_gcn   = (const float*)d_in[3];
    const float* b_gcn   = (const float*)d_in[4];
    const float* g2_gam  = (const float*)d_in[5];
    const float* g2_bet  = (const float*)d_in[6];
    const float* g2_mean = (const float*)d_in[7];
    const float* g2_var  = (const float*)d_in[8];
    const float* w_gat   = (const float*)d_in[9];
    const float* a_src   = (const float*)d_in[10];
    const float* a_dst   = (const float*)d_in[11];
    const float* b_gat   = (const float*)d_in[12];
    const float* g1_gam  = (const float*)d_in[13];
    const float* g1_bet  = (const float*)d_in[14];
    const float* g1_mean = (const float*)d_in[15];
    const float* g1_var  = (const float*)d_in[16];
    const float* w_lin   = (const float*)d_in[17];
    const float* b_lin   = (const float*)d_in[18];
    float* out = (float*)d_out;

    char* ws = (char*)d_ws;
    size_t off = 0;
    auto alloc = [&](size_t bytes) -> void* {
        void* p = ws + off;
        off += (bytes + 255) & ~(size_t)255;
        return p;
    };
    int* deg        = (int*)alloc((size_t)NN * 4);
    int* fill       = (int*)alloc((size_t)NN * 4);
    int* rowptr     = (int*)alloc((size_t)(NN + 1) * 4);
    int* csr        = (int*)alloc((size_t)NE2 * 4);
    int* bsum       = (int*)alloc((size_t)NB_SCAN * 4);
    int* boff       = (int*)alloc((size_t)NB_SCAN * 4);
    float* dis      = (float*)alloc((size_t)NN * 4);
    ushort_t* xb    = (ushort_t*)alloc((size_t)NN * FD * 2);
    ushort_t* wgT   = (ushort_t*)alloc((size_t)FD * HD * 2);
    ushort_t* wgatT = (ushort_t*)alloc((size_t)HD * OD * 2);
    ushort_t* h0b   = (ushort_t*)alloc((size_t)NN * HD * 2);
    ushort_t* hb    = (ushort_t*)alloc((size_t)NN * HD * 2);
    ushort_t* zb    = (ushort_t*)alloc((size_t)NHD * NN * HD * 2);
    float* asrc     = (float*)alloc((size_t)NN * 4 * 4);
    float* adst     = (float*)alloc((size_t)NN * 4 * 4);
    float* wa       = (float*)alloc((size_t)128 * 8 * 4);
    float* Ag       = (float*)alloc((size_t)HD * 4);
    float* Bg       = (float*)alloc((size_t)HD * 4);
    float* Aa       = (float*)alloc((size_t)OD * 4);
    float* Ba       = (float*)alloc((size_t)OD * 4);
    float* pexp     = (float*)alloc((size_t)NE2 * 4 * 4);
    float* inv_s    = (float*)alloc((size_t)NN * 4 * 4);
    ushort_t* ofeat = (ushort_t*)alloc((size_t)NN * OD * 2);
    float* feat     = (float*)alloc((size_t)NG * 1536 * 4);

    // CSR build (multi-block scan; dis fused into phase C)
    init_k<<<(NN + 255) / 256, 256, 0, stream>>>(deg, fill);
    count_k<<<(NE + 255) / 256, 256, 0, stream>>>(ei, deg);
    scanA_k<<<NB_SCAN, 256, 0, stream>>>(deg, bsum);
    scanB_k<<<1, 64, 0, stream>>>(bsum, boff);
    scanC_k<<<NB_SCAN, 256, 0, stream>>>(deg, boff, rowptr, dis);
    fill_k<<<(NE2 + 255) / 256, 256, 0, stream>>>(ei, rowptr, fill, csr);

    // BN affine params
    bnaff_k<<<3, 256, 0, stream>>>(b_gcn, g2_gam, g2_bet, g2_mean, g2_var,
                                   b_gat, g1_gam, g1_bet, g1_mean, g1_var,
                                   Ag, Bg, Aa, Ba);

    // casts: x -> bf16; weights -> transposed bf16
    cast_x_k<<<(NN * FD / 4 + 255) / 256, 256, 0, stream>>>(x, xb);
    trcast_k<<<(FD * HD + 255) / 256, 256, 0, stream>>>(w_gcn, wgT, FD, HD);
    trcast_k<<<(HD * OD + 255) / 256, 256, 0, stream>>>(w_gat, wgatT, HD, OD);

    // GCN linear: h0 = x @ w_gcn   (bf16 MFMA)
    gemm_bf16<<<dim3((NN + 127) / 128, HD / 64), 256, 0, stream>>>(xb, wgT, h0b, NN, HD);

    // attention weight pre-projection
    wa_k<<<4, 256, 0, stream>>>(w_gat, a_src, a_dst, wa);

    // GCN aggregate + BN2 + ReLU
    gcn_agg2_k<<<NN / 4, 256, 0, stream>>>(h0b, rowptr, csr, dis, Ag, Bg, hb);

    // asrc/adst projection
    attn_dots_k<<<(NN + 31) / 32, 256, 0, stream>>>(hb, wa, asrc, adst);

    // per-edge softmax numerators + per-node inverse sums (single pass)
    alpha_k<<<NN / 4, 256, 0, stream>>>(asrc, adst, rowptr, csr, pexp, inv_s);

    // z gather: per-head weighted sums of h rows
    zgather_k<<<NN / 4, 256, 0, stream>>>(hb, rowptr, csr, pexp, inv_s, zb);

    // per-head GEMM + BN1 + ReLU -> ofeat (bf16)
    gemm_z_k<<<dim3((NN + 127) / 128, HD / 64, NHD), 256, 0, stream>>>(zb, wgatT, Aa, Ba, ofeat);

    // pooling
    pool_k<<<dim3(NG, 2), 256, 0, stream>>>(ofeat, batch, feat);

    // head
    head_k<<<NG, 256, 0, stream>>>(feat, w_lin, b_lin, out);
}

// Round 8
// 327.231 us; speedup vs baseline: 2.3762x; 1.0944x over previous
//
#include <hip/hip_runtime.h>

#define NN 50000          // nodes
#define NE 800000         // edges (without self loops)
#define NE2 (NE + NN)     // edges + self loops
#define FD 128            // input feature dim
#define HD 128            // hidden dim
#define NHD 4             // heads
#define OD 512            // heads * HD
#define NG 512            // graphs
#define BN_EPS 1e-5f

#define SCAN_CHUNK 2048
#define NB_SCAN ((NN + SCAN_CHUNK - 1) / SCAN_CHUNK)   // 25

typedef __attribute__((ext_vector_type(8))) short bfrag;   // 8 bf16 = 4 VGPRs
typedef __attribute__((ext_vector_type(4))) float f32x4;
typedef unsigned short ushort_t;

__device__ inline ushort_t f2bf(float f) {               // RNE fp32->bf16
    unsigned int u = __float_as_uint(f);
    unsigned int r = (u + 0x7fffu + ((u >> 16) & 1u)) >> 16;
    return (ushort_t)r;
}
__device__ inline float bf2f_lo(unsigned int v) { return __uint_as_float(v << 16); }
__device__ inline float bf2f_hi(unsigned int v) { return __uint_as_float(v & 0xffff0000u); }
__device__ inline float lk(float x) { return fmaxf(x, 0.2f * x); }   // leaky_relu 0.2

// ---------------- CSR build ----------------
__global__ void init_k(int* __restrict__ deg, int* __restrict__ fill) {
    int i = blockIdx.x * blockDim.x + threadIdx.x;
    if (i < NN) { deg[i] = 1; fill[i] = 0; }   // 1 = self loop
}

__global__ void count_k(const int* __restrict__ ei, int* __restrict__ deg) {
    int e = blockIdx.x * blockDim.x + threadIdx.x;
    if (e < NE) atomicAdd(&deg[ei[NE + e]], 1);
}

// phase A: per-block sums of 2048-element chunks
__global__ __launch_bounds__(256) void scanA_k(const int* __restrict__ deg,
                                               int* __restrict__ bsum) {
    __shared__ int red[256];
    int b = blockIdx.x, t = threadIdx.x;
    int base = b * SCAN_CHUNK + t * 8;
    int s = 0;
    #pragma unroll
    for (int i = 0; i < 8; ++i) { int idx = base + i; if (idx < NN) s += deg[idx]; }
    red[t] = s;
    __syncthreads();
    for (int off = 128; off; off >>= 1) {
        if (t < off) red[t] += red[t + off];
        __syncthreads();
    }
    if (t == 0) bsum[b] = red[0];
}

// phase B: exclusive scan of 25 block sums
__global__ void scanB_k(const int* __restrict__ bsum, int* __restrict__ boff) {
    if (threadIdx.x == 0) {
        int run = 0;
        for (int i = 0; i < NB_SCAN; ++i) { boff[i] = run; run += bsum[i]; }
    }
}

// phase C: block-local scan + global offset -> rowptr; fused dis = rsqrt(deg)
__global__ __launch_bounds__(256) void scanC_k(const int* __restrict__ deg,
                                               const int* __restrict__ boff,
                                               int* __restrict__ rowptr,
                                               float* __restrict__ dis) {
    __shared__ int red[256];
    int b = blockIdx.x, t = threadIdx.x;
    int base = b * SCAN_CHUNK + t * 8;
    int v[8];
    int s = 0;
    #pragma unroll
    for (int i = 0; i < 8; ++i) {
        int idx = base + i;
        v[i] = (idx < NN) ? deg[idx] : 0;
        s += v[i];
    }
    red[t] = s;
    __syncthreads();
    for (int off = 1; off < 256; off <<= 1) {
        int y = (t >= off) ? red[t - off] : 0;
        __syncthreads();
        red[t] += y;
        __syncthreads();
    }
    int run = boff[b] + red[t] - s;     // exclusive prefix for this thread
    #pragma unroll
    for (int i = 0; i < 8; ++i) {
        int idx = base + i;
        if (idx < NN) {
            rowptr[idx] = run;
            run += v[i];
            dis[idx] = rsqrtf((float)v[i]);
        }
    }
    if (b == 0 && t == 0) rowptr[NN] = NE2;
}

__global__ void fill_k(const int* __restrict__ ei, const int* __restrict__ rowptr,
                       int* __restrict__ fill, int* __restrict__ csr) {
    int e = blockIdx.x * blockDim.x + threadIdx.x;
    if (e >= NE2) return;
    int src, dst;
    if (e < NE) { src = ei[e]; dst = ei[NE + e]; }
    else        { src = e - NE; dst = e - NE; }
    int pos = atomicAdd(&fill[dst], 1);
    csr[rowptr[dst] + pos] = src;
}

// ---------------- BN -> affine precompute ----------------
__global__ void bnaff_k(const float* __restrict__ b_gcn, const float* __restrict__ g2_gam,
                        const float* __restrict__ g2_bet, const float* __restrict__ g2_mean,
                        const float* __restrict__ g2_var, const float* __restrict__ b_gat,
                        const float* __restrict__ g1_gam, const float* __restrict__ g1_bet,
                        const float* __restrict__ g1_mean, const float* __restrict__ g1_var,
                        float* __restrict__ Ag, float* __restrict__ Bg,
                        float* __restrict__ Aa, float* __restrict__ Ba) {
    int t = blockIdx.x * blockDim.x + threadIdx.x;
    if (t < HD) {
        float a = rsqrtf(g2_var[t] + BN_EPS) * g2_gam[t];
        Ag[t] = a;
        Bg[t] = (b_gcn[t] - g2_mean[t]) * a + g2_bet[t];
    } else if (t < HD + OD) {
        int d = t - HD;
        float a = rsqrtf(g1_var[d] + BN_EPS) * g1_gam[d];
        Aa[d] = a;
        Ba[d] = (b_gat[d] - g1_mean[d]) * a + g1_bet[d];
    }
}

// ---------------- casts ----------------
__global__ void cast_x_k(const float* __restrict__ x, ushort_t* __restrict__ xb) {
    int t = blockIdx.x * blockDim.x + threadIdx.x;      // one float4 per thread
    const int total = NN * FD / 4;
    if (t >= total) return;
    float4 v = ((const float4*)x)[t];
    ushort_t o[4] = {f2bf(v.x), f2bf(v.y), f2bf(v.z), f2bf(v.w)};
    *(unsigned long long*)(xb + 4 * t) = *(unsigned long long*)o;
}

// wT[n*K + k] = bf16(w[k*N + n])
__global__ void trcast_k(const float* __restrict__ w, ushort_t* __restrict__ wT,
                         int K, int N) {
    int t = blockIdx.x * blockDim.x + threadIdx.x;
    if (t >= K * N) return;
    int n = t / K, k = t - n * K;
    wT[n * K + k] = f2bf(w[k * N + n]);
}

// ---------------- bf16 MFMA GEMM: C[M,N] = A[M,128] @ B[128,N], C stored bf16
__global__ __launch_bounds__(256) void gemm_bf16(const ushort_t* __restrict__ A,
                                                 const ushort_t* __restrict__ BT,
                                                 ushort_t* __restrict__ C,
                                                 int M, int N) {
    __shared__ short As[128][136];
    __shared__ short Bs[64][136];
    const int tid = threadIdx.x;
    const int m0 = blockIdx.x * 128;
    const int n0 = blockIdx.y * 64;

    #pragma unroll
    for (int i = 0; i < 8; ++i) {
        int c = tid + 256 * i;
        int row = c >> 4, off = (c & 15) * 8;
        bfrag v = (bfrag)0;
        if (m0 + row < M) v = *(const bfrag*)(A + (size_t)(m0 + row) * 128 + off);
        *(bfrag*)&As[row][off] = v;
    }
    #pragma unroll
    for (int i = 0; i < 4; ++i) {
        int c = tid + 256 * i;
        int row = c >> 4, off = (c & 15) * 8;
        *(bfrag*)&Bs[row][off] = *(const bfrag*)(BT + (size_t)(n0 + row) * 128 + off);
    }
    __syncthreads();

    const int w = tid >> 6;
    const int lr = tid & 15;
    const int kg = (tid & 63) >> 4;

    f32x4 acc[2][4];
    #pragma unroll
    for (int mi = 0; mi < 2; ++mi)
        #pragma unroll
        for (int ni = 0; ni < 4; ++ni) acc[mi][ni] = (f32x4)0.f;

    #pragma unroll
    for (int ks = 0; ks < 4; ++ks) {
        bfrag af[2], bb[4];
        #pragma unroll
        for (int mi = 0; mi < 2; ++mi)
            af[mi] = *(const bfrag*)&As[32 * w + 16 * mi + lr][32 * ks + 8 * kg];
        #pragma unroll
        for (int ni = 0; ni < 4; ++ni)
            bb[ni] = *(const bfrag*)&Bs[16 * ni + lr][32 * ks + 8 * kg];
        #pragma unroll
        for (int mi = 0; mi < 2; ++mi)
            #pragma unroll
            for (int ni = 0; ni < 4; ++ni)
                acc[mi][ni] = __builtin_amdgcn_mfma_f32_16x16x32_bf16(
                    af[mi], bb[ni], acc[mi][ni], 0, 0, 0);
    }

    #pragma unroll
    for (int mi = 0; mi < 2; ++mi) {
        #pragma unroll
        for (int r = 0; r < 4; ++r) {
            int row = m0 + 32 * w + 16 * mi + 4 * kg + r;
            if (row < M) {
                #pragma unroll
                for (int ni = 0; ni < 4; ++ni) {
                    int col = n0 + 16 * ni + lr;
                    C[(size_t)row * N + col] = f2bf(acc[mi][ni][r]);
                }
            }
        }
    }
}

// ---------------- per-head GEMM: ofeat[:,128h:128h+128] = relu(BN(z_h @ W_h)), bf16 out
__global__ __launch_bounds__(256) void gemm_z_k(const ushort_t* __restrict__ zb,
                                                const ushort_t* __restrict__ wgatT,
                                                const float* __restrict__ Aa,
                                                const float* __restrict__ Ba,
                                                ushort_t* __restrict__ ofeat) {
    __shared__ short As[128][136];
    __shared__ short Bs[64][136];
    const int tid = threadIdx.x;
    const int head = blockIdx.z;
    const int m0 = blockIdx.x * 128;
    const int n0 = blockIdx.y * 64;
    const ushort_t* A = zb + (size_t)head * NN * HD;
    const ushort_t* BT = wgatT + (size_t)head * HD * HD;

    #pragma unroll
    for (int i = 0; i < 8; ++i) {
        int c = tid + 256 * i;
        int row = c >> 4, off = (c & 15) * 8;
        bfrag v = (bfrag)0;
        if (m0 + row < NN) v = *(const bfrag*)(A + (size_t)(m0 + row) * HD + off);
        *(bfrag*)&As[row][off] = v;
    }
    #pragma unroll
    for (int i = 0; i < 4; ++i) {
        int c = tid + 256 * i;
        int row = c >> 4, off = (c & 15) * 8;
        *(bfrag*)&Bs[row][off] = *(const bfrag*)(BT + (size_t)(n0 + row) * HD + off);
    }
    __syncthreads();

    const int w = tid >> 6;
    const int lr = tid & 15;
    const int kg = (tid & 63) >> 4;

    f32x4 acc[2][4];
    #pragma unroll
    for (int mi = 0; mi < 2; ++mi)
        #pragma unroll
        for (int ni = 0; ni < 4; ++ni) acc[mi][ni] = (f32x4)0.f;

    #pragma unroll
    for (int ks = 0; ks < 4; ++ks) {
        bfrag af[2], bb[4];
        #pragma unroll
        for (int mi = 0; mi < 2; ++mi)
            af[mi] = *(const bfrag*)&As[32 * w + 16 * mi + lr][32 * ks + 8 * kg];
        #pragma unroll
        for (int ni = 0; ni < 4; ++ni)
            bb[ni] = *(const bfrag*)&Bs[16 * ni + lr][32 * ks + 8 * kg];
        #pragma unroll
        for (int mi = 0; mi < 2; ++mi)
            #pragma unroll
            for (int ni = 0; ni < 4; ++ni)
                acc[mi][ni] = __builtin_amdgcn_mfma_f32_16x16x32_bf16(
                    af[mi], bb[ni], acc[mi][ni], 0, 0, 0);
    }

    #pragma unroll
    for (int mi = 0; mi < 2; ++mi) {
        #pragma unroll
        for (int r = 0; r < 4; ++r) {
            int row = m0 + 32 * w + 16 * mi + 4 * kg + r;
            if (row < NN) {
                #pragma unroll
                for (int ni = 0; ni < 4; ++ni) {
                    int gc = 128 * head + n0 + 16 * ni + lr;
                    float v = fmaf(acc[mi][ni][r], Aa[gc], Ba[gc]);
                    ofeat[(size_t)row * OD + gc] = f2bf(fmaxf(v, 0.f));
                }
            }
        }
    }
}

// ---------------- precompute wa[k][j]: j<4 -> w_gat col-block . a_src[head] ----------------
__global__ void wa_k(const float* __restrict__ w_gat, const float* __restrict__ a_src,
                     const float* __restrict__ a_dst, float* __restrict__ wa) {
    int t = blockIdx.x * blockDim.x + threadIdx.x;
    if (t >= 128 * 8) return;
    int k = t >> 3, j = t & 7, head = j & 3;
    const float* av = (j < 4 ? a_src : a_dst) + head * 128;
    const float* w = w_gat + (size_t)k * OD + head * 128;
    float s = 0.f;
    for (int d = 0; d < 128; ++d) s += w[d] * av[d];
    wa[k * 8 + j] = s;
}

// ---------------- GCN aggregate: wave/node, 16 lanes/edge (4 edges per wave-load) ----------------
__global__ __launch_bounds__(256) void gcn_agg3_k(
    const ushort_t* __restrict__ h0, const int* __restrict__ rowptr,
    const int* __restrict__ csr, const float* __restrict__ dis,
    const float* __restrict__ Ag, const float* __restrict__ Bg,
    ushort_t* __restrict__ h) {
    int lane = threadIdx.x & 63;
    int g = lane >> 4;              // edge sub-slot within wave
    int sl = lane & 15;             // 16-byte dim chunk
    int sl8 = sl * 8;
    int n = __builtin_amdgcn_readfirstlane((int)(blockIdx.x * 4) + (int)(threadIdx.x >> 6));
    int r0 = __builtin_amdgcn_readfirstlane(rowptr[n]);
    int r1 = __builtin_amdgcn_readfirstlane(rowptr[n + 1]);
    float a[8] = {0.f, 0.f, 0.f, 0.f, 0.f, 0.f, 0.f, 0.f};
    uint4 hv[2];
    float wv[2];

#define GLOAD(i, BASE) { int _e = (BASE) + g; int _ec = min(_e, r1 - 1); \
    int _s = csr[_ec]; \
    wv[i] = (_e < r1) ? dis[_s] : 0.f; \
    hv[i] = *(const uint4*)(h0 + ((size_t)(unsigned)_s << 7) + sl8); }
#define GACC(i) { float _w = wv[i]; \
    a[0] = fmaf(_w, bf2f_lo(hv[i].x), a[0]); a[1] = fmaf(_w, bf2f_hi(hv[i].x), a[1]); \
    a[2] = fmaf(_w, bf2f_lo(hv[i].y), a[2]); a[3] = fmaf(_w, bf2f_hi(hv[i].y), a[3]); \
    a[4] = fmaf(_w, bf2f_lo(hv[i].z), a[4]); a[5] = fmaf(_w, bf2f_hi(hv[i].z), a[5]); \
    a[6] = fmaf(_w, bf2f_lo(hv[i].w), a[6]); a[7] = fmaf(_w, bf2f_hi(hv[i].w), a[7]); }

    GLOAD(0, r0) GLOAD(1, r0 + 4)
    for (int base = r0; base < r1; base += 8) {
        GACC(0) GLOAD(0, base + 8)
        GACC(1) GLOAD(1, base + 12)
    }
#undef GLOAD
#undef GACC

    // reduce across the 4 edge groups
    #pragma unroll
    for (int j = 0; j < 8; ++j) {
        a[j] += __shfl_xor(a[j], 16);
        a[j] += __shfl_xor(a[j], 32);
    }
    float t = dis[n];
    float4 A0 = *(const float4*)(Ag + sl8);
    float4 A1 = *(const float4*)(Ag + sl8 + 4);
    float4 B0 = *(const float4*)(Bg + sl8);
    float4 B1 = *(const float4*)(Bg + sl8 + 4);
    float o0 = fmaxf(fmaf(a[0] * t, A0.x, B0.x), 0.f);
    float o1 = fmaxf(fmaf(a[1] * t, A0.y, B0.y), 0.f);
    float o2 = fmaxf(fmaf(a[2] * t, A0.z, B0.z), 0.f);
    float o3 = fmaxf(fmaf(a[3] * t, A0.w, B0.w), 0.f);
    float o4 = fmaxf(fmaf(a[4] * t, A1.x, B1.x), 0.f);
    float o5 = fmaxf(fmaf(a[5] * t, A1.y, B1.y), 0.f);
    float o6 = fmaxf(fmaf(a[6] * t, A1.z, B1.z), 0.f);
    float o7 = fmaxf(fmaf(a[7] * t, A1.w, B1.w), 0.f);
    if (g == 0) {
        uint4 pk;
        pk.x = (unsigned int)f2bf(o0) | ((unsigned int)f2bf(o1) << 16);
        pk.y = (unsigned int)f2bf(o2) | ((unsigned int)f2bf(o3) << 16);
        pk.z = (unsigned int)f2bf(o4) | ((unsigned int)f2bf(o5) << 16);
        pk.w = (unsigned int)f2bf(o6) | ((unsigned int)f2bf(o7) << 16);
        *(uint4*)(h + (size_t)n * HD + sl8) = pk;
    }
}

// ---------------- asrc/adst: [N,128] @ wa[128,8] ----------------
__global__ __launch_bounds__(256) void attn_dots_k(const ushort_t* __restrict__ h,
                                                   const float* __restrict__ wa,
                                                   float* __restrict__ asrc,
                                                   float* __restrict__ adst) {
    __shared__ float was[128][8];
    int tid = threadIdx.x;
    for (int i = tid; i < 1024; i += 256) was[i >> 3][i & 7] = wa[i];
    __syncthreads();
    int nl = tid >> 3, j = tid & 7;
    int n = blockIdx.x * 32 + nl;
    if (n >= NN) return;
    const ushort_t* hr = h + (size_t)n * HD;
    float s = 0.f;
    #pragma unroll 4
    for (int i = 0; i < 64; ++i) {
        unsigned int hv = *(const unsigned int*)(hr + 2 * i);
        s += bf2f_lo(hv) * was[2 * i][j] + bf2f_hi(hv) * was[2 * i + 1][j];
    }
    if (j < 4) asrc[n * 4 + j] = s;
    else       adst[n * 4 + (j - 4)] = s;
}

// ---------------- fused GAT: per-edge softmax numerators + weighted gather ----------------
// wave per node; 16 lanes/edge; z_h[n,:] = (sum_e p_eh h[src_e,:]) / (sum_e p_eh + 1e-16)
__global__ __launch_bounds__(256) void zgather2_k(
    const ushort_t* __restrict__ h, const int* __restrict__ rowptr,
    const int* __restrict__ csr, const float* __restrict__ asrc,
    const float* __restrict__ adst, ushort_t* __restrict__ zb) {
    int lane = threadIdx.x & 63;
    int g = lane >> 4;
    int sl = lane & 15;
    int sl8 = sl * 8;
    int n = __builtin_amdgcn_readfirstlane((int)(blockIdx.x * 4) + (int)(threadIdx.x >> 6));
    int r0 = __builtin_amdgcn_readfirstlane(rowptr[n]);
    int r1 = __builtin_amdgcn_readfirstlane(rowptr[n + 1]);
    float4 ad = *(const float4*)(adst + 4 * n);     // uniform

    float acc[4][8];
    #pragma unroll
    for (int hh = 0; hh < 4; ++hh)
        #pragma unroll
        for (int j = 0; j < 8; ++j) acc[hh][j] = 0.f;
    float s0 = 0.f, s1 = 0.f, s2 = 0.f, s3 = 0.f;

    uint4 hv[2];
    float4 pv[2];

#define ZLOAD(i, BASE) { int _e = (BASE) + g; int _ec = min(_e, r1 - 1); \
    int _s = csr[_ec]; bool _v = _e < r1; \
    float4 _as = *(const float4*)(asrc + 4 * (size_t)_s); \
    pv[i].x = _v ? __expf(lk(_as.x + ad.x)) : 0.f; \
    pv[i].y = _v ? __expf(lk(_as.y + ad.y)) : 0.f; \
    pv[i].z = _v ? __expf(lk(_as.z + ad.z)) : 0.f; \
    pv[i].w = _v ? __expf(lk(_as.w + ad.w)) : 0.f; \
    hv[i] = *(const uint4*)(h + ((size_t)(unsigned)_s << 7) + sl8); }
#define ZACC(i) { \
    float f0 = bf2f_lo(hv[i].x), f1 = bf2f_hi(hv[i].x); \
    float f2 = bf2f_lo(hv[i].y), f3 = bf2f_hi(hv[i].y); \
    float f4 = bf2f_lo(hv[i].z), f5 = bf2f_hi(hv[i].z); \
    float f6 = bf2f_lo(hv[i].w), f7 = bf2f_hi(hv[i].w); \
    float p0 = pv[i].x, p1 = pv[i].y, p2 = pv[i].z, p3 = pv[i].w; \
    s0 += p0; s1 += p1; s2 += p2; s3 += p3; \
    acc[0][0] = fmaf(p0, f0, acc[0][0]); acc[0][1] = fmaf(p0, f1, acc[0][1]); \
    acc[0][2] = fmaf(p0, f2, acc[0][2]); acc[0][3] = fmaf(p0, f3, acc[0][3]); \
    acc[0][4] = fmaf(p0, f4, acc[0][4]); acc[0][5] = fmaf(p0, f5, acc[0][5]); \
    acc[0][6] = fmaf(p0, f6, acc[0][6]); acc[0][7] = fmaf(p0, f7, acc[0][7]); \
    acc[1][0] = fmaf(p1, f0, acc[1][0]); acc[1][1] = fmaf(p1, f1, acc[1][1]); \
    acc[1][2] = fmaf(p1, f2, acc[1][2]); acc[1][3] = fmaf(p1, f3, acc[1][3]); \
    acc[1][4] = fmaf(p1, f4, acc[1][4]); acc[1][5] = fmaf(p1, f5, acc[1][5]); \
    acc[1][6] = fmaf(p1, f6, acc[1][6]); acc[1][7] = fmaf(p1, f7, acc[1][7]); \
    acc[2][0] = fmaf(p2, f0, acc[2][0]); acc[2][1] = fmaf(p2, f1, acc[2][1]); \
    acc[2][2] = fmaf(p2, f2, acc[2][2]); acc[2][3] = fmaf(p2, f3, acc[2][3]); \
    acc[2][4] = fmaf(p2, f4, acc[2][4]); acc[2][5] = fmaf(p2, f5, acc[2][5]); \
    acc[2][6] = fmaf(p2, f6, acc[2][6]); acc[2][7] = fmaf(p2, f7, acc[2][7]); \
    acc[3][0] = fmaf(p3, f0, acc[3][0]); acc[3][1] = fmaf(p3, f1, acc[3][1]); \
    acc[3][2] = fmaf(p3, f2, acc[3][2]); acc[3][3] = fmaf(p3, f3, acc[3][3]); \
    acc[3][4] = fmaf(p3, f4, acc[3][4]); acc[3][5] = fmaf(p3, f5, acc[3][5]); \
    acc[3][6] = fmaf(p3, f6, acc[3][6]); acc[3][7] = fmaf(p3, f7, acc[3][7]); }

    ZLOAD(0, r0) ZLOAD(1, r0 + 4)
    for (int base = r0; base < r1; base += 8) {
        ZACC(0) ZLOAD(0, base + 8)
        ZACC(1) ZLOAD(1, base + 12)
    }
#undef ZLOAD
#undef ZACC

    // reduce across the 4 edge groups
    #pragma unroll
    for (int hh = 0; hh < 4; ++hh)
        #pragma unroll
        for (int j = 0; j < 8; ++j) {
            acc[hh][j] += __shfl_xor(acc[hh][j], 16);
            acc[hh][j] += __shfl_xor(acc[hh][j], 32);
        }
    s0 += __shfl_xor(s0, 16); s0 += __shfl_xor(s0, 32);
    s1 += __shfl_xor(s1, 16); s1 += __shfl_xor(s1, 32);
    s2 += __shfl_xor(s2, 16); s2 += __shfl_xor(s2, 32);
    s3 += __shfl_xor(s3, 16); s3 += __shfl_xor(s3, 32);

    float inv0 = 1.f / (s0 + 1e-16f), inv1 = 1.f / (s1 + 1e-16f);
    float inv2 = 1.f / (s2 + 1e-16f), inv3 = 1.f / (s3 + 1e-16f);
    float invg = (g == 0) ? inv0 : (g == 1) ? inv1 : (g == 2) ? inv2 : inv3;

    float o[8];
    #pragma unroll
    for (int j = 0; j < 8; ++j) {
        float v01 = (g == 1) ? acc[1][j] : acc[0][j];
        float v23 = (g == 3) ? acc[3][j] : acc[2][j];
        o[j] = ((g & 2) ? v23 : v01) * invg;
    }
    uint4 pk;
    pk.x = (unsigned int)f2bf(o[0]) | ((unsigned int)f2bf(o[1]) << 16);
    pk.y = (unsigned int)f2bf(o[2]) | ((unsigned int)f2bf(o[3]) << 16);
    pk.z = (unsigned int)f2bf(o[4]) | ((unsigned int)f2bf(o[5]) << 16);
    pk.w = (unsigned int)f2bf(o[6]) | ((unsigned int)f2bf(o[7]) << 16);
    *(uint4*)(zb + (size_t)g * NN * HD + (size_t)n * HD + sl8) = pk;
}

// ---------------- pooling: one (graph, 256-dim half) per block, bf16 ofeat ----------------
__global__ __launch_bounds__(256) void pool_k(const ushort_t* __restrict__ outfeat,
                                              const int* __restrict__ batch,
                                              float* __restrict__ feat) {
    int g = blockIdx.x;
    int d = blockIdx.y * 256 + threadIdx.x;
    int lo = 0, hi = NN;
    while (lo < hi) { int mid = (lo + hi) >> 1; if (batch[mid] < g) lo = mid + 1; else hi = mid; }
    int start = lo;
    hi = NN;
    while (lo < hi) { int mid = (lo + hi) >> 1; if (batch[mid] < g + 1) lo = mid + 1; else hi = mid; }
    int end = lo;
    int cnt = end - start;
    float sadd = 0.f, smax = -3.402823466e38f;
    for (int i = start; i < end; ++i) {
        float v = bf2f_lo((unsigned int)outfeat[(size_t)i * OD + d]);
        sadd += v;
        smax = fmaxf(smax, v);
    }
    float smean;
    if (cnt > 0) { smean = sadd / (float)cnt; }
    else { sadd = 0.f; smax = 0.f; smean = 0.f; }
    feat[g * 1536 + d] = sadd;
    feat[g * 1536 + 512 + d] = smax;
    feat[g * 1536 + 1024 + d] = smean;
}

// ---------------- head: out = sigmoid(feat @ w_lin + b_lin) ----------------
__global__ __launch_bounds__(256) void head_k(const float* __restrict__ feat,
                                              const float* __restrict__ w_lin,
                                              const float* __restrict__ b_lin,
                                              float* __restrict__ out) {
    __shared__ float red[256];
    int g = blockIdx.x;
    int t = threadIdx.x;
    int o = t & 15, part = t >> 4;
    float s = 0.f;
    int kbeg = part * 96;
    for (int k = kbeg; k < kbeg + 96; ++k) s += feat[g * 1536 + k] * w_lin[k * 16 + o];
    red[t] = s;
    __syncthreads();
    if (t < 16) {
        float tot = b_lin[o];
        for (int p = 0; p < 16; ++p) tot += red[p * 16 + o];
        out[g * 16 + o] = 1.f / (1.f + __expf(-tot));
    }
}

extern "C" void kernel_launch(void* const* d_in, const int* in_sizes, int n_in,
                              void* d_out, int out_size, void* d_ws, size_t ws_size,
                              hipStream_t stream) {
    const float* x       = (const float*)d_in[0];
    const int*   ei      = (const int*)d_in[1];
    const int*   batch   = (const int*)d_in[2];
    const float* w_gcn   = (const float*)d_in[3];
    const float* b_gcn   = (const float*)d_in[4];
    const float* g2_gam  = (const float*)d_in[5];
    const float* g2_bet  = (const float*)d_in[6];
    const float* g2_mean = (const float*)d_in[7];
    const float* g2_var  = (const float*)d_in[8];
    const float* w_gat   = (const float*)d_in[9];
    const float* a_src   = (const float*)d_in[10];
    const float* a_dst   = (const float*)d_in[11];
    const float* b_gat   = (const float*)d_in[12];
    const float* g1_gam  = (const float*)d_in[13];
    const float* g1_bet  = (const float*)d_in[14];
    const float* g1_mean = (const float*)d_in[15];
    const float* g1_var  = (const float*)d_in[16];
    const float* w_lin   = (const float*)d_in[17];
    const float* b_lin   = (const float*)d_in[18];
    float* out = (float*)d_out;

    char* ws = (char*)d_ws;
    size_t off = 0;
    auto alloc = [&](size_t bytes) -> void* {
        void* p = ws + off;
        off += (bytes + 255) & ~(size_t)255;
        return p;
    };
    int* deg        = (int*)alloc((size_t)NN * 4);
    int* fill       = (int*)alloc((size_t)NN * 4);
    int* rowptr     = (int*)alloc((size_t)(NN + 1) * 4);
    int* csr        = (int*)alloc((size_t)NE2 * 4);
    int* bsum       = (int*)alloc((size_t)NB_SCAN * 4);
    int* boff       = (int*)alloc((size_t)NB_SCAN * 4);
    float* dis      = (float*)alloc((size_t)NN * 4);
    ushort_t* xb    = (ushort_t*)alloc((size_t)NN * FD * 2);
    ushort_t* wgT   = (ushort_t*)alloc((size_t)FD * HD * 2);
    ushort_t* wgatT = (ushort_t*)alloc((size_t)HD * OD * 2);
    ushort_t* h0b   = (ushort_t*)alloc((size_t)NN * HD * 2);
    ushort_t* hb    = (ushort_t*)alloc((size_t)NN * HD * 2);
    ushort_t* zb    = (ushort_t*)alloc((size_t)NHD * NN * HD * 2);
    float* asrc     = (float*)alloc((size_t)NN * 4 * 4);
    float* adst     = (float*)alloc((size_t)NN * 4 * 4);
    float* wa       = (float*)alloc((size_t)128 * 8 * 4);
    float* Ag       = (float*)alloc((size_t)HD * 4);
    float* Bg       = (float*)alloc((size_t)HD * 4);
    float* Aa       = (float*)alloc((size_t)OD * 4);
    float* Ba       = (float*)alloc((size_t)OD * 4);
    ushort_t* ofeat = (ushort_t*)alloc((size_t)NN * OD * 2);
    float* feat     = (float*)alloc((size_t)NG * 1536 * 4);

    // CSR build (multi-block scan; dis fused into phase C)
    init_k<<<(NN + 255) / 256, 256, 0, stream>>>(deg, fill);
    count_k<<<(NE + 255) / 256, 256, 0, stream>>>(ei, deg);
    scanA_k<<<NB_SCAN, 256, 0, stream>>>(deg, bsum);
    scanB_k<<<1, 64, 0, stream>>>(bsum, boff);
    scanC_k<<<NB_SCAN, 256, 0, stream>>>(deg, boff, rowptr, dis);
    fill_k<<<(NE2 + 255) / 256, 256, 0, stream>>>(ei, rowptr, fill, csr);

    // BN affine params
    bnaff_k<<<3, 256, 0, stream>>>(b_gcn, g2_gam, g2_bet, g2_mean, g2_var,
                                   b_gat, g1_gam, g1_bet, g1_mean, g1_var,
                                   Ag, Bg, Aa, Ba);

    // casts: x -> bf16; weights -> transposed bf16
    cast_x_k<<<(NN * FD / 4 + 255) / 256, 256, 0, stream>>>(x, xb);
    trcast_k<<<(FD * HD + 255) / 256, 256, 0, stream>>>(w_gcn, wgT, FD, HD);
    trcast_k<<<(HD * OD + 255) / 256, 256, 0, stream>>>(w_gat, wgatT, HD, OD);

    // GCN linear: h0 = x @ w_gcn   (bf16 MFMA)
    gemm_bf16<<<dim3((NN + 127) / 128, HD / 64), 256, 0, stream>>>(xb, wgT, h0b, NN, HD);

    // attention weight pre-projection
    wa_k<<<4, 256, 0, stream>>>(w_gat, a_src, a_dst, wa);

    // GCN aggregate + BN2 + ReLU
    gcn_agg3_k<<<NN / 4, 256, 0, stream>>>(h0b, rowptr, csr, dis, Ag, Bg, hb);

    // asrc/adst projection
    attn_dots_k<<<(NN + 31) / 32, 256, 0, stream>>>(hb, wa, asrc, adst);

    // fused GAT softmax + gather: per-head weighted sums of h rows
    zgather2_k<<<NN / 4, 256, 0, stream>>>(hb, rowptr, csr, asrc, adst, zb);

    // per-head GEMM + BN1 + ReLU -> ofeat (bf16)
    gemm_z_k<<<dim3((NN + 127) / 128, HD / 64, NHD), 256, 0, stream>>>(zb, wgatT, Aa, Ba, ofeat);

    // pooling
    pool_k<<<dim3(NG, 2), 256, 0, stream>>>(ofeat, batch, feat);

    // head
    head_k<<<NG, 256, 0, stream>>>(feat, w_lin, b_lin, out);
}

// Round 9
// 314.901 us; speedup vs baseline: 2.4693x; 1.0392x over previous
//
#include <hip/hip_runtime.h>

#define NN 50000          // nodes
#define NE 800000         // edges (without self loops)
#define NE2 (NE + NN)     // edges + self loops
#define FD 128            // input feature dim
#define HD 128            // hidden dim
#define NHD 4             // heads
#define OD 512            // heads * HD
#define NG 512            // graphs
#define BN_EPS 1e-5f

#define SCAN_CHUNK 2048
#define NB_SCAN ((NN + SCAN_CHUNK - 1) / SCAN_CHUNK)   // 25
#define XB_BLOCKS (NN * FD / 4 / 256)                  // 6250
#define WG_BLOCKS (FD * HD / 256)                      // 64
#define WA_BLOCKS (HD * OD / 256)                      // 256

typedef __attribute__((ext_vector_type(8))) short bfrag;   // 8 bf16 = 4 VGPRs
typedef __attribute__((ext_vector_type(4))) float f32x4;
typedef __attribute__((ext_vector_type(2))) float f32x2;
typedef unsigned short ushort_t;

__device__ inline ushort_t f2bf(float f) {               // RNE fp32->bf16
    unsigned int u = __float_as_uint(f);
    unsigned int r = (u + 0x7fffu + ((u >> 16) & 1u)) >> 16;
    return (ushort_t)r;
}
__device__ inline float bf2f_lo(unsigned int v) { return __uint_as_float(v << 16); }
__device__ inline float bf2f_hi(unsigned int v) { return __uint_as_float(v & 0xffff0000u); }

// ---------------- CSR build ----------------
__global__ void init_k(int* __restrict__ deg, int* __restrict__ fill) {
    int i = blockIdx.x * blockDim.x + threadIdx.x;
    if (i < NN) { deg[i] = 1; fill[i] = 0; }   // 1 = self loop
}

__global__ void count_k(const int* __restrict__ ei, int* __restrict__ deg) {
    int e = blockIdx.x * blockDim.x + threadIdx.x;
    if (e < NE) atomicAdd(&deg[ei[NE + e]], 1);
}

// phase A: per-block sums of 2048-element chunks
__global__ __launch_bounds__(256) void scanA_k(const int* __restrict__ deg,
                                               int* __restrict__ bsum) {
    __shared__ int red[256];
    int b = blockIdx.x, t = threadIdx.x;
    int base = b * SCAN_CHUNK + t * 8;
    int s = 0;
    #pragma unroll
    for (int i = 0; i < 8; ++i) { int idx = base + i; if (idx < NN) s += deg[idx]; }
    red[t] = s;
    __syncthreads();
    for (int off = 128; off; off >>= 1) {
        if (t < off) red[t] += red[t + off];
        __syncthreads();
    }
    if (t == 0) bsum[b] = red[0];
}

// phase B: exclusive scan of 25 block sums
__global__ void scanB_k(const int* __restrict__ bsum, int* __restrict__ boff) {
    if (threadIdx.x == 0) {
        int run = 0;
        for (int i = 0; i < NB_SCAN; ++i) { boff[i] = run; run += bsum[i]; }
    }
}

// phase C: block-local scan + global offset -> rowptr; fused dis = rsqrt(deg)
__global__ __launch_bounds__(256) void scanC_k(const int* __restrict__ deg,
                                               const int* __restrict__ boff,
                                               int* __restrict__ rowptr,
                                               float* __restrict__ dis) {
    __shared__ int red[256];
    int b = blockIdx.x, t = threadIdx.x;
    int base = b * SCAN_CHUNK + t * 8;
    int v[8];
    int s = 0;
    #pragma unroll
    for (int i = 0; i < 8; ++i) {
        int idx = base + i;
        v[i] = (idx < NN) ? deg[idx] : 0;
        s += v[i];
    }
    red[t] = s;
    __syncthreads();
    for (int off = 1; off < 256; off <<= 1) {
        int y = (t >= off) ? red[t - off] : 0;
        __syncthreads();
        red[t] += y;
        __syncthreads();
    }
    int run = boff[b] + red[t] - s;     // exclusive prefix for this thread
    #pragma unroll
    for (int i = 0; i < 8; ++i) {
        int idx = base + i;
        if (idx < NN) {
            rowptr[idx] = run;
            run += v[i];
            dis[idx] = rsqrtf((float)v[i]);
        }
    }
    if (b == 0 && t == 0) rowptr[NN] = NE2;
}

__global__ void fill_k(const int* __restrict__ ei, const int* __restrict__ rowptr,
                       int* __restrict__ fill, int* __restrict__ csr) {
    int e = blockIdx.x * blockDim.x + threadIdx.x;
    if (e >= NE2) return;
    int src, dst;
    if (e < NE) { src = ei[e]; dst = ei[NE + e]; }
    else        { src = e - NE; dst = e - NE; }
    int pos = atomicAdd(&fill[dst], 1);
    csr[rowptr[dst] + pos] = src;
}

// ---------------- prep: BN affine + wa projection (merged) ----------------
__global__ __launch_bounds__(256) void prep_k(
    const float* __restrict__ b_gcn, const float* __restrict__ g2_gam,
    const float* __restrict__ g2_bet, const float* __restrict__ g2_mean,
    const float* __restrict__ g2_var, const float* __restrict__ b_gat,
    const float* __restrict__ g1_gam, const float* __restrict__ g1_bet,
    const float* __restrict__ g1_mean, const float* __restrict__ g1_var,
    float* __restrict__ Ag, float* __restrict__ Bg,
    float* __restrict__ Aa, float* __restrict__ Ba,
    const float* __restrict__ w_gat, const float* __restrict__ a_src,
    const float* __restrict__ a_dst, float* __restrict__ wa) {
    int b = blockIdx.x, tid = threadIdx.x;
    if (b < 3) {
        int t = b * 256 + tid;
        if (t < HD) {
            float a = rsqrtf(g2_var[t] + BN_EPS) * g2_gam[t];
            Ag[t] = a;
            Bg[t] = (b_gcn[t] - g2_mean[t]) * a + g2_bet[t];
        } else if (t < HD + OD) {
            int d = t - HD;
            float a = rsqrtf(g1_var[d] + BN_EPS) * g1_gam[d];
            Aa[d] = a;
            Ba[d] = (b_gat[d] - g1_mean[d]) * a + g1_bet[d];
        }
    } else {
        int t = (b - 3) * 256 + tid;       // 0..1023
        int k = t >> 3, j = t & 7, head = j & 3;
        const float* av = (j < 4 ? a_src : a_dst) + head * 128;
        const float* w = w_gat + (size_t)k * OD + head * 128;
        float s = 0.f;
        for (int d = 0; d < 128; ++d) s += w[d] * av[d];
        wa[k * 8 + j] = s;
    }
}

// ---------------- merged casts: x -> bf16; two transposed weight casts ----------------
__global__ __launch_bounds__(256) void cast_all_k(
    const float* __restrict__ x, ushort_t* __restrict__ xb,
    const float* __restrict__ w_gcn, ushort_t* __restrict__ wgT,
    const float* __restrict__ w_gat, ushort_t* __restrict__ wgatT) {
    int b = blockIdx.x, tid = threadIdx.x;
    if (b < XB_BLOCKS) {
        int t = b * 256 + tid;
        float4 v = ((const float4*)x)[t];
        ushort_t o[4] = {f2bf(v.x), f2bf(v.y), f2bf(v.z), f2bf(v.w)};
        *(unsigned long long*)(xb + 4 * t) = *(unsigned long long*)o;
    } else if (b < XB_BLOCKS + WG_BLOCKS) {
        int t = (b - XB_BLOCKS) * 256 + tid;       // K=FD, N=HD
        int n = t / FD, k = t - n * FD;
        wgT[n * FD + k] = f2bf(w_gcn[k * HD + n]);
    } else {
        int t = (b - XB_BLOCKS - WG_BLOCKS) * 256 + tid;   // K=HD, N=OD
        int n = t / HD, k = t - n * HD;
        wgatT[n * HD + k] = f2bf(w_gat[k * OD + n]);
    }
}

// ---------------- bf16 MFMA GEMM: C[M,N] = A[M,128] @ B[128,N], C stored bf16
__global__ __launch_bounds__(256) void gemm_bf16(const ushort_t* __restrict__ A,
                                                 const ushort_t* __restrict__ BT,
                                                 ushort_t* __restrict__ C,
                                                 int M, int N) {
    __shared__ short As[128][136];
    __shared__ short Bs[64][136];
    const int tid = threadIdx.x;
    const int m0 = blockIdx.x * 128;
    const int n0 = blockIdx.y * 64;

    #pragma unroll
    for (int i = 0; i < 8; ++i) {
        int c = tid + 256 * i;
        int row = c >> 4, off = (c & 15) * 8;
        bfrag v = (bfrag)0;
        if (m0 + row < M) v = *(const bfrag*)(A + (size_t)(m0 + row) * 128 + off);
        *(bfrag*)&As[row][off] = v;
    }
    #pragma unroll
    for (int i = 0; i < 4; ++i) {
        int c = tid + 256 * i;
        int row = c >> 4, off = (c & 15) * 8;
        *(bfrag*)&Bs[row][off] = *(const bfrag*)(BT + (size_t)(n0 + row) * 128 + off);
    }
    __syncthreads();

    const int w = tid >> 6;
    const int lr = tid & 15;
    const int kg = (tid & 63) >> 4;

    f32x4 acc[2][4];
    #pragma unroll
    for (int mi = 0; mi < 2; ++mi)
        #pragma unroll
        for (int ni = 0; ni < 4; ++ni) acc[mi][ni] = (f32x4)0.f;

    #pragma unroll
    for (int ks = 0; ks < 4; ++ks) {
        bfrag af[2], bb[4];
        #pragma unroll
        for (int mi = 0; mi < 2; ++mi)
            af[mi] = *(const bfrag*)&As[32 * w + 16 * mi + lr][32 * ks + 8 * kg];
        #pragma unroll
        for (int ni = 0; ni < 4; ++ni)
            bb[ni] = *(const bfrag*)&Bs[16 * ni + lr][32 * ks + 8 * kg];
        #pragma unroll
        for (int mi = 0; mi < 2; ++mi)
            #pragma unroll
            for (int ni = 0; ni < 4; ++ni)
                acc[mi][ni] = __builtin_amdgcn_mfma_f32_16x16x32_bf16(
                    af[mi], bb[ni], acc[mi][ni], 0, 0, 0);
    }

    #pragma unroll
    for (int mi = 0; mi < 2; ++mi) {
        #pragma unroll
        for (int r = 0; r < 4; ++r) {
            int row = m0 + 32 * w + 16 * mi + 4 * kg + r;
            if (row < M) {
                #pragma unroll
                for (int ni = 0; ni < 4; ++ni) {
                    int col = n0 + 16 * ni + lr;
                    C[(size_t)row * N + col] = f2bf(acc[mi][ni][r]);
                }
            }
        }
    }
}

// ---------------- per-head GEMM: ofeat[:,128h:128h+128] = relu(BN(z_h @ W_h)), bf16 out
__global__ __launch_bounds__(256) void gemm_z_k(const ushort_t* __restrict__ zb,
                                                const ushort_t* __restrict__ wgatT,
                                                const float* __restrict__ Aa,
                                                const float* __restrict__ Ba,
                                                ushort_t* __restrict__ ofeat) {
    __shared__ short As[128][136];
    __shared__ short Bs[64][136];
    const int tid = threadIdx.x;
    const int head = blockIdx.z;
    const int m0 = blockIdx.x * 128;
    const int n0 = blockIdx.y * 64;
    const ushort_t* A = zb + (size_t)head * NN * HD;
    const ushort_t* BT = wgatT + (size_t)head * HD * HD;

    #pragma unroll
    for (int i = 0; i < 8; ++i) {
        int c = tid + 256 * i;
        int row = c >> 4, off = (c & 15) * 8;
        bfrag v = (bfrag)0;
        if (m0 + row < NN) v = *(const bfrag*)(A + (size_t)(m0 + row) * HD + off);
        *(bfrag*)&As[row][off] = v;
    }
    #pragma unroll
    for (int i = 0; i < 4; ++i) {
        int c = tid + 256 * i;
        int row = c >> 4, off = (c & 15) * 8;
        *(bfrag*)&Bs[row][off] = *(const bfrag*)(BT + (size_t)(n0 + row) * HD + off);
    }
    __syncthreads();

    const int w = tid >> 6;
    const int lr = tid & 15;
    const int kg = (tid & 63) >> 4;

    f32x4 acc[2][4];
    #pragma unroll
    for (int mi = 0; mi < 2; ++mi)
        #pragma unroll
        for (int ni = 0; ni < 4; ++ni) acc[mi][ni] = (f32x4)0.f;

    #pragma unroll
    for (int ks = 0; ks < 4; ++ks) {
        bfrag af[2], bb[4];
        #pragma unroll
        for (int mi = 0; mi < 2; ++mi)
            af[mi] = *(const bfrag*)&As[32 * w + 16 * mi + lr][32 * ks + 8 * kg];
        #pragma unroll
        for (int ni = 0; ni < 4; ++ni)
            bb[ni] = *(const bfrag*)&Bs[16 * ni + lr][32 * ks + 8 * kg];
        #pragma unroll
        for (int mi = 0; mi < 2; ++mi)
            #pragma unroll
            for (int ni = 0; ni < 4; ++ni)
                acc[mi][ni] = __builtin_amdgcn_mfma_f32_16x16x32_bf16(
                    af[mi], bb[ni], acc[mi][ni], 0, 0, 0);
    }

    #pragma unroll
    for (int mi = 0; mi < 2; ++mi) {
        #pragma unroll
        for (int r = 0; r < 4; ++r) {
            int row = m0 + 32 * w + 16 * mi + 4 * kg + r;
            if (row < NN) {
                #pragma unroll
                for (int ni = 0; ni < 4; ++ni) {
                    int gc = 128 * head + n0 + 16 * ni + lr;
                    float v = fmaf(acc[mi][ni][r], Aa[gc], Ba[gc]);
                    ofeat[(size_t)row * OD + gc] = f2bf(fmaxf(v, 0.f));
                }
            }
        }
    }
}

// ---------------- GCN aggregate: wave/node, 16 lanes/edge, packed-f32 FMA ----------------
__global__ __launch_bounds__(256) void gcn_agg3_k(
    const ushort_t* __restrict__ h0, const int* __restrict__ rowptr,
    const int* __restrict__ csr, const float* __restrict__ dis,
    const float* __restrict__ Ag, const float* __restrict__ Bg,
    ushort_t* __restrict__ h) {
    int lane = threadIdx.x & 63;
    int g = lane >> 4;              // edge sub-slot within wave
    int sl = lane & 15;             // 16-byte dim chunk
    int sl8 = sl * 8;
    int n = __builtin_amdgcn_readfirstlane((int)(blockIdx.x * 4) + (int)(threadIdx.x >> 6));
    int r0 = __builtin_amdgcn_readfirstlane(rowptr[n]);
    int r1 = __builtin_amdgcn_readfirstlane(rowptr[n + 1]);
    f32x2 a2[4];
    #pragma unroll
    for (int q = 0; q < 4; ++q) a2[q] = (f32x2)0.f;
    uint4 hv[2];
    float wv[2];

#define GLOAD(i, BASE) { int _e = (BASE) + g; int _ec = min(_e, r1 - 1); \
    int _s = csr[_ec]; \
    wv[i] = (_e < r1) ? dis[_s] : 0.f; \
    hv[i] = *(const uint4*)(h0 + ((size_t)(unsigned)_s << 7) + sl8); }
#define GACC(i) { f32x2 _w = {wv[i], wv[i]}; \
    f32x2 _f0 = {bf2f_lo(hv[i].x), bf2f_hi(hv[i].x)}; \
    f32x2 _f1 = {bf2f_lo(hv[i].y), bf2f_hi(hv[i].y)}; \
    f32x2 _f2 = {bf2f_lo(hv[i].z), bf2f_hi(hv[i].z)}; \
    f32x2 _f3 = {bf2f_lo(hv[i].w), bf2f_hi(hv[i].w)}; \
    a2[0] = __builtin_elementwise_fma(_w, _f0, a2[0]); \
    a2[1] = __builtin_elementwise_fma(_w, _f1, a2[1]); \
    a2[2] = __builtin_elementwise_fma(_w, _f2, a2[2]); \
    a2[3] = __builtin_elementwise_fma(_w, _f3, a2[3]); }

    GLOAD(0, r0) GLOAD(1, r0 + 4)
    for (int base = r0; base < r1; base += 8) {
        GACC(0) GLOAD(0, base + 8)
        GACC(1) GLOAD(1, base + 12)
    }
#undef GLOAD
#undef GACC

    // reduce across the 4 edge groups
    #pragma unroll
    for (int q = 0; q < 4; ++q) {
        f32x2 v = a2[q];
        v.x += __shfl_xor(v.x, 16); v.x += __shfl_xor(v.x, 32);
        v.y += __shfl_xor(v.y, 16); v.y += __shfl_xor(v.y, 32);
        a2[q] = v;
    }
    float a[8] = {a2[0].x, a2[0].y, a2[1].x, a2[1].y,
                  a2[2].x, a2[2].y, a2[3].x, a2[3].y};
    float t = dis[n];
    float4 A0 = *(const float4*)(Ag + sl8);
    float4 A1 = *(const float4*)(Ag + sl8 + 4);
    float4 B0 = *(const float4*)(Bg + sl8);
    float4 B1 = *(const float4*)(Bg + sl8 + 4);
    float o0 = fmaxf(fmaf(a[0] * t, A0.x, B0.x), 0.f);
    float o1 = fmaxf(fmaf(a[1] * t, A0.y, B0.y), 0.f);
    float o2 = fmaxf(fmaf(a[2] * t, A0.z, B0.z), 0.f);
    float o3 = fmaxf(fmaf(a[3] * t, A0.w, B0.w), 0.f);
    float o4 = fmaxf(fmaf(a[4] * t, A1.x, B1.x), 0.f);
    float o5 = fmaxf(fmaf(a[5] * t, A1.y, B1.y), 0.f);
    float o6 = fmaxf(fmaf(a[6] * t, A1.z, B1.z), 0.f);
    float o7 = fmaxf(fmaf(a[7] * t, A1.w, B1.w), 0.f);
    if (g == 0) {
        uint4 pk;
        pk.x = (unsigned int)f2bf(o0) | ((unsigned int)f2bf(o1) << 16);
        pk.y = (unsigned int)f2bf(o2) | ((unsigned int)f2bf(o3) << 16);
        pk.z = (unsigned int)f2bf(o4) | ((unsigned int)f2bf(o5) << 16);
        pk.w = (unsigned int)f2bf(o6) | ((unsigned int)f2bf(o7) << 16);
        *(uint4*)(h + (size_t)n * HD + sl8) = pk;
    }
}

// ---------------- asrc/adst: [N,128] @ wa[128,8] ----------------
__global__ __launch_bounds__(256) void attn_dots_k(const ushort_t* __restrict__ h,
                                                   const float* __restrict__ wa,
                                                   float* __restrict__ asrc,
                                                   float* __restrict__ adst) {
    __shared__ float was[128][8];
    int tid = threadIdx.x;
    for (int i = tid; i < 1024; i += 256) was[i >> 3][i & 7] = wa[i];
    __syncthreads();
    int nl = tid >> 3, j = tid & 7;
    int n = blockIdx.x * 32 + nl;
    if (n >= NN) return;
    const ushort_t* hr = h + (size_t)n * HD;
    float s = 0.f;
    #pragma unroll 4
    for (int i = 0; i < 64; ++i) {
        unsigned int hv = *(const unsigned int*)(hr + 2 * i);
        s += bf2f_lo(hv) * was[2 * i][j] + bf2f_hi(hv) * was[2 * i + 1][j];
    }
    if (j < 4) asrc[n * 4 + j] = s;
    else       adst[n * 4 + (j - 4)] = s;
}

// ---------------- fused GAT: softmax numerators + weighted gather, packed-f32 FMA ----------------
// wave per node; 16 lanes/edge; z_h[n,:] = (sum_e p_eh h[src_e,:]) / (sum_e p_eh + 1e-16)
__global__ __launch_bounds__(256) void zgather2_k(
    const ushort_t* __restrict__ h, const int* __restrict__ rowptr,
    const int* __restrict__ csr, const float* __restrict__ asrc,
    const float* __restrict__ adst, ushort_t* __restrict__ zb) {
    int lane = threadIdx.x & 63;
    int g = lane >> 4;
    int sl = lane & 15;
    int sl8 = sl * 8;
    int n = __builtin_amdgcn_readfirstlane((int)(blockIdx.x * 4) + (int)(threadIdx.x >> 6));
    int r0 = __builtin_amdgcn_readfirstlane(rowptr[n]);
    int r1 = __builtin_amdgcn_readfirstlane(rowptr[n + 1]);
    float4 ad = *(const float4*)(adst + 4 * n);     // uniform

    f32x2 acc[4][4];                // [head][dim-pair]
    #pragma unroll
    for (int hh = 0; hh < 4; ++hh)
        #pragma unroll
        for (int q = 0; q < 4; ++q) acc[hh][q] = (f32x2)0.f;
    f32x2 s01 = (f32x2)0.f, s23 = (f32x2)0.f;

    uint4 hv[2];
    f32x2 pa[2], pb[2];             // {p0,p1}, {p2,p3}

#define ZLOAD(i, BASE) { int _e = (BASE) + g; int _ec = min(_e, r1 - 1); \
    int _s = csr[_ec]; bool _v = _e < r1; \
    float4 _as = *(const float4*)(asrc + 4 * (size_t)_s); \
    f32x2 _x01 = {_as.x + ad.x, _as.y + ad.y}; \
    f32x2 _x23 = {_as.z + ad.z, _as.w + ad.w}; \
    f32x2 _l01 = __builtin_elementwise_max(_x01, 0.2f * _x01); \
    f32x2 _l23 = __builtin_elementwise_max(_x23, 0.2f * _x23); \
    pa[i].x = _v ? __expf(_l01.x) : 0.f; \
    pa[i].y = _v ? __expf(_l01.y) : 0.f; \
    pb[i].x = _v ? __expf(_l23.x) : 0.f; \
    pb[i].y = _v ? __expf(_l23.y) : 0.f; \
    hv[i] = *(const uint4*)(h + ((size_t)(unsigned)_s << 7) + sl8); }
#define ZACC(i) { \
    f32x2 _f0 = {bf2f_lo(hv[i].x), bf2f_hi(hv[i].x)}; \
    f32x2 _f1 = {bf2f_lo(hv[i].y), bf2f_hi(hv[i].y)}; \
    f32x2 _f2 = {bf2f_lo(hv[i].z), bf2f_hi(hv[i].z)}; \
    f32x2 _f3 = {bf2f_lo(hv[i].w), bf2f_hi(hv[i].w)}; \
    s01 += pa[i]; s23 += pb[i]; \
    f32x2 _p0 = {pa[i].x, pa[i].x}; \
    f32x2 _p1 = {pa[i].y, pa[i].y}; \
    f32x2 _p2 = {pb[i].x, pb[i].x}; \
    f32x2 _p3 = {pb[i].y, pb[i].y}; \
    acc[0][0] = __builtin_elementwise_fma(_p0, _f0, acc[0][0]); \
    acc[0][1] = __builtin_elementwise_fma(_p0, _f1, acc[0][1]); \
    acc[0][2] = __builtin_elementwise_fma(_p0, _f2, acc[0][2]); \
    acc[0][3] = __builtin_elementwise_fma(_p0, _f3, acc[0][3]); \
    acc[1][0] = __builtin_elementwise_fma(_p1, _f0, acc[1][0]); \
    acc[1][1] = __builtin_elementwise_fma(_p1, _f1, acc[1][1]); \
    acc[1][2] = __builtin_elementwise_fma(_p1, _f2, acc[1][2]); \
    acc[1][3] = __builtin_elementwise_fma(_p1, _f3, acc[1][3]); \
    acc[2][0] = __builtin_elementwise_fma(_p2, _f0, acc[2][0]); \
    acc[2][1] = __builtin_elementwise_fma(_p2, _f1, acc[2][1]); \
    acc[2][2] = __builtin_elementwise_fma(_p2, _f2, acc[2][2]); \
    acc[2][3] = __builtin_elementwise_fma(_p2, _f3, acc[2][3]); \
    acc[3][0] = __builtin_elementwise_fma(_p3, _f0, acc[3][0]); \
    acc[3][1] = __builtin_elementwise_fma(_p3, _f1, acc[3][1]); \
    acc[3][2] = __builtin_elementwise_fma(_p3, _f2, acc[3][2]); \
    acc[3][3] = __builtin_elementwise_fma(_p3, _f3, acc[3][3]); }

    ZLOAD(0, r0) ZLOAD(1, r0 + 4)
    for (int base = r0; base < r1; base += 8) {
        ZACC(0) ZLOAD(0, base + 8)
        ZACC(1) ZLOAD(1, base + 12)
    }
#undef ZLOAD
#undef ZACC

    // reduce across the 4 edge groups
    #pragma unroll
    for (int hh = 0; hh < 4; ++hh)
        #pragma unroll
        for (int q = 0; q < 4; ++q) {
            f32x2 v = acc[hh][q];
            v.x += __shfl_xor(v.x, 16); v.x += __shfl_xor(v.x, 32);
            v.y += __shfl_xor(v.y, 16); v.y += __shfl_xor(v.y, 32);
            acc[hh][q] = v;
        }
    float s0 = s01.x, s1 = s01.y, s2 = s23.x, s3 = s23.y;
    s0 += __shfl_xor(s0, 16); s0 += __shfl_xor(s0, 32);
    s1 += __shfl_xor(s1, 16); s1 += __shfl_xor(s1, 32);
    s2 += __shfl_xor(s2, 16); s2 += __shfl_xor(s2, 32);
    s3 += __shfl_xor(s3, 16); s3 += __shfl_xor(s3, 32);

    float inv0 = 1.f / (s0 + 1e-16f), inv1 = 1.f / (s1 + 1e-16f);
    float inv2 = 1.f / (s2 + 1e-16f), inv3 = 1.f / (s3 + 1e-16f);
    float invg = (g == 0) ? inv0 : (g == 1) ? inv1 : (g == 2) ? inv2 : inv3;

    unsigned int pkc[4];
    #pragma unroll
    for (int q = 0; q < 4; ++q) {
        f32x2 v01 = (g == 1) ? acc[1][q] : acc[0][q];
        f32x2 v23 = (g == 3) ? acc[3][q] : acc[2][q];
        f32x2 v = (g & 2) ? v23 : v01;
        v = v * invg;
        pkc[q] = (unsigned int)f2bf(v.x) | ((unsigned int)f2bf(v.y) << 16);
    }
    uint4 pk = {pkc[0], pkc[1], pkc[2], pkc[3]};
    *(uint4*)(zb + (size_t)g * NN * HD + (size_t)n * HD + sl8) = pk;
}

// ---------------- pooling: one (graph, 256-dim half) per block, bf16 ofeat ----------------
__global__ __launch_bounds__(256) void pool_k(const ushort_t* __restrict__ outfeat,
                                              const int* __restrict__ batch,
                                              float* __restrict__ feat) {
    int g = blockIdx.x;
    int d = blockIdx.y * 256 + threadIdx.x;
    int lo = 0, hi = NN;
    while (lo < hi) { int mid = (lo + hi) >> 1; if (batch[mid] < g) lo = mid + 1; else hi = mid; }
    int start = lo;
    hi = NN;
    while (lo < hi) { int mid = (lo + hi) >> 1; if (batch[mid] < g + 1) lo = mid + 1; else hi = mid; }
    int end = lo;
    int cnt = end - start;
    float sadd = 0.f, smax = -3.402823466e38f;
    for (int i = start; i < end; ++i) {
        float v = bf2f_lo((unsigned int)outfeat[(size_t)i * OD + d]);
        sadd += v;
        smax = fmaxf(smax, v);
    }
    float smean;
    if (cnt > 0) { smean = sadd / (float)cnt; }
    else { sadd = 0.f; smax = 0.f; smean = 0.f; }
    feat[g * 1536 + d] = sadd;
    feat[g * 1536 + 512 + d] = smax;
    feat[g * 1536 + 1024 + d] = smean;
}

// ---------------- head: out = sigmoid(feat @ w_lin + b_lin) ----------------
__global__ __launch_bounds__(256) void head_k(const float* __restrict__ feat,
                                              const float* __restrict__ w_lin,
                                              const float* __restrict__ b_lin,
                                              float* __restrict__ out) {
    __shared__ float red[256];
    int g = blockIdx.x;
    int t = threadIdx.x;
    int o = t & 15, part = t >> 4;
    float s = 0.f;
    int kbeg = part * 96;
    for (int k = kbeg; k < kbeg + 96; ++k) s += feat[g * 1536 + k] * w_lin[k * 16 + o];
    red[t] = s;
    __syncthreads();
    if (t < 16) {
        float tot = b_lin[o];
        for (int p = 0; p < 16; ++p) tot += red[p * 16 + o];
        out[g * 16 + o] = 1.f / (1.f + __expf(-tot));
    }
}

extern "C" void kernel_launch(void* const* d_in, const int* in_sizes, int n_in,
                              void* d_out, int out_size, void* d_ws, size_t ws_size,
                              hipStream_t stream) {
    const float* x       = (const float*)d_in[0];
    const int*   ei      = (const int*)d_in[1];
    const int*   batch   = (const int*)d_in[2];
    const float* w_gcn   = (const float*)d_in[3];
    const float* b_gcn   = (const float*)d_in[4];
    const float* g2_gam  = (const float*)d_in[5];
    const float* g2_bet  = (const float*)d_in[6];
    const float* g2_mean = (const float*)d_in[7];
    const float* g2_var  = (const float*)d_in[8];
    const float* w_gat   = (const float*)d_in[9];
    const float* a_src   = (const float*)d_in[10];
    const float* a_dst   = (const float*)d_in[11];
    const float* b_gat   = (const float*)d_in[12];
    const float* g1_gam  = (const float*)d_in[13];
    const float* g1_bet  = (const float*)d_in[14];
    const float* g1_mean = (const float*)d_in[15];
    const float* g1_var  = (const float*)d_in[16];
    const float* w_lin   = (const float*)d_in[17];
    const float* b_lin   = (const float*)d_in[18];
    float* out = (float*)d_out;

    char* ws = (char*)d_ws;
    size_t off = 0;
    auto alloc = [&](size_t bytes) -> void* {
        void* p = ws + off;
        off += (bytes + 255) & ~(size_t)255;
        return p;
    };
    int* deg        = (int*)alloc((size_t)NN * 4);
    int* fill       = (int*)alloc((size_t)NN * 4);
    int* rowptr     = (int*)alloc((size_t)(NN + 1) * 4);
    int* csr        = (int*)alloc((size_t)NE2 * 4);
    int* bsum       = (int*)alloc((size_t)NB_SCAN * 4);
    int* boff       = (int*)alloc((size_t)NB_SCAN * 4);
    float* dis      = (float*)alloc((size_t)NN * 4);
    ushort_t* xb    = (ushort_t*)alloc((size_t)NN * FD * 2);
    ushort_t* wgT   = (ushort_t*)alloc((size_t)FD * HD * 2);
    ushort_t* wgatT = (ushort_t*)alloc((size_t)HD * OD * 2);
    ushort_t* h0b   = (ushort_t*)alloc((size_t)NN * HD * 2);
    ushort_t* hb    = (ushort_t*)alloc((size_t)NN * HD * 2);
    ushort_t* zb    = (ushort_t*)alloc((size_t)NHD * NN * HD * 2);
    float* asrc     = (float*)alloc((size_t)NN * 4 * 4);
    float* adst     = (float*)alloc((size_t)NN * 4 * 4);
    float* wa       = (float*)alloc((size_t)128 * 8 * 4);
    float* Ag       = (float*)alloc((size_t)HD * 4);
    float* Bg       = (float*)alloc((size_t)HD * 4);
    float* Aa       = (float*)alloc((size_t)OD * 4);
    float* Ba       = (float*)alloc((size_t)OD * 4);
    ushort_t* ofeat = (ushort_t*)alloc((size_t)NN * OD * 2);
    float* feat     = (float*)alloc((size_t)NG * 1536 * 4);

    // CSR build (multi-block scan; dis fused into phase C)
    init_k<<<(NN + 255) / 256, 256, 0, stream>>>(deg, fill);
    count_k<<<(NE + 255) / 256, 256, 0, stream>>>(ei, deg);
    scanA_k<<<NB_SCAN, 256, 0, stream>>>(deg, bsum);
    scanB_k<<<1, 64, 0, stream>>>(bsum, boff);
    scanC_k<<<NB_SCAN, 256, 0, stream>>>(deg, boff, rowptr, dis);
    fill_k<<<(NE2 + 255) / 256, 256, 0, stream>>>(ei, rowptr, fill, csr);

    // BN affine + wa projection (merged)
    prep_k<<<7, 256, 0, stream>>>(b_gcn, g2_gam, g2_bet, g2_mean, g2_var,
                                  b_gat, g1_gam, g1_bet, g1_mean, g1_var,
                                  Ag, Bg, Aa, Ba, w_gat, a_src, a_dst, wa);

    // merged casts
    cast_all_k<<<XB_BLOCKS + WG_BLOCKS + WA_BLOCKS, 256, 0, stream>>>(
        x, xb, w_gcn, wgT, w_gat, wgatT);

    // GCN linear: h0 = x @ w_gcn   (bf16 MFMA)
    gemm_bf16<<<dim3((NN + 127) / 128, HD / 64), 256, 0, stream>>>(xb, wgT, h0b, NN, HD);

    // GCN aggregate + BN2 + ReLU
    gcn_agg3_k<<<NN / 4, 256, 0, stream>>>(h0b, rowptr, csr, dis, Ag, Bg, hb);

    // asrc/adst projection
    attn_dots_k<<<(NN + 31) / 32, 256, 0, stream>>>(hb, wa, asrc, adst);

    // fused GAT softmax + gather: per-head weighted sums of h rows
    zgather2_k<<<NN / 4, 256, 0, stream>>>(hb, rowptr, csr, asrc, adst, zb);

    // per-head GEMM + BN1 + ReLU -> ofeat (bf16)
    gemm_z_k<<<dim3((NN + 127) / 128, HD / 64, NHD), 256, 0, stream>>>(zb, wgatT, Aa, Ba, ofeat);

    // pooling
    pool_k<<<dim3(NG, 2), 256, 0, stream>>>(ofeat, batch, feat);

    // head
    head_k<<<NG, 256, 0, stream>>>(feat, w_lin, b_lin, out);
}

// Round 10
// 278.528 us; speedup vs baseline: 2.7917x; 1.1306x over previous
//
#include <hip/hip_runtime.h>

#define NN 50000          // nodes
#define NE 800000         // edges (without self loops)
#define NE2 (NE + NN)     // edges + self loops
#define FD 128            // input feature dim
#define HD 128            // hidden dim
#define NHD 4             // heads
#define OD 512            // heads * HD
#define NG 512            // graphs
#define BN_EPS 1e-5f

#define SCAN_CHUNK 2048
#define NB_SCAN ((NN + SCAN_CHUNK - 1) / SCAN_CHUNK)   // 25
#define XB_BLOCKS (NN * FD / 4 / 256)                  // 6250
#define WG_BLOCKS (FD * HD / 256)                      // 64
#define WA_BLOCKS (HD * OD / 256)                      // 256

typedef __attribute__((ext_vector_type(8))) short bfrag;   // 8 bf16 = 4 VGPRs
typedef __attribute__((ext_vector_type(4))) float f32x4;
typedef __attribute__((ext_vector_type(2))) float f32x2;
typedef unsigned short ushort_t;

__device__ inline ushort_t f2bf(float f) {               // RNE fp32->bf16
    unsigned int u = __float_as_uint(f);
    unsigned int r = (u + 0x7fffu + ((u >> 16) & 1u)) >> 16;
    return (ushort_t)r;
}
__device__ inline float bf2f_lo(unsigned int v) { return __uint_as_float(v << 16); }
__device__ inline float bf2f_hi(unsigned int v) { return __uint_as_float(v & 0xffff0000u); }

// ---------------- CSR build ----------------
__global__ void init_k(int* __restrict__ deg, int* __restrict__ fill) {
    int i = blockIdx.x * blockDim.x + threadIdx.x;
    if (i < NN) { deg[i] = 1; fill[i] = 0; }   // 1 = self loop
}

__global__ void count_k(const int* __restrict__ ei, int* __restrict__ deg) {
    int e = blockIdx.x * blockDim.x + threadIdx.x;
    if (e < NE) atomicAdd(&deg[ei[NE + e]], 1);
}

// phase A: per-block sums of 2048-element chunks
__global__ __launch_bounds__(256) void scanA_k(const int* __restrict__ deg,
                                               int* __restrict__ bsum) {
    __shared__ int red[256];
    int b = blockIdx.x, t = threadIdx.x;
    int base = b * SCAN_CHUNK + t * 8;
    int s = 0;
    #pragma unroll
    for (int i = 0; i < 8; ++i) { int idx = base + i; if (idx < NN) s += deg[idx]; }
    red[t] = s;
    __syncthreads();
    for (int off = 128; off; off >>= 1) {
        if (t < off) red[t] += red[t + off];
        __syncthreads();
    }
    if (t == 0) bsum[b] = red[0];
}

// phase C (with inline phase B): block-local scan + global offset -> rowptr; fused dis
__global__ __launch_bounds__(256) void scanC_k(const int* __restrict__ deg,
                                               const int* __restrict__ bsum,
                                               int* __restrict__ rowptr,
                                               float* __restrict__ dis) {
    __shared__ int red[256];
    __shared__ int boff_s;
    int b = blockIdx.x, t = threadIdx.x;
    if (t == 0) {
        int run = 0;
        for (int i = 0; i < b; ++i) run += bsum[i];
        boff_s = run;
    }
    int base = b * SCAN_CHUNK + t * 8;
    int v[8];
    int s = 0;
    #pragma unroll
    for (int i = 0; i < 8; ++i) {
        int idx = base + i;
        v[i] = (idx < NN) ? deg[idx] : 0;
        s += v[i];
    }
    red[t] = s;
    __syncthreads();
    for (int off = 1; off < 256; off <<= 1) {
        int y = (t >= off) ? red[t - off] : 0;
        __syncthreads();
        red[t] += y;
        __syncthreads();
    }
    int run = boff_s + red[t] - s;     // exclusive prefix for this thread
    #pragma unroll
    for (int i = 0; i < 8; ++i) {
        int idx = base + i;
        if (idx < NN) {
            rowptr[idx] = run;
            run += v[i];
            dis[idx] = rsqrtf((float)v[i]);
        }
    }
    if (b == 0 && t == 0) rowptr[NN] = NE2;
}

__global__ void fill_k(const int* __restrict__ ei, const int* __restrict__ rowptr,
                       int* __restrict__ fill, int* __restrict__ csr) {
    int e = blockIdx.x * blockDim.x + threadIdx.x;
    if (e >= NE2) return;
    int src, dst;
    if (e < NE) { src = ei[e]; dst = ei[NE + e]; }
    else        { src = e - NE; dst = e - NE; }
    int pos = atomicAdd(&fill[dst], 1);
    csr[rowptr[dst] + pos] = src;
}

// ---------------- merged: BN affine + waT projection + all casts ----------------
// blocks: [0,3) BN affine; [3,7) waT; [7,7+XB) x cast; then wgT; then wgatT
__global__ __launch_bounds__(256) void castprep_k(
    const float* __restrict__ b_gcn, const float* __restrict__ g2_gam,
    const float* __restrict__ g2_bet, const float* __restrict__ g2_mean,
    const float* __restrict__ g2_var, const float* __restrict__ b_gat,
    const float* __restrict__ g1_gam, const float* __restrict__ g1_bet,
    const float* __restrict__ g1_mean, const float* __restrict__ g1_var,
    float* __restrict__ Ag, float* __restrict__ Bg,
    float* __restrict__ Aa, float* __restrict__ Ba,
    const float* __restrict__ a_src, const float* __restrict__ a_dst,
    float* __restrict__ waT,
    const float* __restrict__ x, ushort_t* __restrict__ xb,
    const float* __restrict__ w_gcn, ushort_t* __restrict__ wgT,
    const float* __restrict__ w_gat, ushort_t* __restrict__ wgatT) {
    int b = blockIdx.x, tid = threadIdx.x;
    if (b < 3) {
        int t = b * 256 + tid;
        if (t < HD) {
            float a = rsqrtf(g2_var[t] + BN_EPS) * g2_gam[t];
            Ag[t] = a;
            Bg[t] = (b_gcn[t] - g2_mean[t]) * a + g2_bet[t];
        } else if (t < HD + OD) {
            int d = t - HD;
            float a = rsqrtf(g1_var[d] + BN_EPS) * g1_gam[d];
            Aa[d] = a;
            Ba[d] = (b_gat[d] - g1_mean[d]) * a + g1_bet[d];
        }
    } else if (b < 7) {
        int t = (b - 3) * 256 + tid;       // 0..1023
        int k = t >> 3, j = t & 7, head = j & 3;
        const float* av = (j < 4 ? a_src : a_dst) + head * 128;
        const float* w = w_gat + (size_t)k * OD + head * 128;
        float s = 0.f;
        for (int d = 0; d < 128; ++d) s += w[d] * av[d];
        waT[j * 128 + k] = s;
    } else if (b < 7 + XB_BLOCKS) {
        int t = (b - 7) * 256 + tid;
        float4 v = ((const float4*)x)[t];
        ushort_t o[4] = {f2bf(v.x), f2bf(v.y), f2bf(v.z), f2bf(v.w)};
        *(unsigned long long*)(xb + 4 * t) = *(unsigned long long*)o;
    } else if (b < 7 + XB_BLOCKS + WG_BLOCKS) {
        int t = (b - 7 - XB_BLOCKS) * 256 + tid;       // K=FD, N=HD
        int n = t / FD, k = t - n * FD;
        wgT[n * FD + k] = f2bf(w_gcn[k * HD + n]);
    } else {
        int t = (b - 7 - XB_BLOCKS - WG_BLOCKS) * 256 + tid;   // K=HD, N=OD
        int n = t / HD, k = t - n * HD;
        wgatT[n * HD + k] = f2bf(w_gat[k * OD + n]);
    }
}

// ---------------- bf16 MFMA GEMM: C[M,N] = A[M,128] @ B[128,N], C stored bf16
__global__ __launch_bounds__(256) void gemm_bf16(const ushort_t* __restrict__ A,
                                                 const ushort_t* __restrict__ BT,
                                                 ushort_t* __restrict__ C,
                                                 int M, int N) {
    __shared__ short As[128][136];
    __shared__ short Bs[64][136];
    const int tid = threadIdx.x;
    const int m0 = blockIdx.x * 128;
    const int n0 = blockIdx.y * 64;

    #pragma unroll
    for (int i = 0; i < 8; ++i) {
        int c = tid + 256 * i;
        int row = c >> 4, off = (c & 15) * 8;
        bfrag v = (bfrag)0;
        if (m0 + row < M) v = *(const bfrag*)(A + (size_t)(m0 + row) * 128 + off);
        *(bfrag*)&As[row][off] = v;
    }
    #pragma unroll
    for (int i = 0; i < 4; ++i) {
        int c = tid + 256 * i;
        int row = c >> 4, off = (c & 15) * 8;
        *(bfrag*)&Bs[row][off] = *(const bfrag*)(BT + (size_t)(n0 + row) * 128 + off);
    }
    __syncthreads();

    const int w = tid >> 6;
    const int lr = tid & 15;
    const int kg = (tid & 63) >> 4;

    f32x4 acc[2][4];
    #pragma unroll
    for (int mi = 0; mi < 2; ++mi)
        #pragma unroll
        for (int ni = 0; ni < 4; ++ni) acc[mi][ni] = (f32x4)0.f;

    #pragma unroll
    for (int ks = 0; ks < 4; ++ks) {
        bfrag af[2], bb[4];
        #pragma unroll
        for (int mi = 0; mi < 2; ++mi)
            af[mi] = *(const bfrag*)&As[32 * w + 16 * mi + lr][32 * ks + 8 * kg];
        #pragma unroll
        for (int ni = 0; ni < 4; ++ni)
            bb[ni] = *(const bfrag*)&Bs[16 * ni + lr][32 * ks + 8 * kg];
        #pragma unroll
        for (int mi = 0; mi < 2; ++mi)
            #pragma unroll
            for (int ni = 0; ni < 4; ++ni)
                acc[mi][ni] = __builtin_amdgcn_mfma_f32_16x16x32_bf16(
                    af[mi], bb[ni], acc[mi][ni], 0, 0, 0);
    }

    #pragma unroll
    for (int mi = 0; mi < 2; ++mi) {
        #pragma unroll
        for (int r = 0; r < 4; ++r) {
            int row = m0 + 32 * w + 16 * mi + 4 * kg + r;
            if (row < M) {
                #pragma unroll
                for (int ni = 0; ni < 4; ++ni) {
                    int col = n0 + 16 * ni + lr;
                    C[(size_t)row * N + col] = f2bf(acc[mi][ni][r]);
                }
            }
        }
    }
}

// ---------------- per-head GEMM: ofeat[:,128h:128h+128] = relu(BN(z_h @ W_h)), bf16 out
__global__ __launch_bounds__(256) void gemm_z_k(const ushort_t* __restrict__ zb,
                                                const ushort_t* __restrict__ wgatT,
                                                const float* __restrict__ Aa,
                                                const float* __restrict__ Ba,
                                                ushort_t* __restrict__ ofeat) {
    __shared__ short As[128][136];
    __shared__ short Bs[64][136];
    const int tid = threadIdx.x;
    const int head = blockIdx.z;
    const int m0 = blockIdx.x * 128;
    const int n0 = blockIdx.y * 64;
    const ushort_t* A = zb + (size_t)head * NN * HD;
    const ushort_t* BT = wgatT + (size_t)head * HD * HD;

    #pragma unroll
    for (int i = 0; i < 8; ++i) {
        int c = tid + 256 * i;
        int row = c >> 4, off = (c & 15) * 8;
        bfrag v = (bfrag)0;
        if (m0 + row < NN) v = *(const bfrag*)(A + (size_t)(m0 + row) * HD + off);
        *(bfrag*)&As[row][off] = v;
    }
    #pragma unroll
    for (int i = 0; i < 4; ++i) {
        int c = tid + 256 * i;
        int row = c >> 4, off = (c & 15) * 8;
        *(bfrag*)&Bs[row][off] = *(const bfrag*)(BT + (size_t)(n0 + row) * HD + off);
    }
    __syncthreads();

    const int w = tid >> 6;
    const int lr = tid & 15;
    const int kg = (tid & 63) >> 4;

    f32x4 acc[2][4];
    #pragma unroll
    for (int mi = 0; mi < 2; ++mi)
        #pragma unroll
        for (int ni = 0; ni < 4; ++ni) acc[mi][ni] = (f32x4)0.f;

    #pragma unroll
    for (int ks = 0; ks < 4; ++ks) {
        bfrag af[2], bb[4];
        #pragma unroll
        for (int mi = 0; mi < 2; ++mi)
            af[mi] = *(const bfrag*)&As[32 * w + 16 * mi + lr][32 * ks + 8 * kg];
        #pragma unroll
        for (int ni = 0; ni < 4; ++ni)
            bb[ni] = *(const bfrag*)&Bs[16 * ni + lr][32 * ks + 8 * kg];
        #pragma unroll
        for (int mi = 0; mi < 2; ++mi)
            #pragma unroll
            for (int ni = 0; ni < 4; ++ni)
                acc[mi][ni] = __builtin_amdgcn_mfma_f32_16x16x32_bf16(
                    af[mi], bb[ni], acc[mi][ni], 0, 0, 0);
    }

    #pragma unroll
    for (int mi = 0; mi < 2; ++mi) {
        #pragma unroll
        for (int r = 0; r < 4; ++r) {
            int row = m0 + 32 * w + 16 * mi + 4 * kg + r;
            if (row < NN) {
                #pragma unroll
                for (int ni = 0; ni < 4; ++ni) {
                    int gc = 128 * head + n0 + 16 * ni + lr;
                    float v = fmaf(acc[mi][ni][r], Aa[gc], Ba[gc]);
                    ofeat[(size_t)row * OD + gc] = f2bf(fmaxf(v, 0.f));
                }
            }
        }
    }
}

// ---------------- GCN aggregate + BN + ReLU + fused attention dots ----------------
// wave/node, 16 lanes/edge, packed-f32 FMA; epilogue: group g computes dots j=2g,2g+1
__global__ __launch_bounds__(256) void gcn_agg4_k(
    const ushort_t* __restrict__ h0, const int* __restrict__ rowptr,
    const int* __restrict__ csr, const float* __restrict__ dis,
    const float* __restrict__ Ag, const float* __restrict__ Bg,
    const float* __restrict__ waT,
    ushort_t* __restrict__ h, float* __restrict__ asrc, float* __restrict__ adst) {
    int lane = threadIdx.x & 63;
    int g = lane >> 4;              // edge sub-slot within wave
    int sl = lane & 15;             // 16-byte dim chunk
    int sl8 = sl * 8;
    int n = __builtin_amdgcn_readfirstlane((int)(blockIdx.x * 4) + (int)(threadIdx.x >> 6));
    int r0 = __builtin_amdgcn_readfirstlane(rowptr[n]);
    int r1 = __builtin_amdgcn_readfirstlane(rowptr[n + 1]);
    f32x2 a2[4];
    #pragma unroll
    for (int q = 0; q < 4; ++q) a2[q] = (f32x2)0.f;
    uint4 hv[2];
    float wv[2];

#define GLOAD(i, BASE) { int _e = (BASE) + g; int _ec = min(_e, r1 - 1); \
    int _s = csr[_ec]; \
    wv[i] = (_e < r1) ? dis[_s] : 0.f; \
    hv[i] = *(const uint4*)(h0 + ((size_t)(unsigned)_s << 7) + sl8); }
#define GACC(i) { f32x2 _w = {wv[i], wv[i]}; \
    f32x2 _f0 = {bf2f_lo(hv[i].x), bf2f_hi(hv[i].x)}; \
    f32x2 _f1 = {bf2f_lo(hv[i].y), bf2f_hi(hv[i].y)}; \
    f32x2 _f2 = {bf2f_lo(hv[i].z), bf2f_hi(hv[i].z)}; \
    f32x2 _f3 = {bf2f_lo(hv[i].w), bf2f_hi(hv[i].w)}; \
    a2[0] = __builtin_elementwise_fma(_w, _f0, a2[0]); \
    a2[1] = __builtin_elementwise_fma(_w, _f1, a2[1]); \
    a2[2] = __builtin_elementwise_fma(_w, _f2, a2[2]); \
    a2[3] = __builtin_elementwise_fma(_w, _f3, a2[3]); }

    GLOAD(0, r0) GLOAD(1, r0 + 4)
    for (int base = r0; base < r1; base += 8) {
        GACC(0) GLOAD(0, base + 8)
        GACC(1) GLOAD(1, base + 12)
    }
#undef GLOAD
#undef GACC

    // reduce across the 4 edge groups
    #pragma unroll
    for (int q = 0; q < 4; ++q) {
        f32x2 v = a2[q];
        v.x += __shfl_xor(v.x, 16); v.x += __shfl_xor(v.x, 32);
        v.y += __shfl_xor(v.y, 16); v.y += __shfl_xor(v.y, 32);
        a2[q] = v;
    }
    float a[8] = {a2[0].x, a2[0].y, a2[1].x, a2[1].y,
                  a2[2].x, a2[2].y, a2[3].x, a2[3].y};
    float t = dis[n];
    float4 A0 = *(const float4*)(Ag + sl8);
    float4 A1 = *(const float4*)(Ag + sl8 + 4);
    float4 B0 = *(const float4*)(Bg + sl8);
    float4 B1 = *(const float4*)(Bg + sl8 + 4);
    float o[8];
    o[0] = fmaxf(fmaf(a[0] * t, A0.x, B0.x), 0.f);
    o[1] = fmaxf(fmaf(a[1] * t, A0.y, B0.y), 0.f);
    o[2] = fmaxf(fmaf(a[2] * t, A0.z, B0.z), 0.f);
    o[3] = fmaxf(fmaf(a[3] * t, A0.w, B0.w), 0.f);
    o[4] = fmaxf(fmaf(a[4] * t, A1.x, B1.x), 0.f);
    o[5] = fmaxf(fmaf(a[5] * t, A1.y, B1.y), 0.f);
    o[6] = fmaxf(fmaf(a[6] * t, A1.z, B1.z), 0.f);
    o[7] = fmaxf(fmaf(a[7] * t, A1.w, B1.w), 0.f);
    if (g == 0) {
        uint4 pk;
        pk.x = (unsigned int)f2bf(o[0]) | ((unsigned int)f2bf(o[1]) << 16);
        pk.y = (unsigned int)f2bf(o[2]) | ((unsigned int)f2bf(o[3]) << 16);
        pk.z = (unsigned int)f2bf(o[4]) | ((unsigned int)f2bf(o[5]) << 16);
        pk.w = (unsigned int)f2bf(o[6]) | ((unsigned int)f2bf(o[7]) << 16);
        *(uint4*)(h + (size_t)n * HD + sl8) = pk;
    }
    // fused attention dots: group g computes j = 2g and 2g+1
    const float* w0 = waT + (2 * g) * 128 + sl8;
    const float* w1 = waT + (2 * g + 1) * 128 + sl8;
    float4 wA0 = *(const float4*)(w0);
    float4 wA1 = *(const float4*)(w0 + 4);
    float4 wB0 = *(const float4*)(w1);
    float4 wB1 = *(const float4*)(w1 + 4);
    float p0 = o[0] * wA0.x + o[1] * wA0.y + o[2] * wA0.z + o[3] * wA0.w
             + o[4] * wA1.x + o[5] * wA1.y + o[6] * wA1.z + o[7] * wA1.w;
    float p1 = o[0] * wB0.x + o[1] * wB0.y + o[2] * wB0.z + o[3] * wB0.w
             + o[4] * wB1.x + o[5] * wB1.y + o[6] * wB1.z + o[7] * wB1.w;
    #pragma unroll
    for (int off2 = 1; off2 < 16; off2 <<= 1) {
        p0 += __shfl_xor(p0, off2);
        p1 += __shfl_xor(p1, off2);
    }
    if (sl == 0) {
        int j0 = 2 * g;
        float* d0 = (j0 < 4) ? asrc : adst;
        float* d1 = (j0 + 1 < 4) ? asrc : adst;
        d0[n * 4 + (j0 & 3)] = p0;
        d1[n * 4 + ((j0 + 1) & 3)] = p1;
    }
}

// ---------------- fused GAT: softmax numerators + weighted gather, packed-f32 FMA ----------------
__global__ __launch_bounds__(256) void zgather2_k(
    const ushort_t* __restrict__ h, const int* __restrict__ rowptr,
    const int* __restrict__ csr, const float* __restrict__ asrc,
    const float* __restrict__ adst, ushort_t* __restrict__ zb) {
    int lane = threadIdx.x & 63;
    int g = lane >> 4;
    int sl = lane & 15;
    int sl8 = sl * 8;
    int n = __builtin_amdgcn_readfirstlane((int)(blockIdx.x * 4) + (int)(threadIdx.x >> 6));
    int r0 = __builtin_amdgcn_readfirstlane(rowptr[n]);
    int r1 = __builtin_amdgcn_readfirstlane(rowptr[n + 1]);
    float4 ad = *(const float4*)(adst + 4 * n);     // uniform

    f32x2 acc[4][4];                // [head][dim-pair]
    #pragma unroll
    for (int hh = 0; hh < 4; ++hh)
        #pragma unroll
        for (int q = 0; q < 4; ++q) acc[hh][q] = (f32x2)0.f;
    f32x2 s01 = (f32x2)0.f, s23 = (f32x2)0.f;

    uint4 hv[2];
    f32x2 pa[2], pb[2];             // {p0,p1}, {p2,p3}

#define ZLOAD(i, BASE) { int _e = (BASE) + g; int _ec = min(_e, r1 - 1); \
    int _s = csr[_ec]; bool _v = _e < r1; \
    float4 _as = *(const float4*)(asrc + 4 * (size_t)_s); \
    f32x2 _x01 = {_as.x + ad.x, _as.y + ad.y}; \
    f32x2 _x23 = {_as.z + ad.z, _as.w + ad.w}; \
    f32x2 _l01 = __builtin_elementwise_max(_x01, 0.2f * _x01); \
    f32x2 _l23 = __builtin_elementwise_max(_x23, 0.2f * _x23); \
    pa[i].x = _v ? __expf(_l01.x) : 0.f; \
    pa[i].y = _v ? __expf(_l01.y) : 0.f; \
    pb[i].x = _v ? __expf(_l23.x) : 0.f; \
    pb[i].y = _v ? __expf(_l23.y) : 0.f; \
    hv[i] = *(const uint4*)(h + ((size_t)(unsigned)_s << 7) + sl8); }
#define ZACC(i) { \
    f32x2 _f0 = {bf2f_lo(hv[i].x), bf2f_hi(hv[i].x)}; \
    f32x2 _f1 = {bf2f_lo(hv[i].y), bf2f_hi(hv[i].y)}; \
    f32x2 _f2 = {bf2f_lo(hv[i].z), bf2f_hi(hv[i].z)}; \
    f32x2 _f3 = {bf2f_lo(hv[i].w), bf2f_hi(hv[i].w)}; \
    s01 += pa[i]; s23 += pb[i]; \
    f32x2 _p0 = {pa[i].x, pa[i].x}; \
    f32x2 _p1 = {pa[i].y, pa[i].y}; \
    f32x2 _p2 = {pb[i].x, pb[i].x}; \
    f32x2 _p3 = {pb[i].y, pb[i].y}; \
    acc[0][0] = __builtin_elementwise_fma(_p0, _f0, acc[0][0]); \
    acc[0][1] = __builtin_elementwise_fma(_p0, _f1, acc[0][1]); \
    acc[0][2] = __builtin_elementwise_fma(_p0, _f2, acc[0][2]); \
    acc[0][3] = __builtin_elementwise_fma(_p0, _f3, acc[0][3]); \
    acc[1][0] = __builtin_elementwise_fma(_p1, _f0, acc[1][0]); \
    acc[1][1] = __builtin_elementwise_fma(_p1, _f1, acc[1][1]); \
    acc[1][2] = __builtin_elementwise_fma(_p1, _f2, acc[1][2]); \
    acc[1][3] = __builtin_elementwise_fma(_p1, _f3, acc[1][3]); \
    acc[2][0] = __builtin_elementwise_fma(_p2, _f0, acc[2][0]); \
    acc[2][1] = __builtin_elementwise_fma(_p2, _f1, acc[2][1]); \
    acc[2][2] = __builtin_elementwise_fma(_p2, _f2, acc[2][2]); \
    acc[2][3] = __builtin_elementwise_fma(_p2, _f3, acc[2][3]); \
    acc[3][0] = __builtin_elementwise_fma(_p3, _f0, acc[3][0]); \
    acc[3][1] = __builtin_elementwise_fma(_p3, _f1, acc[3][1]); \
    acc[3][2] = __builtin_elementwise_fma(_p3, _f2, acc[3][2]); \
    acc[3][3] = __builtin_elementwise_fma(_p3, _f3, acc[3][3]); }

    ZLOAD(0, r0) ZLOAD(1, r0 + 4)
    for (int base = r0; base < r1; base += 8) {
        ZACC(0) ZLOAD(0, base + 8)
        ZACC(1) ZLOAD(1, base + 12)
    }
#undef ZLOAD
#undef ZACC

    // reduce across the 4 edge groups
    #pragma unroll
    for (int hh = 0; hh < 4; ++hh)
        #pragma unroll
        for (int q = 0; q < 4; ++q) {
            f32x2 v = acc[hh][q];
            v.x += __shfl_xor(v.x, 16); v.x += __shfl_xor(v.x, 32);
            v.y += __shfl_xor(v.y, 16); v.y += __shfl_xor(v.y, 32);
            acc[hh][q] = v;
        }
    float s0 = s01.x, s1 = s01.y, s2 = s23.x, s3 = s23.y;
    s0 += __shfl_xor(s0, 16); s0 += __shfl_xor(s0, 32);
    s1 += __shfl_xor(s1, 16); s1 += __shfl_xor(s1, 32);
    s2 += __shfl_xor(s2, 16); s2 += __shfl_xor(s2, 32);
    s3 += __shfl_xor(s3, 16); s3 += __shfl_xor(s3, 32);

    float inv0 = 1.f / (s0 + 1e-16f), inv1 = 1.f / (s1 + 1e-16f);
    float inv2 = 1.f / (s2 + 1e-16f), inv3 = 1.f / (s3 + 1e-16f);
    float invg = (g == 0) ? inv0 : (g == 1) ? inv1 : (g == 2) ? inv2 : inv3;

    unsigned int pkc[4];
    #pragma unroll
    for (int q = 0; q < 4; ++q) {
        f32x2 v01 = (g == 1) ? acc[1][q] : acc[0][q];
        f32x2 v23 = (g == 3) ? acc[3][q] : acc[2][q];
        f32x2 v = (g & 2) ? v23 : v01;
        v = v * invg;
        pkc[q] = (unsigned int)f2bf(v.x) | ((unsigned int)f2bf(v.y) << 16);
    }
    uint4 pk = {pkc[0], pkc[1], pkc[2], pkc[3]};
    *(uint4*)(zb + (size_t)g * NN * HD + (size_t)n * HD + sl8) = pk;
}

// ---------------- fused pooling + head: one block per graph ----------------
__global__ __launch_bounds__(256) void poolhead_k(
    const ushort_t* __restrict__ ofeat, const int* __restrict__ batch,
    const float* __restrict__ w_lin, const float* __restrict__ b_lin,
    float* __restrict__ out) {
    __shared__ float fs[1536];
    __shared__ float red[256];
    int g = blockIdx.x, t = threadIdx.x;
    int lo = 0, hi = NN;
    while (lo < hi) { int mid = (lo + hi) >> 1; if (batch[mid] < g) lo = mid + 1; else hi = mid; }
    int start = lo;
    hi = NN;
    while (lo < hi) { int mid = (lo + hi) >> 1; if (batch[mid] < g + 1) lo = mid + 1; else hi = mid; }
    int end = lo;
    int cnt = end - start;
    float sa0 = 0.f, sa1 = 0.f;
    float mx0 = -3.402823466e38f, mx1 = mx0;
    const unsigned int* base = (const unsigned int*)ofeat + t;   // dword t of each 256-dword row
    int i = start;
    for (; i + 4 <= end; i += 4) {
        unsigned int v0 = base[(size_t)(i + 0) * 256];
        unsigned int v1 = base[(size_t)(i + 1) * 256];
        unsigned int v2 = base[(size_t)(i + 2) * 256];
        unsigned int v3 = base[(size_t)(i + 3) * 256];
        float a0 = bf2f_lo(v0), b0 = bf2f_hi(v0);
        float a1 = bf2f_lo(v1), b1 = bf2f_hi(v1);
        float a2 = bf2f_lo(v2), b2 = bf2f_hi(v2);
        float a3 = bf2f_lo(v3), b3 = bf2f_hi(v3);
        sa0 += (a0 + a1) + (a2 + a3);
        sa1 += (b0 + b1) + (b2 + b3);
        mx0 = fmaxf(fmaxf(fmaxf(mx0, a0), fmaxf(a1, a2)), a3);
        mx1 = fmaxf(fmaxf(fmaxf(mx1, b0), fmaxf(b1, b2)), b3);
    }
    for (; i < end; ++i) {
        unsigned int v = base[(size_t)i * 256];
        float a = bf2f_lo(v), b = bf2f_hi(v);
        sa0 += a; sa1 += b;
        mx0 = fmaxf(mx0, a); mx1 = fmaxf(mx1, b);
    }
    float sm0, sm1;
    if (cnt > 0) { sm0 = sa0 / (float)cnt; sm1 = sa1 / (float)cnt; }
    else { sa0 = sa1 = 0.f; mx0 = mx1 = 0.f; sm0 = sm1 = 0.f; }
    fs[2 * t] = sa0;          fs[2 * t + 1] = sa1;
    fs[512 + 2 * t] = mx0;    fs[512 + 2 * t + 1] = mx1;
    fs[1024 + 2 * t] = sm0;   fs[1024 + 2 * t + 1] = sm1;
    __syncthreads();
    int o = t & 15, part = t >> 4;
    float s = 0.f;
    int kbeg = part * 96;
    for (int k = kbeg; k < kbeg + 96; ++k) s += fs[k] * w_lin[k * 16 + o];
    red[t] = s;
    __syncthreads();
    if (t < 16) {
        float tot = b_lin[o];
        for (int p = 0; p < 16; ++p) tot += red[p * 16 + o];
        out[g * 16 + o] = 1.f / (1.f + __expf(-tot));
    }
}

extern "C" void kernel_launch(void* const* d_in, const int* in_sizes, int n_in,
                              void* d_out, int out_size, void* d_ws, size_t ws_size,
                              hipStream_t stream) {
    const float* x       = (const float*)d_in[0];
    const int*   ei      = (const int*)d_in[1];
    const int*   batch   = (const int*)d_in[2];
    const float* w_gcn   = (const float*)d_in[3];
    const float* b_gcn   = (const float*)d_in[4];
    const float* g2_gam  = (const float*)d_in[5];
    const float* g2_bet  = (const float*)d_in[6];
    const float* g2_mean = (const float*)d_in[7];
    const float* g2_var  = (const float*)d_in[8];
    const float* w_gat   = (const float*)d_in[9];
    const float* a_src   = (const float*)d_in[10];
    const float* a_dst   = (const float*)d_in[11];
    const float* b_gat   = (const float*)d_in[12];
    const float* g1_gam  = (const float*)d_in[13];
    const float* g1_bet  = (const float*)d_in[14];
    const float* g1_mean = (const float*)d_in[15];
    const float* g1_var  = (const float*)d_in[16];
    const float* w_lin   = (const float*)d_in[17];
    const float* b_lin   = (const float*)d_in[18];
    float* out = (float*)d_out;

    char* ws = (char*)d_ws;
    size_t off = 0;
    auto alloc = [&](size_t bytes) -> void* {
        void* p = ws + off;
        off += (bytes + 255) & ~(size_t)255;
        return p;
    };
    int* deg        = (int*)alloc((size_t)NN * 4);
    int* fill       = (int*)alloc((size_t)NN * 4);
    int* rowptr     = (int*)alloc((size_t)(NN + 1) * 4);
    int* csr        = (int*)alloc((size_t)NE2 * 4);
    int* bsum       = (int*)alloc((size_t)NB_SCAN * 4);
    float* dis      = (float*)alloc((size_t)NN * 4);
    ushort_t* xb    = (ushort_t*)alloc((size_t)NN * FD * 2);
    ushort_t* wgT   = (ushort_t*)alloc((size_t)FD * HD * 2);
    ushort_t* wgatT = (ushort_t*)alloc((size_t)HD * OD * 2);
    ushort_t* h0b   = (ushort_t*)alloc((size_t)NN * HD * 2);
    ushort_t* hb    = (ushort_t*)alloc((size_t)NN * HD * 2);
    ushort_t* zb    = (ushort_t*)alloc((size_t)NHD * NN * HD * 2);
    float* asrc     = (float*)alloc((size_t)NN * 4 * 4);
    float* adst     = (float*)alloc((size_t)NN * 4 * 4);
    float* waT      = (float*)alloc((size_t)8 * 128 * 4);
    float* Ag       = (float*)alloc((size_t)HD * 4);
    float* Bg       = (float*)alloc((size_t)HD * 4);
    float* Aa       = (float*)alloc((size_t)OD * 4);
    float* Ba       = (float*)alloc((size_t)OD * 4);
    ushort_t* ofeat = (ushort_t*)alloc((size_t)NN * OD * 2);

    // CSR build
    init_k<<<(NN + 255) / 256, 256, 0, stream>>>(deg, fill);
    count_k<<<(NE + 255) / 256, 256, 0, stream>>>(ei, deg);
    scanA_k<<<NB_SCAN, 256, 0, stream>>>(deg, bsum);
    scanC_k<<<NB_SCAN, 256, 0, stream>>>(deg, bsum, rowptr, dis);
    fill_k<<<(NE2 + 255) / 256, 256, 0, stream>>>(ei, rowptr, fill, csr);

    // merged BN affine + waT + casts
    castprep_k<<<7 + XB_BLOCKS + WG_BLOCKS + WA_BLOCKS, 256, 0, stream>>>(
        b_gcn, g2_gam, g2_bet, g2_mean, g2_var,
        b_gat, g1_gam, g1_bet, g1_mean, g1_var,
        Ag, Bg, Aa, Ba, a_src, a_dst, waT,
        x, xb, w_gcn, wgT, w_gat, wgatT);

    // GCN linear: h0 = x @ w_gcn   (bf16 MFMA)
    gemm_bf16<<<dim3((NN + 127) / 128, HD / 64), 256, 0, stream>>>(xb, wgT, h0b, NN, HD);

    // GCN aggregate + BN2 + ReLU + attention dots
    gcn_agg4_k<<<NN / 4, 256, 0, stream>>>(h0b, rowptr, csr, dis, Ag, Bg, waT,
                                           hb, asrc, adst);

    // fused GAT softmax + gather: per-head weighted sums of h rows
    zgather2_k<<<NN / 4, 256, 0, stream>>>(hb, rowptr, csr, asrc, adst, zb);

    // per-head GEMM + BN1 + ReLU -> ofeat (bf16)
    gemm_z_k<<<dim3((NN + 127) / 128, HD / 64, NHD), 256, 0, stream>>>(zb, wgatT, Aa, Ba, ofeat);

    // fused pooling + head
    poolhead_k<<<NG, 256, 0, stream>>>(ofeat, batch, w_lin, b_lin, out);
}